// Round 11
// baseline (2343.707 us; speedup 1.0000x reference)
//
#include <hip/hip_runtime.h>
#include <hip/hip_bf16.h>
#include <stdint.h>

#define BB 2
#define SS 1024
#define VV 513
#define VP 576          // 513 padded to 9*64
#define DD 512
#define HH 8
#define DKK 64
#define DFFN 2048
#define LL 6
#define MM (BB * SS)    // 2048

typedef __bf16 bf16x8 __attribute__((ext_vector_type(8)));
typedef float f32x4 __attribute__((ext_vector_type(4)));
typedef unsigned short us8 __attribute__((ext_vector_type(8)));
typedef unsigned short us4 __attribute__((ext_vector_type(4)));

static __device__ inline unsigned short f2bf(float f) {
  union { float f; unsigned u; } v; v.f = f;
  unsigned u = v.u;
  unsigned r = (u + 0x7FFFu + ((u >> 16) & 1u)) >> 16;
  return (unsigned short)r;
}

static __device__ inline bf16x8 ldfrag(const unsigned short* p) {
  us8 r = *(const us8*)p;
  return __builtin_bit_cast(bf16x8, r);
}

typedef __attribute__((address_space(3))) void lds_void;
typedef const __attribute__((address_space(1))) void glb_void;
static __device__ inline void gl_lds16(const void* g, void* l) {
  __builtin_amdgcn_global_load_lds((glb_void*)g, (lds_void*)l, 16, 0, 0);
}

// swizzled LDS fragment read: tile rows are linear 128B, byte ^= (row&7)<<4
static __device__ inline bf16x8 ldfrag_swz(const unsigned short* base, int row, int kloc) {
  const unsigned byte = (unsigned)(row * 128 + kloc * 2) ^ (unsigned)((row & 7) << 4);
  return ldfrag((const unsigned short*)((const char*)base + byte));
}

static __device__ inline int rot3(int x) { return (x == 2) ? 0 : x + 1; }

// ---------------------------------------------------------------------------
// Fused row-panel GEMM + residual + LayerNorm (NO cross-block comm).
// Each block owns 64 rows x ALL 512 cols. A panel staged once per 512-K chunk;
// B streamed as 64 pipelined 8KB tiles. acc[8][4] f32x4 in registers; LN on
// registers via 16-lane shfl reduce. out = LN(resid + A@B^T).
// ---------------------------------------------------------------------------
struct RowLnP {
  const unsigned short* A;   // [2048][Kp] bf16
  const unsigned short* B;   // [512][Kp] bf16 (transposed weight)
  const float* resid;        // [2048][512] f32
  const float* gamma; const float* beta;
  float* hfout; unsigned short* hbout;
  int Kp;                    // 512 or 1024
};

__global__ __launch_bounds__(256)
void gemm_rowln(RowLnP p)
{
  __shared__ unsigned short Ap[64 * 512];      // 64KB: 8 subtiles [64][64]
  __shared__ unsigned short Bl[3][64 * 64];    // 24KB
  const int tid = threadIdx.x;
  const int l = tid & 63, w = tid >> 6;
  const int lr = l & 15, lg = l >> 4;
  const int m0 = blockIdx.x << 6;

  f32x4 acc[8][4];
  const f32x4 zf = {0.f, 0.f, 0.f, 0.f};
#pragma unroll
  for (int nt = 0; nt < 8; ++nt)
#pragma unroll
    for (int nf = 0; nf < 4; ++nf) acc[nt][nf] = zf;

  const int Kp = p.Kp;
  const int KC = Kp >> 9;

  auto stageB = [&](int buf, int kc, int t) {
    const int nt = t >> 3, kt = t & 7;
#pragma unroll
    for (int j = 0; j < 2; ++j) {
      const int ti = j * 256 + tid;
      const int rw = ti >> 3, chi = ti & 7;
      const int ch = chi ^ (rw & 7);
      gl_lds16(p.B + (size_t)(nt * 64 + rw) * Kp + kc * 512 + kt * 64 + ch * 8,
               &Bl[buf][ti * 8]);
    }
  };

  for (int kc = 0; kc < KC; ++kc) {
    if (kc > 0) __builtin_amdgcn_s_barrier();   // all waves done with prev chunk
    // stage A chunk: 64 rows x 512 k as 8 linear subtiles (16 instr/thread)
#pragma unroll
    for (int j = 0; j < 16; ++j) {
      const int ti = j * 256 + tid;
      const int kt = ti >> 9, rw = (ti >> 3) & 63, chi = ti & 7;
      const int ch = chi ^ (rw & 7);
      gl_lds16(p.A + (size_t)(m0 + rw) * Kp + kc * 512 + kt * 64 + ch * 8,
               &Ap[ti * 8]);
    }
    stageB(0, kc, 0);
    stageB(1, kc, 1);
    for (int t = 0; t < 64; ++t) {
      if (t + 1 < 64) asm volatile("s_waitcnt vmcnt(2)" ::: "memory");
      else            asm volatile("s_waitcnt vmcnt(0)" ::: "memory");
      __builtin_amdgcn_s_barrier();
      if (t + 2 < 64) stageB((t + 2) % 3, kc, t + 2);
      const unsigned short* Asub = &Ap[(t & 7) * 4096];
      const unsigned short* Bt = &Bl[t % 3][0];
      const int nt = t >> 3;
#pragma unroll
      for (int ks = 0; ks < 2; ++ks) {
        bf16x8 af = ldfrag_swz(Asub, w * 16 + lr, ks * 32 + lg * 8);
#pragma unroll
        for (int nf = 0; nf < 4; ++nf) {
          bf16x8 bfv = ldfrag_swz(Bt, nf * 16 + lr, ks * 32 + lg * 8);
          acc[nt][nf] = __builtin_amdgcn_mfma_f32_16x16x32_bf16(af, bfv, acc[nt][nf], 0, 0, 0);
        }
      }
    }
  }

  // ---- epilogue: residual add + LN, all in registers ----
#pragma unroll
  for (int nt = 0; nt < 8; ++nt)
#pragma unroll
    for (int nf = 0; nf < 4; ++nf) {
      const int col = nt * 64 + nf * 16 + lr;
#pragma unroll
      for (int rr = 0; rr < 4; ++rr) {
        const int row = m0 + w * 16 + (lg << 2) + rr;
        acc[nt][nf][rr] += p.resid[(size_t)row * DD + col];
      }
    }
  float mean[4], rs[4];
#pragma unroll
  for (int rr = 0; rr < 4; ++rr) {
    float s = 0.f;
#pragma unroll
    for (int nt = 0; nt < 8; ++nt)
#pragma unroll
      for (int nf = 0; nf < 4; ++nf) s += acc[nt][nf][rr];
#pragma unroll
    for (int off = 1; off < 16; off <<= 1) s += __shfl_xor(s, off, 64);
    mean[rr] = s * (1.f / 512.f);
  }
#pragma unroll
  for (int rr = 0; rr < 4; ++rr) {
    float v = 0.f;
#pragma unroll
    for (int nt = 0; nt < 8; ++nt)
#pragma unroll
      for (int nf = 0; nf < 4; ++nf) {
        const float d = acc[nt][nf][rr] - mean[rr];
        v += d * d;
      }
#pragma unroll
    for (int off = 1; off < 16; off <<= 1) v += __shfl_xor(v, off, 64);
    rs[rr] = rsqrtf(v * (1.f / 512.f) + 1e-6f);
  }
#pragma unroll
  for (int nt = 0; nt < 8; ++nt)
#pragma unroll
    for (int nf = 0; nf < 4; ++nf) {
      const int col = nt * 64 + nf * 16 + lr;
      const float gg = p.gamma[col], bb = p.beta[col];
#pragma unroll
      for (int rr = 0; rr < 4; ++rr) {
        const int row = m0 + w * 16 + (lg << 2) + rr;
        const float val = (acc[nt][nf][rr] - mean[rr]) * rs[rr] * gg + bb;
        p.hfout[(size_t)row * DD + col] = val;
        p.hbout[(size_t)row * DD + col] = f2bf(val);
      }
    }
}

// ---------------------------------------------------------------------------
// GEMM: C = A[M][Kp](bf16) * B^T, B stored [N][Kp] bf16 (padded).
// TRV: sel==2 output stored transposed into [b][h][dk][s].
// KS: split-K factor (grid.z); partials go to p.C + z*MM*ldc (f32).
// ---------------------------------------------------------------------------
struct GemmP {
  const unsigned short* A;
  const unsigned short* B0; const unsigned short* B1; const unsigned short* B2;
  const float* bias;
  float* C;
  unsigned short* D0; unsigned short* D1; unsigned short* D2;
  int Kp, Np, ldc, Nreal, relu;
};

template<int NB, int NT, int TRV, int KS>
__global__ __launch_bounds__(256)
void gemm_tpl(GemmP p)
{
  constexpr int FN = NT / 32;
  __shared__ unsigned short Al[3][64 * 64];
  __shared__ unsigned short Bl[3][NT * 64];
  const int tid = threadIdx.x;
  const int l = tid & 63, w = tid >> 6;
  const int wm = w >> 1, wn = w & 1;
  const int lr = l & 15, lg = l >> 4;

  const int nbn = p.Np / NT;
  int sel = 0, bx = blockIdx.x;
  if (NB > 1) { sel = bx / nbn; bx -= sel * nbn; }
  const unsigned short* Bmat = p.B0;
  if (NB > 1 && sel == 1) Bmat = p.B1;
  if (NB > 2 && sel == 2) Bmat = p.B2;
  const int m0 = blockIdx.y << 6, n0 = bx * NT;
  const int kz = (KS > 1) ? blockIdx.z : 0;

  f32x4 acc[2][FN];
  const f32x4 zf = {0.f, 0.f, 0.f, 0.f};
#pragma unroll
  for (int i = 0; i < 2; ++i)
#pragma unroll
    for (int j = 0; j < FN; ++j) acc[i][j] = zf;

  const size_t Kp = (size_t)p.Kp;
  const unsigned short* Abase = p.A + (size_t)m0 * Kp;
  const unsigned short* Bbase = Bmat + (size_t)n0 * Kp;
  const int nt = (p.Kp >> 6) / KS;
  const int kb0 = kz * nt;

  auto stage = [&](int buf, int kt) {
    const int k0 = (kb0 + kt) << 6;
#pragma unroll
    for (int j = 0; j < 2; ++j) {
      const int ti = j * 256 + tid;
      const int row = ti >> 3;
      const int ch = (ti & 7) ^ (row & 7);
      gl_lds16(Abase + (size_t)row * Kp + k0 + ch * 8, &Al[buf][ti * 8]);
    }
#pragma unroll
    for (int j = 0; j < FN; ++j) {
      const int ti = j * 256 + tid;
      const int row = ti >> 3;
      const int ch = (ti & 7) ^ (row & 7);
      gl_lds16(Bbase + (size_t)row * Kp + k0 + ch * 8, &Bl[buf][ti * 8]);
    }
  };

  stage(0, 0);
  if (nt > 1) stage(1, 1);
  int cb = 0, sb = 2;

  for (int kt = 0; kt < nt; ++kt) {
    if (kt + 1 < nt) {
      if constexpr (FN == 2) asm volatile("s_waitcnt vmcnt(4)" ::: "memory");
      else                   asm volatile("s_waitcnt vmcnt(6)" ::: "memory");
    } else {
      asm volatile("s_waitcnt vmcnt(0)" ::: "memory");
    }
    __builtin_amdgcn_s_barrier();
    if (kt + 2 < nt) { stage(sb, kt + 2); sb = rot3(sb); }
#pragma unroll
    for (int ks = 0; ks < 2; ++ks) {
      bf16x8 af[2], bfv[FN];
#pragma unroll
      for (int mf = 0; mf < 2; ++mf)
        af[mf] = ldfrag_swz(Al[cb], wm * 32 + mf * 16 + lr, ks * 32 + lg * 8);
#pragma unroll
      for (int nf = 0; nf < FN; ++nf)
        bfv[nf] = ldfrag_swz(Bl[cb], wn * (NT / 2) + nf * 16 + lr, ks * 32 + lg * 8);
#pragma unroll
      for (int mf = 0; mf < 2; ++mf)
#pragma unroll
        for (int nf = 0; nf < FN; ++nf)
          acc[mf][nf] = __builtin_amdgcn_mfma_f32_16x16x32_bf16(af[mf], bfv[nf], acc[mf][nf], 0, 0, 0);
    }
    cb = rot3(cb);
  }

  unsigned short* Dsel = p.D0;
  if (NB > 1 && sel == 1) Dsel = p.D1;
  if (NB > 2 && sel == 2) Dsel = p.D2;

  if (TRV && sel == 2) {
#pragma unroll
    for (int mf = 0; mf < 2; ++mf) {
      const int growb = m0 + wm * 32 + mf * 16 + (lg << 2);
      const int b = growb >> 10, s = growb & 1023;
#pragma unroll
      for (int nf = 0; nf < FN; ++nf) {
        const int gcol = n0 + wn * (NT / 2) + nf * 16 + lr;
        const int h = gcol >> 6, d = gcol & 63;
        us4 t;
#pragma unroll
        for (int r = 0; r < 4; ++r) t[r] = f2bf(acc[mf][nf][r]);
        *(us4*)(Dsel + (((size_t)(b * HH) + h) * DKK + d) * SS + s) = t;
      }
    }
    return;
  }

  float* Cz = p.C ? (p.C + (size_t)kz * MM * p.ldc) : nullptr;
#pragma unroll
  for (int mf = 0; mf < 2; ++mf) {
#pragma unroll
    for (int r = 0; r < 4; ++r) {
      const int grow = m0 + wm * 32 + mf * 16 + (lg << 2) + r;
#pragma unroll
      for (int nf = 0; nf < FN; ++nf) {
        const int gcol = n0 + wn * (NT / 2) + nf * 16 + lr;
        float v = acc[mf][nf][r];
        if (p.bias && kz == 0 && gcol < p.Nreal) v += p.bias[gcol];
        if (p.relu) v = fmaxf(v, 0.f);
        if (Dsel) Dsel[(size_t)grow * p.Np + gcol] = f2bf(v);
        if (Cz && gcol < p.Nreal) Cz[(size_t)grow * p.ldc + gcol] = v;
      }
    }
  }
}

// ---------------------------------------------------------------------------
// Batched GEMM over 12 (B,D) pairs sharing A. Odd sel (V) stored transposed.
// ---------------------------------------------------------------------------
struct GemmBat {
  const unsigned short* A;
  const unsigned short* B[12];
  unsigned short* D[12];
  int Kp, Np;
};

__global__ __launch_bounds__(256)
void gemm_bat(GemmBat p)
{
  __shared__ unsigned short Al[3][64 * 64];
  __shared__ unsigned short Bl[3][64 * 64];
  const int tid = threadIdx.x;
  const int l = tid & 63, w = tid >> 6;
  const int wm = w >> 1, wn = w & 1;
  const int lr = l & 15, lg = l >> 4;

  const int nbn = p.Np >> 6;
  const int sel = blockIdx.x / nbn;
  const int bx = blockIdx.x - sel * nbn;
  const unsigned short* Bmat = p.B[sel];
  unsigned short* Dmat = p.D[sel];
  const int m0 = blockIdx.y << 6, n0 = bx << 6;

  f32x4 acc[2][2];
  const f32x4 zf = {0.f, 0.f, 0.f, 0.f};
#pragma unroll
  for (int i = 0; i < 2; ++i)
#pragma unroll
    for (int j = 0; j < 2; ++j) acc[i][j] = zf;

  const size_t Kp = (size_t)p.Kp;
  const unsigned short* Abase = p.A + (size_t)m0 * Kp;
  const unsigned short* Bbase = Bmat + (size_t)n0 * Kp;

  auto stage = [&](int buf, int kt) {
    const int k0 = kt << 6;
#pragma unroll
    for (int j = 0; j < 2; ++j) {
      const int ti = j * 256 + tid;
      const int row = ti >> 3;
      const int ch = (ti & 7) ^ (row & 7);
      gl_lds16(Abase + (size_t)row * Kp + k0 + ch * 8, &Al[buf][ti * 8]);
    }
#pragma unroll
    for (int j = 0; j < 2; ++j) {
      const int ti = j * 256 + tid;
      const int row = ti >> 3;
      const int ch = (ti & 7) ^ (row & 7);
      gl_lds16(Bbase + (size_t)row * Kp + k0 + ch * 8, &Bl[buf][ti * 8]);
    }
  };

  const int nt = p.Kp >> 6;
  stage(0, 0);
  if (nt > 1) stage(1, 1);
  int cb = 0, sb = 2;

  for (int kt = 0; kt < nt; ++kt) {
    if (kt + 1 < nt) asm volatile("s_waitcnt vmcnt(4)" ::: "memory");
    else             asm volatile("s_waitcnt vmcnt(0)" ::: "memory");
    __builtin_amdgcn_s_barrier();
    if (kt + 2 < nt) { stage(sb, kt + 2); sb = rot3(sb); }
#pragma unroll
    for (int ks = 0; ks < 2; ++ks) {
      bf16x8 af[2], bfv[2];
#pragma unroll
      for (int mf = 0; mf < 2; ++mf)
        af[mf] = ldfrag_swz(Al[cb], wm * 32 + mf * 16 + lr, ks * 32 + lg * 8);
#pragma unroll
      for (int nf = 0; nf < 2; ++nf)
        bfv[nf] = ldfrag_swz(Bl[cb], wn * 32 + nf * 16 + lr, ks * 32 + lg * 8);
#pragma unroll
      for (int mf = 0; mf < 2; ++mf)
#pragma unroll
        for (int nf = 0; nf < 2; ++nf)
          acc[mf][nf] = __builtin_amdgcn_mfma_f32_16x16x32_bf16(af[mf], bfv[nf], acc[mf][nf], 0, 0, 0);
    }
    cb = rot3(cb);
  }

  if (sel & 1) {
#pragma unroll
    for (int mf = 0; mf < 2; ++mf) {
      const int growb = m0 + wm * 32 + mf * 16 + (lg << 2);
      const int b = growb >> 10, s = growb & 1023;
#pragma unroll
      for (int nf = 0; nf < 2; ++nf) {
        const int gcol = n0 + wn * 32 + nf * 16 + lr;
        const int h = gcol >> 6, d = gcol & 63;
        us4 t;
#pragma unroll
        for (int r = 0; r < 4; ++r) t[r] = f2bf(acc[mf][nf][r]);
        *(us4*)(Dmat + (((size_t)(b * HH) + h) * DKK + d) * SS + s) = t;
      }
    }
    return;
  }

#pragma unroll
  for (int mf = 0; mf < 2; ++mf) {
#pragma unroll
    for (int r = 0; r < 4; ++r) {
      const int grow = m0 + wm * 32 + mf * 16 + (lg << 2) + r;
#pragma unroll
      for (int nf = 0; nf < 2; ++nf) {
        const int gcol = n0 + wn * 32 + nf * 16 + lr;
        Dmat[(size_t)grow * p.Np + gcol] = f2bf(acc[mf][nf][r]);
      }
    }
  }
}

// ---------------------------------------------------------------------------
// Self-attention (causal): QBLK=32, 2 waves split KV.
// ---------------------------------------------------------------------------
__global__ __launch_bounds__(128)
void attn_kernel(const unsigned short* __restrict__ Qb,
                 const unsigned short* __restrict__ Kb,
                 const unsigned short* __restrict__ VbT,
                 unsigned short* __restrict__ Ob,
                 const float* __restrict__ maskadd)
{
  __shared__ unsigned short Kl[2][2][64 * 64];
  __shared__ unsigned short Vl[2][2][64 * 64];
  __shared__ char PC[9216];
  unsigned short* Pl = (unsigned short*)PC;
  float (*comb)[66] = (float(*)[66])PC;

  const int tid = threadIdx.x;
  const int l = tid & 63, w = tid >> 6;
  const int qt = blockIdx.x, h = blockIdx.y, b = blockIdx.z;
  const int lr = l & 15, lg = l >> 4;

  bf16x8 qf[2][2];
#pragma unroll
  for (int mf = 0; mf < 2; ++mf) {
    const unsigned short* qrow = Qb + ((size_t)(b * SS) + qt * 32 + mf * 16 + lr) * DD + h * DKK;
    qf[mf][0] = ldfrag(qrow + (lg << 3));
    qf[mf][1] = ldfrag(qrow + 32 + (lg << 3));
  }

  const unsigned short* Kbase = Kb + (size_t)(b * SS) * DD + h * DKK;
  const unsigned short* Vbase = VbT + ((size_t)(b * HH) + h) * DKK * SS;

  auto stage = [&](int buf, int kt) {
#pragma unroll
    for (int j = 0; j < 8; ++j) {
      const int ti = j * 64 + l;
      const int row = ti >> 3;
      const int ch = (ti & 7) ^ (row & 7);
      gl_lds16(Kbase + (size_t)(kt * 64 + row) * DD + ch * 8, &Kl[w][buf][ti * 8]);
    }
#pragma unroll
    for (int j = 0; j < 8; ++j) {
      const int ti = j * 64 + l;
      const int row = ti >> 3;
      const int ch = (ti & 7) ^ (row & 7);
      gl_lds16(Vbase + (size_t)row * SS + kt * 64 + ch * 8, &Vl[w][buf][ti * 8]);
    }
  };

  f32x4 accO[2][4];
  const f32x4 zf = {0.f, 0.f, 0.f, 0.f};
#pragma unroll
  for (int mf = 0; mf < 2; ++mf)
#pragma unroll
    for (int nf = 0; nf < 4; ++nf) accO[mf][nf] = zf;
  float mold[2][4], lsum[2][4];
#pragma unroll
  for (int mf = 0; mf < 2; ++mf)
#pragma unroll
    for (int r = 0; r < 4; ++r) { mold[mf][r] = -1e30f; lsum[mf][r] = 0.f; }

  const int ktmax = (qt >> 1) + 1;
  const int myn = (ktmax - w + 1) >> 1;

  if (myn > 0) stage(0, w);
  int buf = 0;

  for (int i = 0; i < myn; ++i) {
    const int kt = w + 2 * i;
    if (i + 1 < myn) {
      stage(buf ^ 1, kt + 2);
      asm volatile("s_waitcnt vmcnt(16)" ::: "memory");
    } else {
      asm volatile("s_waitcnt vmcnt(0)" ::: "memory");
    }
    const unsigned short* KB = &Kl[w][buf][0];
    const unsigned short* VB = &Vl[w][buf][0];
    float sc[2][4][4];
    __builtin_amdgcn_s_setprio(1);
#pragma unroll
    for (int nf = 0; nf < 4; ++nf) {
      bf16x8 k0 = ldfrag_swz(KB, nf * 16 + lr, lg * 8);
      bf16x8 k1 = ldfrag_swz(KB, nf * 16 + lr, 32 + lg * 8);
      const int kglob = kt * 64 + nf * 16 + lr;
      const float madd = maskadd[b * SS + kglob];
#pragma unroll
      for (int mf = 0; mf < 2; ++mf) {
        f32x4 s = zf;
        s = __builtin_amdgcn_mfma_f32_16x16x32_bf16(qf[mf][0], k0, s, 0, 0, 0);
        s = __builtin_amdgcn_mfma_f32_16x16x32_bf16(qf[mf][1], k1, s, 0, 0, 0);
#pragma unroll
        for (int r = 0; r < 4; ++r) {
          const int qglob = qt * 32 + mf * 16 + (lg << 2) + r;
          sc[mf][nf][r] = (kglob > qglob) ? -1e9f : s[r] * 0.125f + madd;
        }
      }
    }
    __builtin_amdgcn_s_setprio(0);
#pragma unroll
    for (int mf = 0; mf < 2; ++mf)
#pragma unroll
      for (int r = 0; r < 4; ++r) {
        float mloc = fmaxf(fmaxf(sc[mf][0][r], sc[mf][1][r]), fmaxf(sc[mf][2][r], sc[mf][3][r]));
#pragma unroll
        for (int off = 1; off < 16; off <<= 1)
          mloc = fmaxf(mloc, __shfl_xor(mloc, off, 64));
        const float mnew = fmaxf(mold[mf][r], mloc);
        const float corr = __expf(mold[mf][r] - mnew);
        float ps = 0.f;
#pragma unroll
        for (int nf = 0; nf < 4; ++nf) {
          const float pv = __expf(sc[mf][nf][r] - mnew);
          sc[mf][nf][r] = pv;
          ps += pv;
        }
#pragma unroll
        for (int off = 1; off < 16; off <<= 1)
          ps += __shfl_xor(ps, off, 64);
        lsum[mf][r] = lsum[mf][r] * corr + ps;
#pragma unroll
        for (int nf = 0; nf < 4; ++nf) accO[mf][nf][r] *= corr;
        mold[mf][r] = mnew;
      }
    unsigned short* pw = Pl + w * 32 * 72;
#pragma unroll
    for (int mf = 0; mf < 2; ++mf)
#pragma unroll
      for (int nf = 0; nf < 4; ++nf)
#pragma unroll
        for (int r = 0; r < 4; ++r)
          pw[(mf * 16 + (lg << 2) + r) * 72 + nf * 16 + lr] = f2bf(sc[mf][nf][r]);
    bf16x8 pa[2][2];
#pragma unroll
    for (int mf = 0; mf < 2; ++mf) {
      pa[mf][0] = ldfrag(&pw[(mf * 16 + lr) * 72 + (lg << 3)]);
      pa[mf][1] = ldfrag(&pw[(mf * 16 + lr) * 72 + 32 + (lg << 3)]);
    }
    __builtin_amdgcn_s_setprio(1);
#pragma unroll
    for (int nf = 0; nf < 4; ++nf) {
      bf16x8 v0 = ldfrag_swz(VB, nf * 16 + lr, lg * 8);
      bf16x8 v1 = ldfrag_swz(VB, nf * 16 + lr, 32 + lg * 8);
#pragma unroll
      for (int mf = 0; mf < 2; ++mf) {
        accO[mf][nf] = __builtin_amdgcn_mfma_f32_16x16x32_bf16(pa[mf][0], v0, accO[mf][nf], 0, 0, 0);
        accO[mf][nf] = __builtin_amdgcn_mfma_f32_16x16x32_bf16(pa[mf][1], v1, accO[mf][nf], 0, 0, 0);
      }
    }
    __builtin_amdgcn_s_setprio(0);
    buf ^= 1;
  }

  __syncthreads();
  if (w == 1) {
#pragma unroll
    for (int mf = 0; mf < 2; ++mf)
#pragma unroll
      for (int r = 0; r < 4; ++r) {
        const int qrow = mf * 16 + (lg << 2) + r;
#pragma unroll
        for (int nf = 0; nf < 4; ++nf)
          comb[qrow][nf * 16 + lr] = accO[mf][nf][r];
        if (lr == 0) { comb[qrow][64] = mold[mf][r]; comb[qrow][65] = lsum[mf][r]; }
      }
  }
  __syncthreads();
  if (w == 0) {
#pragma unroll
    for (int mf = 0; mf < 2; ++mf)
#pragma unroll
      for (int r = 0; r < 4; ++r) {
        const int qrow = mf * 16 + (lg << 2) + r;
        const float m1 = comb[qrow][64], l1 = comb[qrow][65];
        const float m0v = mold[mf][r], l0 = lsum[mf][r];
        const float ms = fmaxf(m0v, m1);
        const float f0 = __expf(m0v - ms), f1 = __expf(m1 - ms);
        const float inv = 1.f / (l0 * f0 + l1 * f1);
        const size_t orow = ((size_t)(b * SS) + qt * 32 + mf * 16 + (lg << 2) + r) * DD + h * DKK;
#pragma unroll
        for (int nf = 0; nf < 4; ++nf)
          Ob[orow + nf * 16 + lr] =
              f2bf((accO[mf][nf][r] * f0 + comb[qrow][nf * 16 + lr] * f1) * inv);
      }
  }
}

// ---------------------------------------------------------------------------
// Cross-attention with fused Q-projection (scale folded into Q).
// ---------------------------------------------------------------------------
__global__ __launch_bounds__(128)
void attnx_kernel(const unsigned short* __restrict__ Hb,
                  const unsigned short* __restrict__ Wq,
                  const unsigned short* __restrict__ Kb,
                  const unsigned short* __restrict__ VbT,
                  unsigned short* __restrict__ Ob,
                  const float* __restrict__ maskadd)
{
  __shared__ unsigned short Kl[2][2][64 * 64];
  __shared__ unsigned short Vl[2][2][64 * 64];
  __shared__ char PC[9216];
  unsigned short* Pl = (unsigned short*)PC;
  float (*comb)[66] = (float(*)[66])PC;
  unsigned short* QA = &Kl[0][0][0];
  unsigned short* QB = &Vl[0][0][0];
  unsigned short* Ql = (unsigned short*)PC;

  const int tid = threadIdx.x;
  const int l = tid & 63, w = tid >> 6;
  const int qt = blockIdx.x, h = blockIdx.y, b = blockIdx.z;
  const int lr = l & 15, lg = l >> 4;

  {
    const unsigned short* Abase = Hb + ((size_t)(b * SS) + qt * 32) * DD;
    const unsigned short* Bbase = Wq + (size_t)(h * DKK) * DD;
    auto stage_q = [&](int buf, int kt) {
      const int k0 = kt << 6;
#pragma unroll
      for (int j = 0; j < 2; ++j) {
        const int ti = j * 128 + tid;
        const int row = ti >> 3;
        const int ch = (ti & 7) ^ (row & 7);
        gl_lds16(Abase + (size_t)row * DD + k0 + ch * 8, &QA[buf * 2048 + ti * 8]);
      }
#pragma unroll
      for (int j = 0; j < 4; ++j) {
        const int ti = j * 128 + tid;
        const int row = ti >> 3;
        const int ch = (ti & 7) ^ (row & 7);
        gl_lds16(Bbase + (size_t)row * DD + k0 + ch * 8, &QB[buf * 4096 + ti * 8]);
      }
    };
    f32x4 qacc[2][2];
    const f32x4 zf = {0.f, 0.f, 0.f, 0.f};
#pragma unroll
    for (int i = 0; i < 2; ++i)
#pragma unroll
      for (int j = 0; j < 2; ++j) qacc[i][j] = zf;

    stage_q(0, 0);
    for (int kt = 0; kt < 8; ++kt) {
      if (kt + 1 < 8) {
        stage_q((kt + 1) & 1, kt + 1);
        asm volatile("s_waitcnt vmcnt(6)" ::: "memory");
      } else {
        asm volatile("s_waitcnt vmcnt(0)" ::: "memory");
      }
      __builtin_amdgcn_s_barrier();
      const unsigned short* qa = &QA[(kt & 1) * 2048];
      const unsigned short* qbuf = &QB[(kt & 1) * 4096];
#pragma unroll
      for (int ks = 0; ks < 2; ++ks) {
        bf16x8 af[2], bfv[2];
#pragma unroll
        for (int mf = 0; mf < 2; ++mf)
          af[mf] = ldfrag_swz(qa, mf * 16 + lr, ks * 32 + lg * 8);
#pragma unroll
        for (int nf = 0; nf < 2; ++nf)
          bfv[nf] = ldfrag_swz(qbuf, w * 32 + nf * 16 + lr, ks * 32 + lg * 8);
#pragma unroll
        for (int mf = 0; mf < 2; ++mf)
#pragma unroll
          for (int nf = 0; nf < 2; ++nf)
            qacc[mf][nf] = __builtin_amdgcn_mfma_f32_16x16x32_bf16(af[mf], bfv[nf], qacc[mf][nf], 0, 0, 0);
      }
      __builtin_amdgcn_s_barrier();
    }
#pragma unroll
    for (int mf = 0; mf < 2; ++mf)
#pragma unroll
      for (int nf = 0; nf < 2; ++nf)
#pragma unroll
        for (int r = 0; r < 4; ++r)
          Ql[(mf * 16 + (lg << 2) + r) * 72 + w * 32 + nf * 16 + lr] = f2bf(qacc[mf][nf][r] * 0.125f);
    __syncthreads();
  }
  bf16x8 qf[2][2];
#pragma unroll
  for (int mf = 0; mf < 2; ++mf) {
    qf[mf][0] = ldfrag(&Ql[(mf * 16 + lr) * 72 + (lg << 3)]);
    qf[mf][1] = ldfrag(&Ql[(mf * 16 + lr) * 72 + 32 + (lg << 3)]);
  }
  __syncthreads();

  const unsigned short* Kbase = Kb + (size_t)(b * SS) * DD + h * DKK;
  const unsigned short* Vbase = VbT + ((size_t)(b * HH) + h) * DKK * SS;

  auto stage = [&](int buf, int kt) {
#pragma unroll
    for (int j = 0; j < 8; ++j) {
      const int ti = j * 64 + l;
      const int row = ti >> 3;
      const int ch = (ti & 7) ^ (row & 7);
      gl_lds16(Kbase + (size_t)(kt * 64 + row) * DD + ch * 8, &Kl[w][buf][ti * 8]);
    }
#pragma unroll
    for (int j = 0; j < 8; ++j) {
      const int ti = j * 64 + l;
      const int row = ti >> 3;
      const int ch = (ti & 7) ^ (row & 7);
      gl_lds16(Vbase + (size_t)row * SS + kt * 64 + ch * 8, &Vl[w][buf][ti * 8]);
    }
  };

  f32x4 accO[2][4];
  const f32x4 zf = {0.f, 0.f, 0.f, 0.f};
#pragma unroll
  for (int mf = 0; mf < 2; ++mf)
#pragma unroll
    for (int nf = 0; nf < 4; ++nf) accO[mf][nf] = zf;
  float mold[2][4], lsum[2][4];
#pragma unroll
  for (int mf = 0; mf < 2; ++mf)
#pragma unroll
    for (int r = 0; r < 4; ++r) { mold[mf][r] = -1e30f; lsum[mf][r] = 0.f; }

  const int myn = (SS / 64 - w + 1) >> 1;
  stage(0, w);
  int buf = 0;

  for (int i = 0; i < myn; ++i) {
    const int kt = w + 2 * i;
    if (i + 1 < myn) {
      stage(buf ^ 1, kt + 2);
      asm volatile("s_waitcnt vmcnt(16)" ::: "memory");
    } else {
      asm volatile("s_waitcnt vmcnt(0)" ::: "memory");
    }
    const unsigned short* KB = &Kl[w][buf][0];
    const unsigned short* VB = &Vl[w][buf][0];
    float sc[2][4][4];
    __builtin_amdgcn_s_setprio(1);
#pragma unroll
    for (int nf = 0; nf < 4; ++nf) {
      bf16x8 k0 = ldfrag_swz(KB, nf * 16 + lr, lg * 8);
      bf16x8 k1 = ldfrag_swz(KB, nf * 16 + lr, 32 + lg * 8);
      const int kglob = kt * 64 + nf * 16 + lr;
      const float madd = maskadd[b * SS + kglob];
#pragma unroll
      for (int mf = 0; mf < 2; ++mf) {
        f32x4 s = zf;
        s = __builtin_amdgcn_mfma_f32_16x16x32_bf16(qf[mf][0], k0, s, 0, 0, 0);
        s = __builtin_amdgcn_mfma_f32_16x16x32_bf16(qf[mf][1], k1, s, 0, 0, 0);
#pragma unroll
        for (int r = 0; r < 4; ++r)
          sc[mf][nf][r] = s[r] + madd;
      }
    }
    __builtin_amdgcn_s_setprio(0);
#pragma unroll
    for (int mf = 0; mf < 2; ++mf)
#pragma unroll
      for (int r = 0; r < 4; ++r) {
        float mloc = fmaxf(fmaxf(sc[mf][0][r], sc[mf][1][r]), fmaxf(sc[mf][2][r], sc[mf][3][r]));
#pragma unroll
        for (int off = 1; off < 16; off <<= 1)
          mloc = fmaxf(mloc, __shfl_xor(mloc, off, 64));
        const float mnew = fmaxf(mold[mf][r], mloc);
        const float corr = __expf(mold[mf][r] - mnew);
        float ps = 0.f;
#pragma unroll
        for (int nf = 0; nf < 4; ++nf) {
          const float pv = __expf(sc[mf][nf][r] - mnew);
          sc[mf][nf][r] = pv;
          ps += pv;
        }
#pragma unroll
        for (int off = 1; off < 16; off <<= 1)
          ps += __shfl_xor(ps, off, 64);
        lsum[mf][r] = lsum[mf][r] * corr + ps;
#pragma unroll
        for (int nf = 0; nf < 4; ++nf) accO[mf][nf][r] *= corr;
        mold[mf][r] = mnew;
      }
    unsigned short* pw = Pl + w * 32 * 72;
#pragma unroll
    for (int mf = 0; mf < 2; ++mf)
#pragma unroll
      for (int nf = 0; nf < 4; ++nf)
#pragma unroll
        for (int r = 0; r < 4; ++r)
          pw[(mf * 16 + (lg << 2) + r) * 72 + nf * 16 + lr] = f2bf(sc[mf][nf][r]);
    bf16x8 pa[2][2];
#pragma unroll
    for (int mf = 0; mf < 2; ++mf) {
      pa[mf][0] = ldfrag(&pw[(mf * 16 + lr) * 72 + (lg << 3)]);
      pa[mf][1] = ldfrag(&pw[(mf * 16 + lr) * 72 + 32 + (lg << 3)]);
    }
    __builtin_amdgcn_s_setprio(1);
#pragma unroll
    for (int nf = 0; nf < 4; ++nf) {
      bf16x8 v0 = ldfrag_swz(VB, nf * 16 + lr, lg * 8);
      bf16x8 v1 = ldfrag_swz(VB, nf * 16 + lr, 32 + lg * 8);
#pragma unroll
      for (int mf = 0; mf < 2; ++mf) {
        accO[mf][nf] = __builtin_amdgcn_mfma_f32_16x16x32_bf16(pa[mf][0], v0, accO[mf][nf], 0, 0, 0);
        accO[mf][nf] = __builtin_amdgcn_mfma_f32_16x16x32_bf16(pa[mf][1], v1, accO[mf][nf], 0, 0, 0);
      }
    }
    __builtin_amdgcn_s_setprio(0);
    buf ^= 1;
  }

  __syncthreads();
  if (w == 1) {
#pragma unroll
    for (int mf = 0; mf < 2; ++mf)
#pragma unroll
      for (int r = 0; r < 4; ++r) {
        const int qrow = mf * 16 + (lg << 2) + r;
#pragma unroll
        for (int nf = 0; nf < 4; ++nf)
          comb[qrow][nf * 16 + lr] = accO[mf][nf][r];
        if (lr == 0) { comb[qrow][64] = mold[mf][r]; comb[qrow][65] = lsum[mf][r]; }
      }
  }
  __syncthreads();
  if (w == 0) {
#pragma unroll
    for (int mf = 0; mf < 2; ++mf)
#pragma unroll
      for (int r = 0; r < 4; ++r) {
        const int qrow = mf * 16 + (lg << 2) + r;
        const float m1 = comb[qrow][64], l1 = comb[qrow][65];
        const float m0v = mold[mf][r], l0 = lsum[mf][r];
        const float ms = fmaxf(m0v, m1);
        const float f0 = __expf(m0v - ms), f1 = __expf(m1 - ms);
        const float inv = 1.f / (l0 * f0 + l1 * f1);
        const size_t orow = ((size_t)(b * SS) + qt * 32 + mf * 16 + (lg << 2) + r) * DD + h * DKK;
#pragma unroll
        for (int nf = 0; nf < 4; ++nf)
          Ob[orow + nf * 16 + lr] =
              f2bf((accO[mf][nf][r] * f0 + comb[qrow][nf * 16 + lr] * f1) * inv);
      }
  }
}

// ---------------------------------------------------------------------------
// out = LN(a + sum_p c_p); 4 rows per block
// ---------------------------------------------------------------------------
template<int P>
__global__ __launch_bounds__(256)
void addln_kernel(const float* __restrict__ a, const float* __restrict__ c,
                  const float* __restrict__ g, const float* __restrict__ bb,
                  float* __restrict__ hf, unsigned short* __restrict__ hb)
{
  const int row = blockIdx.x * 4 + (threadIdx.x >> 6);
  const int l = threadIdx.x & 63;
  const float* ar = a + (size_t)row * DD + l * 8;
  f32x4 x0 = *(const f32x4*)ar;
  f32x4 x1 = *(const f32x4*)(ar + 4);
#pragma unroll
  for (int pp = 0; pp < P; ++pp) {
    const float* cr = c + (size_t)pp * MM * DD + (size_t)row * DD + l * 8;
    x0 += *(const f32x4*)cr;
    x1 += *(const f32x4*)(cr + 4);
  }
  float sum = x0[0] + x0[1] + x0[2] + x0[3] + x1[0] + x1[1] + x1[2] + x1[3];
#pragma unroll
  for (int off = 1; off < 64; off <<= 1) sum += __shfl_xor(sum, off, 64);
  const float mean = sum * (1.f / 512.f);
  float vs = 0.f;
#pragma unroll
  for (int j = 0; j < 4; ++j) { float d0 = x0[j] - mean; float d1 = x1[j] - mean; vs += d0 * d0 + d1 * d1; }
#pragma unroll
  for (int off = 1; off < 64; off <<= 1) vs += __shfl_xor(vs, off, 64);
  const float rs = rsqrtf(vs * (1.f / 512.f) + 1e-6f);
  const f32x4 g0 = *(const f32x4*)(g + l * 8), g1 = *(const f32x4*)(g + l * 8 + 4);
  const f32x4 b0 = *(const f32x4*)(bb + l * 8), b1 = *(const f32x4*)(bb + l * 8 + 4);
  f32x4 o0, o1;
  us8 ob;
#pragma unroll
  for (int j = 0; j < 4; ++j) {
    o0[j] = (x0[j] - mean) * rs * g0[j] + b0[j];
    o1[j] = (x1[j] - mean) * rs * g1[j] + b1[j];
    ob[j] = f2bf(o0[j]); ob[j + 4] = f2bf(o1[j]);
  }
  float* of = hf + (size_t)row * DD + l * 8;
  *(f32x4*)of = o0; *(f32x4*)(of + 4) = o1;
  *(us8*)(hb + (size_t)row * DD + l * 8) = ob;
}

// ---------------------------------------------------------------------------
// Mega prologue: prep (11264 blocks) + wconv8 (3072) + wconv jobs (rest)
// ---------------------------------------------------------------------------
struct ProP {
  const float *dec_in, *prev, *gk;
  unsigned short *decb, *prevb, *tabT, *Mb;
  float *kvs, *kve;
  const float* W8[8]; unsigned short* WT8[8];
  const float* W[8]; unsigned short* WT[8];
  int K[8], N[8], Kp[8], Np[8], nbx[8], nby[8];
  int off[9];
};

__global__ __launch_bounds__(256)
void prologue_all(ProP p)
{
  __shared__ float t[64][65];
  const int bid = blockIdx.x, tid = threadIdx.x;
  if (bid < 1024) {
    const int isdec = bid < 512;
    const int row = (isdec ? bid : bid - 512) * 4 + (tid >> 6);
    const int l = tid & 63;
    const int NC = isdec ? VV : DD, NP = isdec ? VP : DD;
    const float* xr = (isdec ? p.dec_in : p.prev) + (size_t)row * NC;
    unsigned short* ob = (isdec ? p.decb : p.prevb) + (size_t)row * NP;
    int ok = 1;
    for (int j = l; j < NP; j += 64) {
      if (j < NC) {
        const float v = xr[j];
        ok &= (v != -1.0f) ? 1 : 0;
        ob[j] = f2bf(v);
      } else ob[j] = 0;
    }
    ok = __all(ok) ? 1 : 0;
    if (l == 0) (isdec ? p.kvs : p.kve)[row] = ok ? 0.f : -1e9f;
  } else if (bid < 3072) {
    const int i = (bid - 1024) * 256 + tid;
    const int d = i >> 10, s = i & 1023;
    const float ex = (float)(2 * (d >> 1)) * (1.0f / (float)DD);
    const float ang = (float)s * exp2f(ex * -13.287712379549449f);
    p.tabT[i] = f2bf((d & 1) ? cosf(ang) : sinf(ang));
  } else if (bid < 11264) {
    const int i = (bid - 3072) * 256 + tid;
    const int b = i / (SS * SS);
    const int rem = i - b * (SS * SS);
    const float* q = p.gk + (size_t)b * 3 * SS * SS + rem;
    p.Mb[i] = f2bf((q[0] + 0.9f * q[SS * SS] + 0.81f * q[2 * SS * SS]) * (1.0f / 2.71f));
  } else if (bid < 11264 + 3072) {
    const int idx = bid - 11264;
    const int z = idx >> 6;
    const int rem = idx & 63;
    const int by = rem >> 3, bx = rem & 7;
    const int wi = z / LL, li = z - wi * LL;
    const float* Wl = p.W8[wi] + (size_t)li * DD * DD;
    unsigned short* WTl = p.WT8[wi] + (size_t)li * DD * DD;
    const int n0 = bx << 6, k0 = by << 6;
    const int cx = tid & 63, ry = tid >> 6;
#pragma unroll
    for (int i = 0; i < 16; ++i)
      t[ry + i * 4][cx] = Wl[(size_t)(k0 + ry + i * 4) * DD + n0 + cx];
    __syncthreads();
#pragma unroll
    for (int i = 0; i < 16; ++i)
      WTl[(size_t)(n0 + ry + i * 4) * DD + k0 + cx] = f2bf(t[cx][ry + i * 4]);
  } else {
    const int bid2 = bid - 11264 - 3072;
    int j = 0;
#pragma unroll
    for (int i = 0; i < 8; ++i) if (bid2 >= p.off[i + 1]) j = i + 1;
    const int local = bid2 - p.off[j];
    const int per = p.nbx[j] * p.nby[j];
    const int z = local / per;
    const int rem = local - z * per;
    const int by = rem / p.nbx[j];
    const int bx = rem - by * p.nbx[j];
    const int K = p.K[j], N = p.N[j], Kp = p.Kp[j], Np = p.Np[j];
    const float* Wl = p.W[j] + (size_t)z * K * N;
    unsigned short* WTl = p.WT[j] + (size_t)z * Np * Kp;
    const int n0 = bx << 6, k0 = by << 6;
    const int cx = tid & 63, ry = tid >> 6;
#pragma unroll
    for (int i = 0; i < 16; ++i) {
      const int kk = k0 + ry + i * 4, nn = n0 + cx;
      t[ry + i * 4][cx] = (kk < K && nn < N) ? Wl[(size_t)kk * N + nn] : 0.f;
    }
    __syncthreads();
#pragma unroll
    for (int i = 0; i < 16; ++i) {
      const int nn = n0 + ry + i * 4, kk = k0 + cx;
      if (nn < Np && kk < Kp) WTl[(size_t)nn * Kp + kk] = f2bf(t[cx][ry + i * 4]);
    }
  }
}

// f32-out GEMM with Nreal guard (emb/head)
__global__ __launch_bounds__(256)
void gemm_f32(GemmP p)
{
  __shared__ unsigned short Al[3 * 4096];
  __shared__ unsigned short Bl[3 * 4096];
  const int tid = threadIdx.x;
  const int l = tid & 63, w = tid >> 6;
  const int wm = w >> 1, wn = w & 1;
  const int lr = l & 15, lg = l >> 4;
  const int m0 = blockIdx.y << 6, n0 = blockIdx.x << 6;

  f32x4 acc[2][2];
  const f32x4 zf = {0.f, 0.f, 0.f, 0.f};
#pragma unroll
  for (int i = 0; i < 2; ++i)
#pragma unroll
    for (int j = 0; j < 2; ++j) acc[i][j] = zf;

  const size_t Kp = (size_t)p.Kp;
  const unsigned short* Abase = p.A + (size_t)m0 * Kp;
  const unsigned short* Bbase = p.B0 + (size_t)n0 * Kp;
  const int nt = p.Kp >> 6;

  auto stage = [&](int buf, int kt) {
    const int k0 = kt << 6;
#pragma unroll
    for (int j = 0; j < 2; ++j) {
      const int ti = j * 256 + tid;
      const int row = ti >> 3;
      const int ch = (ti & 7) ^ (row & 7);
      gl_lds16(Abase + (size_t)row * Kp + k0 + ch * 8, &Al[buf * 4096 + ti * 8]);
    }
#pragma unroll
    for (int j = 0; j < 2; ++j) {
      const int ti = j * 256 + tid;
      const int row = ti >> 3;
      const int ch = (ti & 7) ^ (row & 7);
      gl_lds16(Bbase + (size_t)row * Kp + k0 + ch * 8, &Bl[buf * 4096 + ti * 8]);
    }
  };
  stage(0, 0);
  if (nt > 1) stage(1, 1);
  int cb = 0, sb = 2;
  for (int kt = 0; kt < nt; ++kt) {
    if (kt + 1 < nt) asm volatile("s_waitcnt vmcnt(4)" ::: "memory");
    else             asm volatile("s_waitcnt vmcnt(0)" ::: "memory");
    __builtin_amdgcn_s_barrier();
    if (kt + 2 < nt) { stage(sb, kt + 2); sb = rot3(sb); }
#pragma unroll
    for (int ks = 0; ks < 2; ++ks) {
      bf16x8 af[2], bfv[2];
#pragma unroll
      for (int mf = 0; mf < 2; ++mf)
        af[mf] = ldfrag_swz(Al + cb * 4096, wm * 32 + mf * 16 + lr, ks * 32 + lg * 8);
#pragma unroll
      for (int nf = 0; nf < 2; ++nf)
        bfv[nf] = ldfrag_swz(Bl + cb * 4096, wn * 32 + nf * 16 + lr, ks * 32 + lg * 8);
#pragma unroll
      for (int mf = 0; mf < 2; ++mf)
#pragma unroll
        for (int nf = 0; nf < 2; ++nf)
          acc[mf][nf] = __builtin_amdgcn_mfma_f32_16x16x32_bf16(af[mf], bfv[nf], acc[mf][nf], 0, 0, 0);
    }
    cb = rot3(cb);
  }
#pragma unroll
  for (int mf = 0; mf < 2; ++mf) {
#pragma unroll
    for (int r = 0; r < 4; ++r) {
      const int grow = m0 + wm * 32 + mf * 16 + (lg << 2) + r;
#pragma unroll
      for (int nf = 0; nf < 2; ++nf) {
        const int gcol = n0 + wn * 32 + nf * 16 + lr;
        float v = acc[mf][nf][r];
        if (p.bias && gcol < p.Nreal) v += p.bias[gcol];
        if (p.relu) v = fmaxf(v, 0.f);
        if (p.D0) p.D0[(size_t)grow * p.Np + gcol] = f2bf(v);
        if (p.C && gcol < p.Nreal) p.C[(size_t)grow * p.ldc + gcol] = v;
      }
    }
  }
}

// ---------------------------------------------------------------------------
static inline void g1(hipStream_t s, const unsigned short* A, const unsigned short* B,
                      const float* bias, float* C, unsigned short* D,
                      int Kp, int Np, int ldc, int Nreal, int relu)
{
  GemmP p{};
  p.A = A; p.B0 = B; p.bias = bias; p.C = C; p.D0 = D;
  p.Kp = Kp; p.Np = Np; p.ldc = ldc; p.Nreal = Nreal; p.relu = relu;
  gemm_f32<<<dim3(Np >> 6, MM >> 6), 256, 0, s>>>(p);
}

static inline void g1w(hipStream_t s, const unsigned short* A, const unsigned short* B,
                       const float* bias, unsigned short* D, int Kp, int Np, int relu)
{
  GemmP p{};
  p.A = A; p.B0 = B; p.bias = bias; p.D0 = D;
  p.Kp = Kp; p.Np = Np; p.ldc = Np; p.Nreal = Np; p.relu = relu;
  gemm_tpl<1, 128, 0, 1><<<dim3(Np >> 7, MM >> 6), 256, 0, s>>>(p);
}

template<int KS>
static inline void g1k(hipStream_t s, const unsigned short* A, const unsigned short* B,
                       const float* bias, float* C, int Kp)
{
  GemmP p{};
  p.A = A; p.B0 = B; p.bias = bias; p.C = C;
  p.Kp = Kp; p.Np = DD; p.ldc = DD; p.Nreal = DD; p.relu = 0;
  gemm_tpl<1, 64, 0, KS><<<dim3(DD >> 6, MM >> 6, KS), 256, 0, s>>>(p);
}

static inline void g3t(hipStream_t s, const unsigned short* A, const unsigned short* B0,
                       const unsigned short* B1, const unsigned short* B2,
                       unsigned short* D0, unsigned short* D1, unsigned short* D2T)
{
  GemmP p{};
  p.A = A; p.B0 = B0; p.B1 = B1; p.B2 = B2; p.D0 = D0; p.D1 = D1; p.D2 = D2T;
  p.Kp = DD; p.Np = DD; p.ldc = DD; p.Nreal = DD; p.relu = 0;
  gemm_tpl<3, 64, 1, 1><<<dim3(3 * (DD >> 6), MM >> 6), 256, 0, s>>>(p);
}

static inline void grl(hipStream_t s, const unsigned short* A, const unsigned short* B,
                       const float* resid, const float* gamma, const float* beta,
                       float* hfout, unsigned short* hbout, int Kp)
{
  RowLnP p{};
  p.A = A; p.B = B; p.resid = resid; p.gamma = gamma; p.beta = beta;
  p.hfout = hfout; p.hbout = hbout; p.Kp = Kp;
  gemm_rowln<<<32, 256, 0, s>>>(p);
}

extern "C" void kernel_launch(void* const* d_in, const int* in_sizes, int n_in,
                              void* d_out, int out_size, void* d_ws, size_t ws_size,
                              hipStream_t stream)
{
  (void)in_sizes; (void)n_in; (void)out_size; (void)ws_size;
  const float* dec_in = (const float*)d_in[0];
  const float* prev   = (const float*)d_in[1];
  const float* gk     = (const float*)d_in[6];
  const float* emb_w1 = (const float*)d_in[7];
  const float* emb_b1 = (const float*)d_in[8];
  const float* emb_w2 = (const float*)d_in[9];
  const float* emb_b2 = (const float*)d_in[10];
  const float* emb_w3 = (const float*)d_in[11];
  const float* emb_b3 = (const float*)d_in[12];
  const float* ln0_g  = (const float*)d_in[13];
  const float* ln0_b  = (const float*)d_in[14];
  const float* wq     = (const float*)d_in[15];
  const float* wk     = (const float*)d_in[16];
  const float* wv     = (const float*)d_in[17];
  const float* wo     = (const float*)d_in[18];
  const float* cq     = (const float*)d_in[19];
  const float* ck     = (const float*)d_in[20];
  const float* cv     = (const float*)d_in[21];
  const float* co     = (const float*)d_in[22];
  const float* ffn_w1 = (const float*)d_in[23];
  const float* ffn_w2 = (const float*)d_in[24];
  const float* ffn_b1 = (const float*)d_in[25];
  const float* ffn_b2 = (const float*)d_in[26];
  const float* ln1_g  = (const float*)d_in[27];
  const float* ln1_b  = (const float*)d_in[28];
  const float* ln2_g  = (const float*)d_in[29];
  const float* ln2_b  = (const float*)d_in[30];
  const float* ln3_g  = (const float*)d_in[31];
  const float* ln3_b  = (const float*)d_in[32];
  const float* p_w1   = (const float*)d_in[33];
  const float* p_b1   = (const float*)d_in[34];
  const float* p_w2   = (const float*)d_in[35];
  const float* p_b2   = (const float*)d_in[36];
  const float* p_w3   = (const float*)d_in[37];
  const float* p_b3   = (const float*)d_in[38];

  // ---- workspace carve ----
  char* wsp = (char*)d_ws;
  auto carve = [&](size_t bytes) { char* r = wsp; wsp += (bytes + 255) & ~(size_t)255; return r; };

  unsigned short* decb  = (unsigned short*)carve((size_t)MM * VP * 2);
  unsigned short* prevb = (unsigned short*)carve((size_t)MM * DD * 2);
  float*          hf    = (float*)carve((size_t)MM * DD * 4);
  unsigned short* hb    = (unsigned short*)carve((size_t)MM * DD * 2);
  float*          xf1   = (float*)carve((size_t)MM * DD * 4);
  unsigned short* tb1   = (unsigned short*)carve((size_t)MM * DFFN * 2);   // 8 MB
  unsigned short* Mbb   = tb1;                                   // alias: first 4 MB
  unsigned short* tb2a  = (unsigned short*)carve((size_t)MM * VP * 2);
  unsigned short* tb2b  = (unsigned short*)carve((size_t)MM * VP * 2);
  unsigned short* qb    = (unsigned short*)carve((size_t)MM * DD * 2);
  unsigned short* kb    = (unsigned short*)carve((size_t)MM * DD * 2);
  unsigned short* vbT   = (unsigned short*)carve((size_t)MM * DD * 2);
  float* kvs = (float*)carve((size_t)MM * 4);
  float* kve = (float*)carve((size_t)MM * 4);
  unsigned short* postabt = (unsigned short*)carve((size_t)DD * SS * 2);
  unsigned short* ew1t  = (unsigned short*)carve((size_t)VP * VP * 2);
  unsigned short* ew2t  = (unsigned short*)carve((size_t)VP * VP * 2);
  unsigned short* ew3t  = (unsigned short*)carve((size_t)DD * VP * 2);
  unsigned short* wqt   = (unsigned short*)carve((size_t)LL * DD * DD * 2);
  unsigned short* wkt   = (unsigned short*)carve((size_t)LL * DD * DD * 2);
  unsigned short* wvt   = (unsigned short*)carve((size_t)LL * DD * DD * 2);
  unsigned short* wot   = (unsigned short*)carve((size_t)LL * DD * DD * 2);
  unsigned short* cqt   = (unsigned short*)carve((size_t)LL * DD * DD * 2);
  unsigned short* ckt   = (unsigned short*)carve((size_t)LL * DD * DD * 2);
  unsigned short* cvt   = (unsigned short*)carve((size_t)LL * DD * DD * 2);
  unsigned short* cot   = (unsigned short*)carve((size_t)LL * DD * DD * 2);
  unsigned short* f1t   = (unsigned short*)carve((size_t)LL * DFFN * DD * 2);
  unsigned short* f2t   = (unsigned short*)carve((size_t)LL * DD * DFFN * 2);
  unsigned short* p1t   = (unsigned short*)carve((size_t)VP * DD * 2);
  unsigned short* p2t   = (unsigned short*)carve((size_t)VP * VP * 2);
  unsigned short* p3t   = (unsigned short*)carve((size_t)VP * VP * 2);
  unsigned short* ckall = (unsigned short*)carve((size_t)LL * MM * DD * 2);  // 12 MB
  unsigned short* cvbT  = (unsigned short*)carve((size_t)LL * MM * DD * 2);  // 12 MB
  float*          xk4   = (float*)carve((size_t)4 * MM * DD * 4);            // 16 MB

  const dim3 agrid(SS / 32, HH, BB);

  // ---- mega prologue (1 launch) ----
  {
    ProP pp{};
    pp.dec_in = dec_in; pp.prev = prev; pp.gk = gk;
    pp.decb = decb; pp.prevb = prevb; pp.tabT = postabt; pp.Mb = Mbb;
    pp.kvs = kvs; pp.kve = kve;
    const float* W8s[8] = {wq, wk, wv, wo, cq, ck, cv, co};
    unsigned short* WT8s[8] = {wqt, wkt, wvt, wot, cqt, ckt, cvt, cot};
    for (int i = 0; i < 8; ++i) { pp.W8[i] = W8s[i]; pp.WT8[i] = WT8s[i]; }
    const float* Ws[8]    = {emb_w1, emb_w2, emb_w3, ffn_w1, ffn_w2, p_w1, p_w2, p_w3};
    unsigned short* Ds[8] = {ew1t, ew2t, ew3t, f1t, f2t, p1t, p2t, p3t};
    const int Ks[8]  = {VV, VV, VV, DD, DFFN, DD, VV, VV};
    const int Ns[8]  = {VV, VV, DD, DFFN, DD, VV, VV, VV};
    const int Kps[8] = {VP, VP, VP, DD, DFFN, DD, VP, VP};
    const int Nps[8] = {VP, VP, DD, DFFN, DD, VP, VP, VP};
    const int nls[8] = {1, 1, 1, LL, LL, 1, 1, 1};
    int off = 0;
    for (int j = 0; j < 8; ++j) {
      pp.W[j] = Ws[j]; pp.WT[j] = Ds[j];
      pp.K[j] = Ks[j]; pp.N[j] = Ns[j]; pp.Kp[j] = Kps[j]; pp.Np[j] = Nps[j];
      pp.nbx[j] = (Nps[j] + 63) / 64; pp.nby[j] = (Kps[j] + 63) / 64;
      pp.off[j] = off;
      off += pp.nbx[j] * pp.nby[j] * nls[j];
    }
    pp.off[8] = off;
    prologue_all<<<11264 + 3072 + off, 256, 0, stream>>>(pp);
  }

  // ---- cross-attention K/V for all layers ----
  {
    GemmBat p{};
    p.A = prevb; p.Kp = DD; p.Np = DD;
    for (int i = 0; i < LL; ++i) {
      p.B[2 * i]     = ckt + (size_t)i * DD * DD;
      p.B[2 * i + 1] = cvt + (size_t)i * DD * DD;
      p.D[2 * i]     = ckall + (size_t)i * MM * DD;
      p.D[2 * i + 1] = cvbT + (size_t)i * MM * DD;
    }
    gemm_bat<<<dim3(12 * (DD >> 6), MM >> 6), 256, 0, stream>>>(p);
  }

  // ---- embedding MLP + GPE (GPE GEMM+LN fused, K=1024) ----
  g1(stream, decb, ew1t, emb_b1, nullptr, tb2a, VP, VP, VP, VV, 1);
  g1(stream, tb2a, ew2t, emb_b2, nullptr, tb2b, VP, VP, VP, VV, 1);
  g1(stream, tb2b, ew3t, emb_b3, xf1, nullptr, VP, DD, DD, DD, 0);
  grl(stream, Mbb, postabt, xf1, ln0_g, ln0_b, hf, hb, SS);

  for (int i = 0; i < LL; ++i) {
    const size_t od = (size_t)i * DD * DD;
    // self attention (V written transposed by the QKV GEMM)
    g3t(stream, hb, wqt + od, wkt + od, wvt + od, qb, kb, vbT);
    attn_kernel<<<agrid, 128, 0, stream>>>(qb, kb, vbT, qb, kvs);
    grl(stream, qb, wot + od, hf, ln1_g + i * DD, ln1_b + i * DD, hf, hb, DD);
    // cross attention with fused Q-projection
    attnx_kernel<<<agrid, 128, 0, stream>>>(hb, cqt + od, ckall + (size_t)i * MM * DD,
                                            cvbT + (size_t)i * MM * DD, qb, kve);
    grl(stream, qb, cot + od, hf, ln2_g + i * DD, ln2_b + i * DD, hf, hb, DD);
    // FFN (split-K4 + addln)
    g1w(stream, hb, f1t + (size_t)i * DFFN * DD, ffn_b1 + i * DFFN, tb1, DD, DFFN, 1);
    g1k<4>(stream, tb1, f2t + (size_t)i * DD * DFFN, ffn_b2 + i * DD, xk4, DFFN);
    addln_kernel<4><<<MM / 4, 256, 0, stream>>>(hf, xk4, ln3_g + i * DD, ln3_b + i * DD, hf, hb);
  }

  // ---- output head ----
  g1(stream, hb, p1t, p_b1, nullptr, tb2a, DD, VP, VP, VV, 1);
  g1(stream, tb2a, p2t, p_b2, nullptr, tb2b, VP, VP, VP, VV, 1);
  g1(stream, tb2b, p3t, p_b3, (float*)d_out, nullptr, VP, VP, VV, VV, 0);
}

// Round 12
// 993.931 us; speedup vs baseline: 2.3580x; 2.3580x over previous
//
#include <hip/hip_runtime.h>
#include <hip/hip_bf16.h>
#include <stdint.h>

#define BB 2
#define SS 1024
#define VV 513
#define VP 576          // 513 padded to 9*64
#define DD 512
#define HH 8
#define DKK 64
#define DFFN 2048
#define LL 6
#define MM (BB * SS)    // 2048

typedef __bf16 bf16x8 __attribute__((ext_vector_type(8)));
typedef float f32x4 __attribute__((ext_vector_type(4)));
typedef unsigned short us8 __attribute__((ext_vector_type(8)));
typedef unsigned short us4 __attribute__((ext_vector_type(4)));

static __device__ inline unsigned short f2bf(float f) {
  union { float f; unsigned u; } v; v.f = f;
  unsigned u = v.u;
  unsigned r = (u + 0x7FFFu + ((u >> 16) & 1u)) >> 16;
  return (unsigned short)r;
}

static __device__ inline bf16x8 ldfrag(const unsigned short* p) {
  us8 r = *(const us8*)p;
  return __builtin_bit_cast(bf16x8, r);
}

typedef __attribute__((address_space(3))) void lds_void;
typedef const __attribute__((address_space(1))) void glb_void;
static __device__ inline void gl_lds16(const void* g, void* l) {
  __builtin_amdgcn_global_load_lds((glb_void*)g, (lds_void*)l, 16, 0, 0);
}

// swizzled LDS fragment read: tile rows are linear 128B, byte ^= (row&7)<<4
static __device__ inline bf16x8 ldfrag_swz(const unsigned short* base, int row, int kloc) {
  const unsigned byte = (unsigned)(row * 128 + kloc * 2) ^ (unsigned)((row & 7) << 4);
  return ldfrag((const unsigned short*)((const char*)base + byte));
}

static __device__ inline int rot3(int x) { return (x == 2) ? 0 : x + 1; }

// ---------------------------------------------------------------------------
// GEMM: C = A[M][Kp](bf16) * B^T, B stored [N][Kp] bf16 (padded).
// TRV: sel==2 output stored transposed into [b][h][dk][s].
// KS: split-K factor (grid.z); partials go to p.C + z*MM*ldc (f32).
// ---------------------------------------------------------------------------
struct GemmP {
  const unsigned short* A;
  const unsigned short* B0; const unsigned short* B1; const unsigned short* B2;
  const float* bias;
  float* C;
  unsigned short* D0; unsigned short* D1; unsigned short* D2;
  int Kp, Np, ldc, Nreal, relu;
};

template<int NB, int NT, int TRV, int KS>
__global__ __launch_bounds__(256)
void gemm_tpl(GemmP p)
{
  constexpr int FN = NT / 32;
  __shared__ unsigned short Al[3][64 * 64];
  __shared__ unsigned short Bl[3][NT * 64];
  const int tid = threadIdx.x;
  const int l = tid & 63, w = tid >> 6;
  const int wm = w >> 1, wn = w & 1;
  const int lr = l & 15, lg = l >> 4;

  const int nbn = p.Np / NT;
  int sel = 0, bx = blockIdx.x;
  if (NB > 1) { sel = bx / nbn; bx -= sel * nbn; }
  const unsigned short* Bmat = p.B0;
  if (NB > 1 && sel == 1) Bmat = p.B1;
  if (NB > 2 && sel == 2) Bmat = p.B2;
  const int m0 = blockIdx.y << 6, n0 = bx * NT;
  const int kz = (KS > 1) ? blockIdx.z : 0;

  f32x4 acc[2][FN];
  const f32x4 zf = {0.f, 0.f, 0.f, 0.f};
#pragma unroll
  for (int i = 0; i < 2; ++i)
#pragma unroll
    for (int j = 0; j < FN; ++j) acc[i][j] = zf;

  const size_t Kp = (size_t)p.Kp;
  const unsigned short* Abase = p.A + (size_t)m0 * Kp;
  const unsigned short* Bbase = Bmat + (size_t)n0 * Kp;
  const int nt = (p.Kp >> 6) / KS;
  const int kb0 = kz * nt;

  auto stage = [&](int buf, int kt) {
    const int k0 = (kb0 + kt) << 6;
#pragma unroll
    for (int j = 0; j < 2; ++j) {
      const int ti = j * 256 + tid;
      const int row = ti >> 3;
      const int ch = (ti & 7) ^ (row & 7);
      gl_lds16(Abase + (size_t)row * Kp + k0 + ch * 8, &Al[buf][ti * 8]);
    }
#pragma unroll
    for (int j = 0; j < FN; ++j) {
      const int ti = j * 256 + tid;
      const int row = ti >> 3;
      const int ch = (ti & 7) ^ (row & 7);
      gl_lds16(Bbase + (size_t)row * Kp + k0 + ch * 8, &Bl[buf][ti * 8]);
    }
  };

  stage(0, 0);
  if (nt > 1) stage(1, 1);
  int cb = 0, sb = 2;

  for (int kt = 0; kt < nt; ++kt) {
    if (kt + 1 < nt) {
      if constexpr (FN == 2) asm volatile("s_waitcnt vmcnt(4)" ::: "memory");
      else                   asm volatile("s_waitcnt vmcnt(6)" ::: "memory");
    } else {
      asm volatile("s_waitcnt vmcnt(0)" ::: "memory");
    }
    __builtin_amdgcn_s_barrier();
    if (kt + 2 < nt) { stage(sb, kt + 2); sb = rot3(sb); }
#pragma unroll
    for (int ks = 0; ks < 2; ++ks) {
      bf16x8 af[2], bfv[FN];
#pragma unroll
      for (int mf = 0; mf < 2; ++mf)
        af[mf] = ldfrag_swz(Al[cb], wm * 32 + mf * 16 + lr, ks * 32 + lg * 8);
#pragma unroll
      for (int nf = 0; nf < FN; ++nf)
        bfv[nf] = ldfrag_swz(Bl[cb], wn * (NT / 2) + nf * 16 + lr, ks * 32 + lg * 8);
#pragma unroll
      for (int mf = 0; mf < 2; ++mf)
#pragma unroll
        for (int nf = 0; nf < FN; ++nf)
          acc[mf][nf] = __builtin_amdgcn_mfma_f32_16x16x32_bf16(af[mf], bfv[nf], acc[mf][nf], 0, 0, 0);
    }
    cb = rot3(cb);
  }

  unsigned short* Dsel = p.D0;
  if (NB > 1 && sel == 1) Dsel = p.D1;
  if (NB > 2 && sel == 2) Dsel = p.D2;

  if (TRV && sel == 2) {
#pragma unroll
    for (int mf = 0; mf < 2; ++mf) {
      const int growb = m0 + wm * 32 + mf * 16 + (lg << 2);
      const int b = growb >> 10, s = growb & 1023;
#pragma unroll
      for (int nf = 0; nf < FN; ++nf) {
        const int gcol = n0 + wn * (NT / 2) + nf * 16 + lr;
        const int h = gcol >> 6, d = gcol & 63;
        us4 t;
#pragma unroll
        for (int r = 0; r < 4; ++r) t[r] = f2bf(acc[mf][nf][r]);
        *(us4*)(Dsel + (((size_t)(b * HH) + h) * DKK + d) * SS + s) = t;
      }
    }
    return;
  }

  float* Cz = p.C ? (p.C + (size_t)kz * MM * p.ldc) : nullptr;
#pragma unroll
  for (int mf = 0; mf < 2; ++mf) {
#pragma unroll
    for (int r = 0; r < 4; ++r) {
      const int grow = m0 + wm * 32 + mf * 16 + (lg << 2) + r;
#pragma unroll
      for (int nf = 0; nf < FN; ++nf) {
        const int gcol = n0 + wn * (NT / 2) + nf * 16 + lr;
        float v = acc[mf][nf][r];
        if (p.bias && kz == 0 && gcol < p.Nreal) v += p.bias[gcol];
        if (p.relu) v = fmaxf(v, 0.f);
        if (Dsel) Dsel[(size_t)grow * p.Np + gcol] = f2bf(v);
        if (Cz && gcol < p.Nreal) Cz[(size_t)grow * p.ldc + gcol] = v;
      }
    }
  }
}

// ---------------------------------------------------------------------------
// Batched GEMM over 12 (B,D) pairs sharing A. Np=Kp=512.
// Odd sel (V) stored transposed into [b][h][dk][s].
// ---------------------------------------------------------------------------
struct GemmBat {
  const unsigned short* A;
  const unsigned short* B[12];
  unsigned short* D[12];
  int Kp, Np;
};

__global__ __launch_bounds__(256)
void gemm_bat(GemmBat p)
{
  __shared__ unsigned short Al[3][64 * 64];
  __shared__ unsigned short Bl[3][64 * 64];
  const int tid = threadIdx.x;
  const int l = tid & 63, w = tid >> 6;
  const int wm = w >> 1, wn = w & 1;
  const int lr = l & 15, lg = l >> 4;

  const int nbn = p.Np >> 6;
  const int sel = blockIdx.x / nbn;
  const int bx = blockIdx.x - sel * nbn;
  const unsigned short* Bmat = p.B[sel];
  unsigned short* Dmat = p.D[sel];
  const int m0 = blockIdx.y << 6, n0 = bx << 6;

  f32x4 acc[2][2];
  const f32x4 zf = {0.f, 0.f, 0.f, 0.f};
#pragma unroll
  for (int i = 0; i < 2; ++i)
#pragma unroll
    for (int j = 0; j < 2; ++j) acc[i][j] = zf;

  const size_t Kp = (size_t)p.Kp;
  const unsigned short* Abase = p.A + (size_t)m0 * Kp;
  const unsigned short* Bbase = Bmat + (size_t)n0 * Kp;

  auto stage = [&](int buf, int kt) {
    const int k0 = kt << 6;
#pragma unroll
    for (int j = 0; j < 2; ++j) {
      const int ti = j * 256 + tid;
      const int row = ti >> 3;
      const int ch = (ti & 7) ^ (row & 7);
      gl_lds16(Abase + (size_t)row * Kp + k0 + ch * 8, &Al[buf][ti * 8]);
    }
#pragma unroll
    for (int j = 0; j < 2; ++j) {
      const int ti = j * 256 + tid;
      const int row = ti >> 3;
      const int ch = (ti & 7) ^ (row & 7);
      gl_lds16(Bbase + (size_t)row * Kp + k0 + ch * 8, &Bl[buf][ti * 8]);
    }
  };

  const int nt = p.Kp >> 6;
  stage(0, 0);
  if (nt > 1) stage(1, 1);
  int cb = 0, sb = 2;

  for (int kt = 0; kt < nt; ++kt) {
    if (kt + 1 < nt) asm volatile("s_waitcnt vmcnt(4)" ::: "memory");
    else             asm volatile("s_waitcnt vmcnt(0)" ::: "memory");
    __builtin_amdgcn_s_barrier();
    if (kt + 2 < nt) { stage(sb, kt + 2); sb = rot3(sb); }
#pragma unroll
    for (int ks = 0; ks < 2; ++ks) {
      bf16x8 af[2], bfv[2];
#pragma unroll
      for (int mf = 0; mf < 2; ++mf)
        af[mf] = ldfrag_swz(Al[cb], wm * 32 + mf * 16 + lr, ks * 32 + lg * 8);
#pragma unroll
      for (int nf = 0; nf < 2; ++nf)
        bfv[nf] = ldfrag_swz(Bl[cb], wn * 32 + nf * 16 + lr, ks * 32 + lg * 8);
#pragma unroll
      for (int mf = 0; mf < 2; ++mf)
#pragma unroll
        for (int nf = 0; nf < 2; ++nf)
          acc[mf][nf] = __builtin_amdgcn_mfma_f32_16x16x32_bf16(af[mf], bfv[nf], acc[mf][nf], 0, 0, 0);
    }
    cb = rot3(cb);
  }

  if (sel & 1) {
#pragma unroll
    for (int mf = 0; mf < 2; ++mf) {
      const int growb = m0 + wm * 32 + mf * 16 + (lg << 2);
      const int b = growb >> 10, s = growb & 1023;
#pragma unroll
      for (int nf = 0; nf < 2; ++nf) {
        const int gcol = n0 + wn * 32 + nf * 16 + lr;
        const int h = gcol >> 6, d = gcol & 63;
        us4 t;
#pragma unroll
        for (int r = 0; r < 4; ++r) t[r] = f2bf(acc[mf][nf][r]);
        *(us4*)(Dmat + (((size_t)(b * HH) + h) * DKK + d) * SS + s) = t;
      }
    }
    return;
  }

#pragma unroll
  for (int mf = 0; mf < 2; ++mf) {
#pragma unroll
    for (int r = 0; r < 4; ++r) {
      const int grow = m0 + wm * 32 + mf * 16 + (lg << 2) + r;
#pragma unroll
      for (int nf = 0; nf < 2; ++nf) {
        const int gcol = n0 + wn * 32 + nf * 16 + lr;
        Dmat[(size_t)grow * p.Np + gcol] = f2bf(acc[mf][nf][r]);
      }
    }
  }
}

// ---------------------------------------------------------------------------
// Self-attention (causal): QBLK=32, 2 waves split KV (wave w: tiles ≡w mod 2).
// Per-wave LDS double-buffer + per-wave vmcnt pipeline, no main-loop barriers.
// ---------------------------------------------------------------------------
__global__ __launch_bounds__(128)
void attn_kernel(const unsigned short* __restrict__ Qb,
                 const unsigned short* __restrict__ Kb,
                 const unsigned short* __restrict__ VbT,
                 unsigned short* __restrict__ Ob,
                 const float* __restrict__ maskadd)
{
  __shared__ unsigned short Kl[2][2][64 * 64];
  __shared__ unsigned short Vl[2][2][64 * 64];
  __shared__ char PC[9216];
  unsigned short* Pl = (unsigned short*)PC;
  float (*comb)[66] = (float(*)[66])PC;

  const int tid = threadIdx.x;
  const int l = tid & 63, w = tid >> 6;
  const int qt = blockIdx.x, h = blockIdx.y, b = blockIdx.z;
  const int lr = l & 15, lg = l >> 4;

  bf16x8 qf[2][2];
#pragma unroll
  for (int mf = 0; mf < 2; ++mf) {
    const unsigned short* qrow = Qb + ((size_t)(b * SS) + qt * 32 + mf * 16 + lr) * DD + h * DKK;
    qf[mf][0] = ldfrag(qrow + (lg << 3));
    qf[mf][1] = ldfrag(qrow + 32 + (lg << 3));
  }

  const unsigned short* Kbase = Kb + (size_t)(b * SS) * DD + h * DKK;
  const unsigned short* Vbase = VbT + ((size_t)(b * HH) + h) * DKK * SS;

  auto stage = [&](int buf, int kt) {
#pragma unroll
    for (int j = 0; j < 8; ++j) {
      const int ti = j * 64 + l;
      const int row = ti >> 3;
      const int ch = (ti & 7) ^ (row & 7);
      gl_lds16(Kbase + (size_t)(kt * 64 + row) * DD + ch * 8, &Kl[w][buf][ti * 8]);
    }
#pragma unroll
    for (int j = 0; j < 8; ++j) {
      const int ti = j * 64 + l;
      const int row = ti >> 3;
      const int ch = (ti & 7) ^ (row & 7);
      gl_lds16(Vbase + (size_t)row * SS + kt * 64 + ch * 8, &Vl[w][buf][ti * 8]);
    }
  };

  f32x4 accO[2][4];
  const f32x4 zf = {0.f, 0.f, 0.f, 0.f};
#pragma unroll
  for (int mf = 0; mf < 2; ++mf)
#pragma unroll
    for (int nf = 0; nf < 4; ++nf) accO[mf][nf] = zf;
  float mold[2][4], lsum[2][4];
#pragma unroll
  for (int mf = 0; mf < 2; ++mf)
#pragma unroll
    for (int r = 0; r < 4; ++r) { mold[mf][r] = -1e30f; lsum[mf][r] = 0.f; }

  const int ktmax = (qt >> 1) + 1;
  const int myn = (ktmax - w + 1) >> 1;

  if (myn > 0) stage(0, w);
  int buf = 0;

  for (int i = 0; i < myn; ++i) {
    const int kt = w + 2 * i;
    if (i + 1 < myn) {
      stage(buf ^ 1, kt + 2);
      asm volatile("s_waitcnt vmcnt(16)" ::: "memory");
    } else {
      asm volatile("s_waitcnt vmcnt(0)" ::: "memory");
    }
    const unsigned short* KB = &Kl[w][buf][0];
    const unsigned short* VB = &Vl[w][buf][0];
    float sc[2][4][4];
    __builtin_amdgcn_s_setprio(1);
#pragma unroll
    for (int nf = 0; nf < 4; ++nf) {
      bf16x8 k0 = ldfrag_swz(KB, nf * 16 + lr, lg * 8);
      bf16x8 k1 = ldfrag_swz(KB, nf * 16 + lr, 32 + lg * 8);
      const int kglob = kt * 64 + nf * 16 + lr;
      const float madd = maskadd[b * SS + kglob];
#pragma unroll
      for (int mf = 0; mf < 2; ++mf) {
        f32x4 s = zf;
        s = __builtin_amdgcn_mfma_f32_16x16x32_bf16(qf[mf][0], k0, s, 0, 0, 0);
        s = __builtin_amdgcn_mfma_f32_16x16x32_bf16(qf[mf][1], k1, s, 0, 0, 0);
#pragma unroll
        for (int r = 0; r < 4; ++r) {
          const int qglob = qt * 32 + mf * 16 + (lg << 2) + r;
          sc[mf][nf][r] = (kglob > qglob) ? -1e9f : s[r] * 0.125f + madd;
        }
      }
    }
    __builtin_amdgcn_s_setprio(0);
#pragma unroll
    for (int mf = 0; mf < 2; ++mf)
#pragma unroll
      for (int r = 0; r < 4; ++r) {
        float mloc = fmaxf(fmaxf(sc[mf][0][r], sc[mf][1][r]), fmaxf(sc[mf][2][r], sc[mf][3][r]));
#pragma unroll
        for (int off = 1; off < 16; off <<= 1)
          mloc = fmaxf(mloc, __shfl_xor(mloc, off, 64));
        const float mnew = fmaxf(mold[mf][r], mloc);
        const float corr = __expf(mold[mf][r] - mnew);
        float ps = 0.f;
#pragma unroll
        for (int nf = 0; nf < 4; ++nf) {
          const float pv = __expf(sc[mf][nf][r] - mnew);
          sc[mf][nf][r] = pv;
          ps += pv;
        }
#pragma unroll
        for (int off = 1; off < 16; off <<= 1)
          ps += __shfl_xor(ps, off, 64);
        lsum[mf][r] = lsum[mf][r] * corr + ps;
#pragma unroll
        for (int nf = 0; nf < 4; ++nf) accO[mf][nf][r] *= corr;
        mold[mf][r] = mnew;
      }
    unsigned short* pw = Pl + w * 32 * 72;
#pragma unroll
    for (int mf = 0; mf < 2; ++mf)
#pragma unroll
      for (int nf = 0; nf < 4; ++nf)
#pragma unroll
        for (int r = 0; r < 4; ++r)
          pw[(mf * 16 + (lg << 2) + r) * 72 + nf * 16 + lr] = f2bf(sc[mf][nf][r]);
    bf16x8 pa[2][2];
#pragma unroll
    for (int mf = 0; mf < 2; ++mf) {
      pa[mf][0] = ldfrag(&pw[(mf * 16 + lr) * 72 + (lg << 3)]);
      pa[mf][1] = ldfrag(&pw[(mf * 16 + lr) * 72 + 32 + (lg << 3)]);
    }
    __builtin_amdgcn_s_setprio(1);
#pragma unroll
    for (int nf = 0; nf < 4; ++nf) {
      bf16x8 v0 = ldfrag_swz(VB, nf * 16 + lr, lg * 8);
      bf16x8 v1 = ldfrag_swz(VB, nf * 16 + lr, 32 + lg * 8);
#pragma unroll
      for (int mf = 0; mf < 2; ++mf) {
        accO[mf][nf] = __builtin_amdgcn_mfma_f32_16x16x32_bf16(pa[mf][0], v0, accO[mf][nf], 0, 0, 0);
        accO[mf][nf] = __builtin_amdgcn_mfma_f32_16x16x32_bf16(pa[mf][1], v1, accO[mf][nf], 0, 0, 0);
      }
    }
    __builtin_amdgcn_s_setprio(0);
    buf ^= 1;
  }

  __syncthreads();
  if (w == 1) {
#pragma unroll
    for (int mf = 0; mf < 2; ++mf)
#pragma unroll
      for (int r = 0; r < 4; ++r) {
        const int qrow = mf * 16 + (lg << 2) + r;
#pragma unroll
        for (int nf = 0; nf < 4; ++nf)
          comb[qrow][nf * 16 + lr] = accO[mf][nf][r];
        if (lr == 0) { comb[qrow][64] = mold[mf][r]; comb[qrow][65] = lsum[mf][r]; }
      }
  }
  __syncthreads();
  if (w == 0) {
#pragma unroll
    for (int mf = 0; mf < 2; ++mf)
#pragma unroll
      for (int r = 0; r < 4; ++r) {
        const int qrow = mf * 16 + (lg << 2) + r;
        const float m1 = comb[qrow][64], l1 = comb[qrow][65];
        const float m0v = mold[mf][r], l0 = lsum[mf][r];
        const float ms = fmaxf(m0v, m1);
        const float f0 = __expf(m0v - ms), f1 = __expf(m1 - ms);
        const float inv = 1.f / (l0 * f0 + l1 * f1);
        const size_t orow = ((size_t)(b * SS) + qt * 32 + mf * 16 + (lg << 2) + r) * DD + h * DKK;
#pragma unroll
        for (int nf = 0; nf < 4; ++nf)
          Ob[orow + nf * 16 + lr] =
              f2bf((accO[mf][nf][r] * f0 + comb[qrow][nf * 16 + lr] * f1) * inv);
      }
  }
}

// ---------------------------------------------------------------------------
// Cross-attention with FUSED Q-projection: Q = hb[rows] @ Wq[head cols],
// scale 0.125 folded into Q (exact: power of 2). Then KV-split loop.
// Q-phase LDS aliases the K/V buffers (disjoint in time).
// ---------------------------------------------------------------------------
__global__ __launch_bounds__(128)
void attnx_kernel(const unsigned short* __restrict__ Hb,
                  const unsigned short* __restrict__ Wq,   // [512][512] layer slice
                  const unsigned short* __restrict__ Kb,
                  const unsigned short* __restrict__ VbT,
                  unsigned short* __restrict__ Ob,
                  const float* __restrict__ maskadd)
{
  __shared__ unsigned short Kl[2][2][64 * 64];
  __shared__ unsigned short Vl[2][2][64 * 64];
  __shared__ char PC[9216];
  unsigned short* Pl = (unsigned short*)PC;
  float (*comb)[66] = (float(*)[66])PC;
  unsigned short* QA = &Kl[0][0][0];     // 2 bufs x 2048 us (aliases Kl)
  unsigned short* QB = &Vl[0][0][0];     // 2 bufs x 4096 us (aliases Vl)
  unsigned short* Ql = (unsigned short*)PC;  // 32 x 72 us (aliases PC)

  const int tid = threadIdx.x;
  const int l = tid & 63, w = tid >> 6;
  const int qt = blockIdx.x, h = blockIdx.y, b = blockIdx.z;
  const int lr = l & 15, lg = l >> 4;

  // ---- Q-phase: 32x64 = hb[qt*32.., :] @ Wq[h*64.., :]^T ----
  {
    const unsigned short* Abase = Hb + ((size_t)(b * SS) + qt * 32) * DD;
    const unsigned short* Bbase = Wq + (size_t)(h * DKK) * DD;
    auto stage_q = [&](int buf, int kt) {
      const int k0 = kt << 6;
#pragma unroll
      for (int j = 0; j < 2; ++j) {
        const int ti = j * 128 + tid;
        const int row = ti >> 3;
        const int ch = (ti & 7) ^ (row & 7);
        gl_lds16(Abase + (size_t)row * DD + k0 + ch * 8, &QA[buf * 2048 + ti * 8]);
      }
#pragma unroll
      for (int j = 0; j < 4; ++j) {
        const int ti = j * 128 + tid;
        const int row = ti >> 3;
        const int ch = (ti & 7) ^ (row & 7);
        gl_lds16(Bbase + (size_t)row * DD + k0 + ch * 8, &QB[buf * 4096 + ti * 8]);
      }
    };
    f32x4 qacc[2][2];
    const f32x4 zf = {0.f, 0.f, 0.f, 0.f};
#pragma unroll
    for (int i = 0; i < 2; ++i)
#pragma unroll
      for (int j = 0; j < 2; ++j) qacc[i][j] = zf;

    stage_q(0, 0);
    for (int kt = 0; kt < 8; ++kt) {
      if (kt + 1 < 8) {
        stage_q((kt + 1) & 1, kt + 1);
        asm volatile("s_waitcnt vmcnt(6)" ::: "memory");
      } else {
        asm volatile("s_waitcnt vmcnt(0)" ::: "memory");
      }
      __builtin_amdgcn_s_barrier();
      const unsigned short* qa = &QA[(kt & 1) * 2048];
      const unsigned short* qbuf = &QB[(kt & 1) * 4096];
#pragma unroll
      for (int ks = 0; ks < 2; ++ks) {
        bf16x8 af[2], bfv[2];
#pragma unroll
        for (int mf = 0; mf < 2; ++mf)
          af[mf] = ldfrag_swz(qa, mf * 16 + lr, ks * 32 + lg * 8);
#pragma unroll
        for (int nf = 0; nf < 2; ++nf)
          bfv[nf] = ldfrag_swz(qbuf, w * 32 + nf * 16 + lr, ks * 32 + lg * 8);
#pragma unroll
        for (int mf = 0; mf < 2; ++mf)
#pragma unroll
          for (int nf = 0; nf < 2; ++nf)
            qacc[mf][nf] = __builtin_amdgcn_mfma_f32_16x16x32_bf16(af[mf], bfv[nf], qacc[mf][nf], 0, 0, 0);
      }
      __builtin_amdgcn_s_barrier();
    }
    // write Q (scaled) to LDS, then load per-lane fragments
#pragma unroll
    for (int mf = 0; mf < 2; ++mf)
#pragma unroll
      for (int nf = 0; nf < 2; ++nf)
#pragma unroll
        for (int r = 0; r < 4; ++r)
          Ql[(mf * 16 + (lg << 2) + r) * 72 + w * 32 + nf * 16 + lr] = f2bf(qacc[mf][nf][r] * 0.125f);
    __syncthreads();
  }
  bf16x8 qf[2][2];
#pragma unroll
  for (int mf = 0; mf < 2; ++mf) {
    qf[mf][0] = ldfrag(&Ql[(mf * 16 + lr) * 72 + (lg << 3)]);
    qf[mf][1] = ldfrag(&Ql[(mf * 16 + lr) * 72 + 32 + (lg << 3)]);
  }
  __syncthreads();

  // ---- KV loop (non-causal), per-wave split ----
  const unsigned short* Kbase = Kb + (size_t)(b * SS) * DD + h * DKK;
  const unsigned short* Vbase = VbT + ((size_t)(b * HH) + h) * DKK * SS;

  auto stage = [&](int buf, int kt) {
#pragma unroll
    for (int j = 0; j < 8; ++j) {
      const int ti = j * 64 + l;
      const int row = ti >> 3;
      const int ch = (ti & 7) ^ (row & 7);
      gl_lds16(Kbase + (size_t)(kt * 64 + row) * DD + ch * 8, &Kl[w][buf][ti * 8]);
    }
#pragma unroll
    for (int j = 0; j < 8; ++j) {
      const int ti = j * 64 + l;
      const int row = ti >> 3;
      const int ch = (ti & 7) ^ (row & 7);
      gl_lds16(Vbase + (size_t)row * SS + kt * 64 + ch * 8, &Vl[w][buf][ti * 8]);
    }
  };

  f32x4 accO[2][4];
  const f32x4 zf = {0.f, 0.f, 0.f, 0.f};
#pragma unroll
  for (int mf = 0; mf < 2; ++mf)
#pragma unroll
    for (int nf = 0; nf < 4; ++nf) accO[mf][nf] = zf;
  float mold[2][4], lsum[2][4];
#pragma unroll
  for (int mf = 0; mf < 2; ++mf)
#pragma unroll
    for (int r = 0; r < 4; ++r) { mold[mf][r] = -1e30f; lsum[mf][r] = 0.f; }

  const int myn = (SS / 64 - w + 1) >> 1;
  stage(0, w);
  int buf = 0;

  for (int i = 0; i < myn; ++i) {
    const int kt = w + 2 * i;
    if (i + 1 < myn) {
      stage(buf ^ 1, kt + 2);
      asm volatile("s_waitcnt vmcnt(16)" ::: "memory");
    } else {
      asm volatile("s_waitcnt vmcnt(0)" ::: "memory");
    }
    const unsigned short* KB = &Kl[w][buf][0];
    const unsigned short* VB = &Vl[w][buf][0];
    float sc[2][4][4];
    __builtin_amdgcn_s_setprio(1);
#pragma unroll
    for (int nf = 0; nf < 4; ++nf) {
      bf16x8 k0 = ldfrag_swz(KB, nf * 16 + lr, lg * 8);
      bf16x8 k1 = ldfrag_swz(KB, nf * 16 + lr, 32 + lg * 8);
      const int kglob = kt * 64 + nf * 16 + lr;
      const float madd = maskadd[b * SS + kglob];
#pragma unroll
      for (int mf = 0; mf < 2; ++mf) {
        f32x4 s = zf;
        s = __builtin_amdgcn_mfma_f32_16x16x32_bf16(qf[mf][0], k0, s, 0, 0, 0);
        s = __builtin_amdgcn_mfma_f32_16x16x32_bf16(qf[mf][1], k1, s, 0, 0, 0);
#pragma unroll
        for (int r = 0; r < 4; ++r)
          sc[mf][nf][r] = s[r] + madd;   // scale folded into Q
      }
    }
    __builtin_amdgcn_s_setprio(0);
#pragma unroll
    for (int mf = 0; mf < 2; ++mf)
#pragma unroll
      for (int r = 0; r < 4; ++r) {
        float mloc = fmaxf(fmaxf(sc[mf][0][r], sc[mf][1][r]), fmaxf(sc[mf][2][r], sc[mf][3][r]));
#pragma unroll
        for (int off = 1; off < 16; off <<= 1)
          mloc = fmaxf(mloc, __shfl_xor(mloc, off, 64));
        const float mnew = fmaxf(mold[mf][r], mloc);
        const float corr = __expf(mold[mf][r] - mnew);
        float ps = 0.f;
#pragma unroll
        for (int nf = 0; nf < 4; ++nf) {
          const float pv = __expf(sc[mf][nf][r] - mnew);
          sc[mf][nf][r] = pv;
          ps += pv;
        }
#pragma unroll
        for (int off = 1; off < 16; off <<= 1)
          ps += __shfl_xor(ps, off, 64);
        lsum[mf][r] = lsum[mf][r] * corr + ps;
#pragma unroll
        for (int nf = 0; nf < 4; ++nf) accO[mf][nf][r] *= corr;
        mold[mf][r] = mnew;
      }
    unsigned short* pw = Pl + w * 32 * 72;
#pragma unroll
    for (int mf = 0; mf < 2; ++mf)
#pragma unroll
      for (int nf = 0; nf < 4; ++nf)
#pragma unroll
        for (int r = 0; r < 4; ++r)
          pw[(mf * 16 + (lg << 2) + r) * 72 + nf * 16 + lr] = f2bf(sc[mf][nf][r]);
    bf16x8 pa[2][2];
#pragma unroll
    for (int mf = 0; mf < 2; ++mf) {
      pa[mf][0] = ldfrag(&pw[(mf * 16 + lr) * 72 + (lg << 3)]);
      pa[mf][1] = ldfrag(&pw[(mf * 16 + lr) * 72 + 32 + (lg << 3)]);
    }
    __builtin_amdgcn_s_setprio(1);
#pragma unroll
    for (int nf = 0; nf < 4; ++nf) {
      bf16x8 v0 = ldfrag_swz(VB, nf * 16 + lr, lg * 8);
      bf16x8 v1 = ldfrag_swz(VB, nf * 16 + lr, 32 + lg * 8);
#pragma unroll
      for (int mf = 0; mf < 2; ++mf) {
        accO[mf][nf] = __builtin_amdgcn_mfma_f32_16x16x32_bf16(pa[mf][0], v0, accO[mf][nf], 0, 0, 0);
        accO[mf][nf] = __builtin_amdgcn_mfma_f32_16x16x32_bf16(pa[mf][1], v1, accO[mf][nf], 0, 0, 0);
      }
    }
    __builtin_amdgcn_s_setprio(0);
    buf ^= 1;
  }

  __syncthreads();
  if (w == 1) {
#pragma unroll
    for (int mf = 0; mf < 2; ++mf)
#pragma unroll
      for (int r = 0; r < 4; ++r) {
        const int qrow = mf * 16 + (lg << 2) + r;
#pragma unroll
        for (int nf = 0; nf < 4; ++nf)
          comb[qrow][nf * 16 + lr] = accO[mf][nf][r];
        if (lr == 0) { comb[qrow][64] = mold[mf][r]; comb[qrow][65] = lsum[mf][r]; }
      }
  }
  __syncthreads();
  if (w == 0) {
#pragma unroll
    for (int mf = 0; mf < 2; ++mf)
#pragma unroll
      for (int r = 0; r < 4; ++r) {
        const int qrow = mf * 16 + (lg << 2) + r;
        const float m1 = comb[qrow][64], l1 = comb[qrow][65];
        const float m0v = mold[mf][r], l0 = lsum[mf][r];
        const float ms = fmaxf(m0v, m1);
        const float f0 = __expf(m0v - ms), f1 = __expf(m1 - ms);
        const float inv = 1.f / (l0 * f0 + l1 * f1);
        const size_t orow = ((size_t)(b * SS) + qt * 32 + mf * 16 + (lg << 2) + r) * DD + h * DKK;
#pragma unroll
        for (int nf = 0; nf < 4; ++nf)
          Ob[orow + nf * 16 + lr] =
              f2bf((accO[mf][nf][r] * f0 + comb[qrow][nf * 16 + lr] * f1) * inv);
      }
  }
}

// ---------------------------------------------------------------------------
// out = LN(a + sum_p c_p); 4 rows per block, vectorized. P = #partials.
// ---------------------------------------------------------------------------
template<int P>
__global__ __launch_bounds__(256)
void addln_kernel(const float* __restrict__ a, const float* __restrict__ c,
                  const float* __restrict__ g, const float* __restrict__ bb,
                  float* __restrict__ hf, unsigned short* __restrict__ hb)
{
  const int row = blockIdx.x * 4 + (threadIdx.x >> 6);
  const int l = threadIdx.x & 63;
  const float* ar = a + (size_t)row * DD + l * 8;
  f32x4 x0 = *(const f32x4*)ar;
  f32x4 x1 = *(const f32x4*)(ar + 4);
#pragma unroll
  for (int pp = 0; pp < P; ++pp) {
    const float* cr = c + (size_t)pp * MM * DD + (size_t)row * DD + l * 8;
    x0 += *(const f32x4*)cr;
    x1 += *(const f32x4*)(cr + 4);
  }
  float sum = x0[0] + x0[1] + x0[2] + x0[3] + x1[0] + x1[1] + x1[2] + x1[3];
#pragma unroll
  for (int off = 1; off < 64; off <<= 1) sum += __shfl_xor(sum, off, 64);
  const float mean = sum * (1.f / 512.f);
  float vs = 0.f;
#pragma unroll
  for (int j = 0; j < 4; ++j) { float d0 = x0[j] - mean; float d1 = x1[j] - mean; vs += d0 * d0 + d1 * d1; }
#pragma unroll
  for (int off = 1; off < 64; off <<= 1) vs += __shfl_xor(vs, off, 64);
  const float rs = rsqrtf(vs * (1.f / 512.f) + 1e-6f);
  const f32x4 g0 = *(const f32x4*)(g + l * 8), g1 = *(const f32x4*)(g + l * 8 + 4);
  const f32x4 b0 = *(const f32x4*)(bb + l * 8), b1 = *(const f32x4*)(bb + l * 8 + 4);
  f32x4 o0, o1;
  us8 ob;
#pragma unroll
  for (int j = 0; j < 4; ++j) {
    o0[j] = (x0[j] - mean) * rs * g0[j] + b0[j];
    o1[j] = (x1[j] - mean) * rs * g1[j] + b1[j];
    ob[j] = f2bf(o0[j]); ob[j + 4] = f2bf(o1[j]);
  }
  float* of = hf + (size_t)row * DD + l * 8;
  *(f32x4*)of = o0; *(f32x4*)(of + 4) = o1;
  *(us8*)(hb + (size_t)row * DD + l * 8) = ob;
}

// ---------------------------------------------------------------------------
// merged prep: [0,512) dec rows, [512,1024) prev rows, [1024,3072) postable,
// [3072,11264) gpec. 256 threads.
// ---------------------------------------------------------------------------
__global__ __launch_bounds__(256)
void prep_all(const float* __restrict__ dec_in, const float* __restrict__ prev,
              unsigned short* __restrict__ decb, unsigned short* __restrict__ prevb,
              float* __restrict__ kvs, float* __restrict__ kve,
              unsigned short* __restrict__ tabT,
              const float* __restrict__ gk, unsigned short* __restrict__ Mb)
{
  const int blk = blockIdx.x, tid = threadIdx.x;
  if (blk < 1024) {
    const int isdec = blk < 512;
    const int row = (isdec ? blk : blk - 512) * 4 + (tid >> 6);
    const int l = tid & 63;
    const int NC = isdec ? VV : DD, NP = isdec ? VP : DD;
    const float* xr = (isdec ? dec_in : prev) + (size_t)row * NC;
    unsigned short* ob = (isdec ? decb : prevb) + (size_t)row * NP;
    int ok = 1;
    for (int j = l; j < NP; j += 64) {
      if (j < NC) {
        const float v = xr[j];
        ok &= (v != -1.0f) ? 1 : 0;
        ob[j] = f2bf(v);
      } else ob[j] = 0;
    }
    ok = __all(ok) ? 1 : 0;
    if (l == 0) (isdec ? kvs : kve)[row] = ok ? 0.f : -1e9f;
  } else if (blk < 3072) {
    const int i = (blk - 1024) * 256 + tid;
    const int d = i >> 10, s = i & 1023;
    const float ex = (float)(2 * (d >> 1)) * (1.0f / (float)DD);
    const float ang = (float)s * exp2f(ex * -13.287712379549449f);
    tabT[i] = f2bf((d & 1) ? cosf(ang) : sinf(ang));
  } else {
    const int i = (blk - 3072) * 256 + tid;
    const int b = i / (SS * SS);
    const int rem = i - b * (SS * SS);
    const float* p = gk + (size_t)b * 3 * SS * SS + rem;
    Mb[i] = f2bf((p[0] + 0.9f * p[SS * SS] + 0.81f * p[2 * SS * SS]) * (1.0f / 2.71f));
  }
}

// ---------------------------------------------------------------------------
// all remaining weight conversions in one launch (job table)
// ---------------------------------------------------------------------------
struct WJobs {
  const float* W[8]; unsigned short* WT[8];
  int K[8], N[8], Kp[8], Np[8], nbx[8], nby[8];
  int off[9];
};
__global__ __launch_bounds__(256)
void wconv_all(WJobs p)
{
  __shared__ float t[64][65];
  const int bid = blockIdx.x;
  int j = 0;
#pragma unroll
  for (int i = 0; i < 8; ++i) if (bid >= p.off[i + 1]) j = i + 1;
  const int local = bid - p.off[j];
  const int per = p.nbx[j] * p.nby[j];
  const int z = local / per;
  const int rem = local - z * per;
  const int by = rem / p.nbx[j];
  const int bx = rem - by * p.nbx[j];
  const int K = p.K[j], N = p.N[j], Kp = p.Kp[j], Np = p.Np[j];
  const float* Wl = p.W[j] + (size_t)z * K * N;
  unsigned short* WTl = p.WT[j] + (size_t)z * Np * Kp;
  const int n0 = bx << 6, k0 = by << 6;
  const int cx = threadIdx.x & 63, ry = threadIdx.x >> 6;
#pragma unroll
  for (int i = 0; i < 16; ++i) {
    const int kk = k0 + ry + i * 4, nn = n0 + cx;
    t[ry + i * 4][cx] = (kk < K && nn < N) ? Wl[(size_t)kk * N + nn] : 0.f;
  }
  __syncthreads();
#pragma unroll
  for (int i = 0; i < 16; ++i) {
    const int nn = n0 + ry + i * 4, kk = k0 + cx;
    if (nn < Np && kk < Kp) WTl[(size_t)nn * Kp + kk] = f2bf(t[cx][ry + i * 4]);
  }
}

// 8 attention weight sets [L][512][512] in one launch; z = wi*LL + li
struct WconvB { const float* W[8]; unsigned short* WT[8]; };
__global__ __launch_bounds__(256)
void wconv8_kernel(WconvB p)
{
  __shared__ float t[64][65];
  const int z = blockIdx.z;
  const int wi = z / LL, li = z - wi * LL;
  const float* Wl = p.W[wi] + (size_t)li * DD * DD;
  unsigned short* WTl = p.WT[wi] + (size_t)li * DD * DD;
  const int n0 = blockIdx.x << 6, k0 = blockIdx.y << 6;
  const int cx = threadIdx.x & 63, ry = threadIdx.x >> 6;
#pragma unroll
  for (int i = 0; i < 16; ++i)
    t[ry + i * 4][cx] = Wl[(size_t)(k0 + ry + i * 4) * DD + n0 + cx];
  __syncthreads();
#pragma unroll
  for (int i = 0; i < 16; ++i)
    WTl[(size_t)(n0 + ry + i * 4) * DD + k0 + cx] = f2bf(t[cx][ry + i * 4]);
}

// ---------------------------------------------------------------------------
static inline void g1(hipStream_t s, const unsigned short* A, const unsigned short* B,
                      const float* bias, float* C, unsigned short* D,
                      int Kp, int Np, int ldc, int Nreal, int relu)
{
  GemmP p{};
  p.A = A; p.B0 = B; p.bias = bias; p.C = C; p.D0 = D;
  p.Kp = Kp; p.Np = Np; p.ldc = ldc; p.Nreal = Nreal; p.relu = relu;
  gemm_tpl<1, 64, 0, 1><<<dim3(Np >> 6, MM >> 6), 256, 0, s>>>(p);
}

static inline void g1w(hipStream_t s, const unsigned short* A, const unsigned short* B,
                       const float* bias, unsigned short* D, int Kp, int Np, int relu)
{
  GemmP p{};
  p.A = A; p.B0 = B; p.bias = bias; p.D0 = D;
  p.Kp = Kp; p.Np = Np; p.ldc = Np; p.Nreal = Np; p.relu = relu;
  gemm_tpl<1, 128, 0, 1><<<dim3(Np >> 7, MM >> 6), 256, 0, s>>>(p);
}

// split-K: f32 partials to C + z*MM*DD
template<int KS>
static inline void g1k(hipStream_t s, const unsigned short* A, const unsigned short* B,
                       const float* bias, float* C, int Kp)
{
  GemmP p{};
  p.A = A; p.B0 = B; p.bias = bias; p.C = C;
  p.Kp = Kp; p.Np = DD; p.ldc = DD; p.Nreal = DD; p.relu = 0;
  gemm_tpl<1, 64, 0, KS><<<dim3(DD >> 6, MM >> 6, KS), 256, 0, s>>>(p);
}

// QKV fused: D0=Q rows, D1=K rows, D2=V transposed
static inline void g3t(hipStream_t s, const unsigned short* A, const unsigned short* B0,
                       const unsigned short* B1, const unsigned short* B2,
                       unsigned short* D0, unsigned short* D1, unsigned short* D2T)
{
  GemmP p{};
  p.A = A; p.B0 = B0; p.B1 = B1; p.B2 = B2; p.D0 = D0; p.D1 = D1; p.D2 = D2T;
  p.Kp = DD; p.Np = DD; p.ldc = DD; p.Nreal = DD; p.relu = 0;
  gemm_tpl<3, 64, 1, 1><<<dim3(3 * (DD >> 6), MM >> 6), 256, 0, s>>>(p);
}

extern "C" void kernel_launch(void* const* d_in, const int* in_sizes, int n_in,
                              void* d_out, int out_size, void* d_ws, size_t ws_size,
                              hipStream_t stream)
{
  (void)in_sizes; (void)n_in; (void)out_size; (void)ws_size;
  const float* dec_in = (const float*)d_in[0];
  const float* prev   = (const float*)d_in[1];
  const float* gk     = (const float*)d_in[6];
  const float* emb_w1 = (const float*)d_in[7];
  const float* emb_b1 = (const float*)d_in[8];
  const float* emb_w2 = (const float*)d_in[9];
  const float* emb_b2 = (const float*)d_in[10];
  const float* emb_w3 = (const float*)d_in[11];
  const float* emb_b3 = (const float*)d_in[12];
  const float* ln0_g  = (const float*)d_in[13];
  const float* ln0_b  = (const float*)d_in[14];
  const float* wq     = (const float*)d_in[15];
  const float* wk     = (const float*)d_in[16];
  const float* wv     = (const float*)d_in[17];
  const float* wo     = (const float*)d_in[18];
  const float* cq     = (const float*)d_in[19];
  const float* ck     = (const float*)d_in[20];
  const float* cv     = (const float*)d_in[21];
  const float* co     = (const float*)d_in[22];
  const float* ffn_w1 = (const float*)d_in[23];
  const float* ffn_w2 = (const float*)d_in[24];
  const float* ffn_b1 = (const float*)d_in[25];
  const float* ffn_b2 = (const float*)d_in[26];
  const float* ln1_g  = (const float*)d_in[27];
  const float* ln1_b  = (const float*)d_in[28];
  const float* ln2_g  = (const float*)d_in[29];
  const float* ln2_b  = (const float*)d_in[30];
  const float* ln3_g  = (const float*)d_in[31];
  const float* ln3_b  = (const float*)d_in[32];
  const float* p_w1   = (const float*)d_in[33];
  const float* p_b1   = (const float*)d_in[34];
  const float* p_w2   = (const float*)d_in[35];
  const float* p_b2   = (const float*)d_in[36];
  const float* p_w3   = (const float*)d_in[37];
  const float* p_b3   = (const float*)d_in[38];

  // ---- workspace carve ----
  char* wsp = (char*)d_ws;
  auto carve = [&](size_t bytes) { char* r = wsp; wsp += (bytes + 255) & ~(size_t)255; return r; };

  unsigned short* decb  = (unsigned short*)carve((size_t)MM * VP * 2);
  unsigned short* prevb = (unsigned short*)carve((size_t)MM * DD * 2);
  float*          hf    = (float*)carve((size_t)MM * DD * 4);
  unsigned short* hb    = (unsigned short*)carve((size_t)MM * DD * 2);
  float*          xf1   = (float*)carve((size_t)MM * DD * 4);
  unsigned short* tb1   = (unsigned short*)carve((size_t)MM * DFFN * 2);   // 8 MB
  unsigned short* Mbb   = tb1;                                   // alias: first 4 MB
  float*          xf2   = (float*)((char*)tb1 + (size_t)MM * SS * 2);      // alias: last 4 MB
  unsigned short* tb2a  = (unsigned short*)carve((size_t)MM * VP * 2);
  unsigned short* tb2b  = (unsigned short*)carve((size_t)MM * VP * 2);
  unsigned short* qb    = (unsigned short*)carve((size_t)MM * DD * 2);
  unsigned short* kb    = (unsigned short*)carve((size_t)MM * DD * 2);
  unsigned short* vbT   = (unsigned short*)carve((size_t)MM * DD * 2);
  float* kvs = (float*)carve((size_t)MM * 4);
  float* kve = (float*)carve((size_t)MM * 4);
  unsigned short* postabt = (unsigned short*)carve((size_t)DD * SS * 2);
  unsigned short* ew1t  = (unsigned short*)carve((size_t)VP * VP * 2);
  unsigned short* ew2t  = (unsigned short*)carve((size_t)VP * VP * 2);
  unsigned short* ew3t  = (unsigned short*)carve((size_t)DD * VP * 2);
  unsigned short* wqt   = (unsigned short*)carve((size_t)LL * DD * DD * 2);
  unsigned short* wkt   = (unsigned short*)carve((size_t)LL * DD * DD * 2);
  unsigned short* wvt   = (unsigned short*)carve((size_t)LL * DD * DD * 2);
  unsigned short* wot   = (unsigned short*)carve((size_t)LL * DD * DD * 2);
  unsigned short* cqt   = (unsigned short*)carve((size_t)LL * DD * DD * 2);
  unsigned short* ckt   = (unsigned short*)carve((size_t)LL * DD * DD * 2);
  unsigned short* cvt   = (unsigned short*)carve((size_t)LL * DD * DD * 2);
  unsigned short* cot   = (unsigned short*)carve((size_t)LL * DD * DD * 2);
  unsigned short* f1t   = (unsigned short*)carve((size_t)LL * DFFN * DD * 2);
  unsigned short* f2t   = (unsigned short*)carve((size_t)LL * DD * DFFN * 2);
  unsigned short* p1t   = (unsigned short*)carve((size_t)VP * DD * 2);
  unsigned short* p2t   = (unsigned short*)carve((size_t)VP * VP * 2);
  unsigned short* p3t   = (unsigned short*)carve((size_t)VP * VP * 2);
  unsigned short* ckall = (unsigned short*)carve((size_t)LL * MM * DD * 2);  // 12 MB
  unsigned short* cvbT  = (unsigned short*)carve((size_t)LL * MM * DD * 2);  // 12 MB
  float*          xk4   = (float*)carve((size_t)4 * MM * DD * 4);            // 16 MB

  const dim3 agrid(SS / 32, HH, BB);

  // ---- prep (1 launch) ----
  prep_all<<<11264, 256, 0, stream>>>(dec_in, prev, decb, prevb, kvs, kve, postabt, gk, Mbb);

  // ---- weight conversions (2 launches) ----
  {
    WconvB wb{};
    wb.W[0] = wq; wb.W[1] = wk; wb.W[2] = wv; wb.W[3] = wo;
    wb.W[4] = cq; wb.W[5] = ck; wb.W[6] = cv; wb.W[7] = co;
    wb.WT[0] = wqt; wb.WT[1] = wkt; wb.WT[2] = wvt; wb.WT[3] = wot;
    wb.WT[4] = cqt; wb.WT[5] = ckt; wb.WT[6] = cvt; wb.WT[7] = cot;
    wconv8_kernel<<<dim3(8, 8, 8 * LL), 256, 0, stream>>>(wb);
  }
  {
    WJobs wj{};
    const float* Ws[8]   = {emb_w1, emb_w2, emb_w3, ffn_w1, ffn_w2, p_w1, p_w2, p_w3};
    unsigned short* Ds[8] = {ew1t, ew2t, ew3t, f1t, f2t, p1t, p2t, p3t};
    const int Ks[8]  = {VV, VV, VV, DD, DFFN, DD, VV, VV};
    const int Ns[8]  = {VV, VV, DD, DFFN, DD, VV, VV, VV};
    const int Kps[8] = {VP, VP, VP, DD, DFFN, DD, VP, VP};
    const int Nps[8] = {VP, VP, DD, DFFN, DD, VP, VP, VP};
    const int nls[8] = {1, 1, 1, LL, LL, 1, 1, 1};
    int off = 0;
    for (int j = 0; j < 8; ++j) {
      wj.W[j] = Ws[j]; wj.WT[j] = Ds[j];
      wj.K[j] = Ks[j]; wj.N[j] = Ns[j]; wj.Kp[j] = Kps[j]; wj.Np[j] = Nps[j];
      wj.nbx[j] = (Nps[j] + 63) / 64; wj.nby[j] = (Kps[j] + 63) / 64;
      wj.off[j] = off;
      off += wj.nbx[j] * wj.nby[j] * nls[j];
    }
    wj.off[8] = off;
    wconv_all<<<off, 256, 0, stream>>>(wj);
  }

  // ---- all 6 layers' cross-attention K/V: one batched GEMM, V transposed ----
  {
    GemmBat p{};
    p.A = prevb; p.Kp = DD; p.Np = DD;
    for (int i = 0; i < LL; ++i) {
      p.B[2 * i]     = ckt + (size_t)i * DD * DD;
      p.B[2 * i + 1] = cvt + (size_t)i * DD * DD;
      p.D[2 * i]     = ckall + (size_t)i * MM * DD;
      p.D[2 * i + 1] = cvbT + (size_t)i * MM * DD;
    }
    gemm_bat<<<dim3(12 * (DD >> 6), MM >> 6), 256, 0, stream>>>(p);
  }

  // ---- embedding MLP + graph positional encoding ----
  g1(stream, decb, ew1t, emb_b1, nullptr, tb2a, VP, VP, VP, VV, 1);
  g1(stream, tb2a, ew2t, emb_b2, nullptr, tb2b, VP, VP, VP, VV, 1);
  g1(stream, tb2b, ew3t, emb_b3, xf1, nullptr, VP, DD, DD, DD, 0);
  g1(stream, Mbb, postabt, nullptr, xf2, nullptr, SS, DD, DD, DD, 0);
  addln_kernel<1><<<MM / 4, 256, 0, stream>>>(xf1, xf2, ln0_g, ln0_b, hf, hb);

  for (int i = 0; i < LL; ++i) {
    const size_t od = (size_t)i * DD * DD;
    // self attention (V written transposed by the QKV GEMM)
    g3t(stream, hb, wqt + od, wkt + od, wvt + od, qb, kb, vbT);
    attn_kernel<<<agrid, 128, 0, stream>>>(qb, kb, vbT, qb, kvs);
    g1k<2>(stream, qb, wot + od, nullptr, xk4, DD);
    addln_kernel<2><<<MM / 4, 256, 0, stream>>>(hf, xk4, ln1_g + i * DD, ln1_b + i * DD, hf, hb);
    // cross attention with fused Q-projection (K/V precomputed)
    attnx_kernel<<<agrid, 128, 0, stream>>>(hb, cqt + od, ckall + (size_t)i * MM * DD,
                                            cvbT + (size_t)i * MM * DD, qb, kve);
    g1k<2>(stream, qb, cot + od, nullptr, xk4, DD);
    addln_kernel<2><<<MM / 4, 256, 0, stream>>>(hf, xk4, ln2_g + i * DD, ln2_b + i * DD, hf, hb);
    // FFN (ffn2 split-K x4)
    g1w(stream, hb, f1t + (size_t)i * DFFN * DD, ffn_b1 + i * DFFN, tb1, DD, DFFN, 1);
    g1k<4>(stream, tb1, f2t + (size_t)i * DD * DFFN, ffn_b2 + i * DD, xk4, DFFN);
    addln_kernel<4><<<MM / 4, 256, 0, stream>>>(hf, xk4, ln3_g + i * DD, ln3_b + i * DD, hf, hb);
  }

  // ---- output head ----
  g1(stream, hb, p1t, p_b1, nullptr, tb2a, DD, VP, VP, VV, 1);
  g1(stream, tb2a, p2t, p_b2, nullptr, tb2b, VP, VP, VP, VV, 1);
  g1(stream, tb2b, p3t, p_b3, (float*)d_out, nullptr, VP, VP, VV, VV, 0);
}

// Round 13
// 971.546 us; speedup vs baseline: 2.4123x; 1.0230x over previous
//
#include <hip/hip_runtime.h>
#include <hip/hip_bf16.h>
#include <stdint.h>

#define BB 2
#define SS 1024
#define VV 513
#define VP 576          // 513 padded to 9*64
#define DD 512
#define HH 8
#define DKK 64
#define DFFN 2048
#define LL 6
#define MM (BB * SS)    // 2048

typedef __bf16 bf16x8 __attribute__((ext_vector_type(8)));
typedef float f32x4 __attribute__((ext_vector_type(4)));
typedef unsigned short us8 __attribute__((ext_vector_type(8)));
typedef unsigned short us4 __attribute__((ext_vector_type(4)));

static __device__ inline unsigned short f2bf(float f) {
  union { float f; unsigned u; } v; v.f = f;
  unsigned u = v.u;
  unsigned r = (u + 0x7FFFu + ((u >> 16) & 1u)) >> 16;
  return (unsigned short)r;
}

static __device__ inline bf16x8 ldfrag(const unsigned short* p) {
  us8 r = *(const us8*)p;
  return __builtin_bit_cast(bf16x8, r);
}

typedef __attribute__((address_space(3))) void lds_void;
typedef const __attribute__((address_space(1))) void glb_void;
static __device__ inline void gl_lds16(const void* g, void* l) {
  __builtin_amdgcn_global_load_lds((glb_void*)g, (lds_void*)l, 16, 0, 0);
}

// swizzled LDS fragment read: tile rows are linear 128B, byte ^= (row&7)<<4
static __device__ inline bf16x8 ldfrag_swz(const unsigned short* base, int row, int kloc) {
  const unsigned byte = (unsigned)(row * 128 + kloc * 2) ^ (unsigned)((row & 7) << 4);
  return ldfrag((const unsigned short*)((const char*)base + byte));
}

static __device__ inline int rot3(int x) { return (x == 2) ? 0 : x + 1; }

// ---------------------------------------------------------------------------
// core 64x64xK pipelined MFMA accumulate (3-deep counted-vmcnt staging)
// ---------------------------------------------------------------------------
__device__ __forceinline__ void gemm_core64(
    unsigned short* Al, unsigned short* Bl,
    const unsigned short* Abase, const unsigned short* Bbase, int Kp, int nt,
    f32x4 (&acc)[2][2])
{
  const int tid = threadIdx.x;
  const int l = tid & 63, w = tid >> 6;
  const int wm = w >> 1, wn = w & 1;
  const int lr = l & 15, lg = l >> 4;

  auto stage = [&](int buf, int kt) {
    const int k0 = kt << 6;
#pragma unroll
    for (int j = 0; j < 2; ++j) {
      const int ti = j * 256 + tid;
      const int row = ti >> 3;
      const int ch = (ti & 7) ^ (row & 7);
      gl_lds16(Abase + (size_t)row * Kp + k0 + ch * 8, &Al[buf * 4096 + ti * 8]);
    }
#pragma unroll
    for (int j = 0; j < 2; ++j) {
      const int ti = j * 256 + tid;
      const int row = ti >> 3;
      const int ch = (ti & 7) ^ (row & 7);
      gl_lds16(Bbase + (size_t)row * Kp + k0 + ch * 8, &Bl[buf * 4096 + ti * 8]);
    }
  };

  stage(0, 0);
  if (nt > 1) stage(1, 1);
  int cb = 0, sb = 2;
  for (int kt = 0; kt < nt; ++kt) {
    if (kt + 1 < nt) asm volatile("s_waitcnt vmcnt(4)" ::: "memory");
    else             asm volatile("s_waitcnt vmcnt(0)" ::: "memory");
    __builtin_amdgcn_s_barrier();
    if (kt + 2 < nt) { stage(sb, kt + 2); sb = rot3(sb); }
#pragma unroll
    for (int ks = 0; ks < 2; ++ks) {
      bf16x8 af[2], bfv[2];
#pragma unroll
      for (int mf = 0; mf < 2; ++mf)
        af[mf] = ldfrag_swz(Al + cb * 4096, wm * 32 + mf * 16 + lr, ks * 32 + lg * 8);
#pragma unroll
      for (int nf = 0; nf < 2; ++nf)
        bfv[nf] = ldfrag_swz(Bl + cb * 4096, wn * 32 + nf * 16 + lr, ks * 32 + lg * 8);
#pragma unroll
      for (int mf = 0; mf < 2; ++mf)
#pragma unroll
        for (int nf = 0; nf < 2; ++nf)
          acc[mf][nf] = __builtin_amdgcn_mfma_f32_16x16x32_bf16(af[mf], bfv[nf], acc[mf][nf], 0, 0, 0);
    }
    cb = rot3(cb);
  }
}

// ---------------------------------------------------------------------------
// GEMM: C = A[M][Kp](bf16) * B^T, B stored [N][Kp] bf16 (padded).
// TRV: sel==2 output stored transposed into [b][h][dk][s].
// KS: split-K factor (grid.z); partials go to p.C + z*MM*ldc (f32).
// ---------------------------------------------------------------------------
struct GemmP {
  const unsigned short* A;
  const unsigned short* B0; const unsigned short* B1; const unsigned short* B2;
  const float* bias;
  float* C;
  unsigned short* D0; unsigned short* D1; unsigned short* D2;
  int Kp, Np, ldc, Nreal, relu;
};

template<int NB, int NT, int TRV, int KS>
__global__ __launch_bounds__(256)
void gemm_tpl(GemmP p)
{
  constexpr int FN = NT / 32;
  __shared__ unsigned short Al[3][64 * 64];
  __shared__ unsigned short Bl[3][NT * 64];
  const int tid = threadIdx.x;
  const int l = tid & 63, w = tid >> 6;
  const int wm = w >> 1, wn = w & 1;
  const int lr = l & 15, lg = l >> 4;

  const int nbn = p.Np / NT;
  int sel = 0, bx = blockIdx.x;
  if (NB > 1) { sel = bx / nbn; bx -= sel * nbn; }
  const unsigned short* Bmat = p.B0;
  if (NB > 1 && sel == 1) Bmat = p.B1;
  if (NB > 2 && sel == 2) Bmat = p.B2;
  const int m0 = blockIdx.y << 6, n0 = bx * NT;
  const int kz = (KS > 1) ? blockIdx.z : 0;

  f32x4 acc[2][FN];
  const f32x4 zf = {0.f, 0.f, 0.f, 0.f};
#pragma unroll
  for (int i = 0; i < 2; ++i)
#pragma unroll
    for (int j = 0; j < FN; ++j) acc[i][j] = zf;

  const size_t Kp = (size_t)p.Kp;
  const unsigned short* Abase = p.A + (size_t)m0 * Kp;
  const unsigned short* Bbase = Bmat + (size_t)n0 * Kp;
  const int nt = (p.Kp >> 6) / KS;
  const int kb0 = kz * nt;

  auto stage = [&](int buf, int kt) {
    const int k0 = (kb0 + kt) << 6;
#pragma unroll
    for (int j = 0; j < 2; ++j) {
      const int ti = j * 256 + tid;
      const int row = ti >> 3;
      const int ch = (ti & 7) ^ (row & 7);
      gl_lds16(Abase + (size_t)row * Kp + k0 + ch * 8, &Al[buf][ti * 8]);
    }
#pragma unroll
    for (int j = 0; j < FN; ++j) {
      const int ti = j * 256 + tid;
      const int row = ti >> 3;
      const int ch = (ti & 7) ^ (row & 7);
      gl_lds16(Bbase + (size_t)row * Kp + k0 + ch * 8, &Bl[buf][ti * 8]);
    }
  };

  stage(0, 0);
  if (nt > 1) stage(1, 1);
  int cb = 0, sb = 2;

  for (int kt = 0; kt < nt; ++kt) {
    if (kt + 1 < nt) {
      if constexpr (FN == 2) asm volatile("s_waitcnt vmcnt(4)" ::: "memory");
      else                   asm volatile("s_waitcnt vmcnt(6)" ::: "memory");
    } else {
      asm volatile("s_waitcnt vmcnt(0)" ::: "memory");
    }
    __builtin_amdgcn_s_barrier();
    if (kt + 2 < nt) { stage(sb, kt + 2); sb = rot3(sb); }
#pragma unroll
    for (int ks = 0; ks < 2; ++ks) {
      bf16x8 af[2], bfv[FN];
#pragma unroll
      for (int mf = 0; mf < 2; ++mf)
        af[mf] = ldfrag_swz(Al[cb], wm * 32 + mf * 16 + lr, ks * 32 + lg * 8);
#pragma unroll
      for (int nf = 0; nf < FN; ++nf)
        bfv[nf] = ldfrag_swz(Bl[cb], wn * (NT / 2) + nf * 16 + lr, ks * 32 + lg * 8);
#pragma unroll
      for (int mf = 0; mf < 2; ++mf)
#pragma unroll
        for (int nf = 0; nf < FN; ++nf)
          acc[mf][nf] = __builtin_amdgcn_mfma_f32_16x16x32_bf16(af[mf], bfv[nf], acc[mf][nf], 0, 0, 0);
    }
    cb = rot3(cb);
  }

  unsigned short* Dsel = p.D0;
  if (NB > 1 && sel == 1) Dsel = p.D1;
  if (NB > 2 && sel == 2) Dsel = p.D2;

  if (TRV && sel == 2) {
#pragma unroll
    for (int mf = 0; mf < 2; ++mf) {
      const int growb = m0 + wm * 32 + mf * 16 + (lg << 2);
      const int b = growb >> 10, s = growb & 1023;
#pragma unroll
      for (int nf = 0; nf < FN; ++nf) {
        const int gcol = n0 + wn * (NT / 2) + nf * 16 + lr;
        const int h = gcol >> 6, d = gcol & 63;
        us4 t;
#pragma unroll
        for (int r = 0; r < 4; ++r) t[r] = f2bf(acc[mf][nf][r]);
        *(us4*)(Dsel + (((size_t)(b * HH) + h) * DKK + d) * SS + s) = t;
      }
    }
    return;
  }

  float* Cz = p.C ? (p.C + (size_t)kz * MM * p.ldc) : nullptr;
#pragma unroll
  for (int mf = 0; mf < 2; ++mf) {
#pragma unroll
    for (int r = 0; r < 4; ++r) {
      const int grow = m0 + wm * 32 + mf * 16 + (lg << 2) + r;
#pragma unroll
      for (int nf = 0; nf < FN; ++nf) {
        const int gcol = n0 + wn * (NT / 2) + nf * 16 + lr;
        float v = acc[mf][nf][r];
        if (p.bias && kz == 0 && gcol < p.Nreal) v += p.bias[gcol];
        if (p.relu) v = fmaxf(v, 0.f);
        if (Dsel) Dsel[(size_t)grow * p.Np + gcol] = f2bf(v);
        if (Cz && gcol < p.Nreal) Cz[(size_t)grow * p.ldc + gcol] = v;
      }
    }
  }
}

// ---------------------------------------------------------------------------
// Mega GEMM launch: flat job decode.
//   bid <  3072 : cross-KV batched GEMM (12 sel, odd sel -> transposed V)
//   bid <  3360 : emb1  (decb @ ew1t^T, relu+bias, bf16 out, Kp=Np=576)
//   bid <  3616 : GPE   (Mbb @ postabt^T, f32 out, Kp=1024, Np=512)
// ---------------------------------------------------------------------------
struct GemmMultiP {
  const unsigned short* A;            // prevb
  const unsigned short* B[12];
  unsigned short* D[12];
  const unsigned short* eA; const unsigned short* eB; const float* ebias;
  unsigned short* eD;
  const unsigned short* gA; const unsigned short* gB; float* gC;
};

__global__ __launch_bounds__(256)
void gemm_multi(GemmMultiP p)
{
  __shared__ unsigned short Al[3 * 4096];
  __shared__ unsigned short Bl[3 * 4096];
  const int bid = blockIdx.x;
  const int tid = threadIdx.x;
  const int l = tid & 63, w = tid >> 6;
  const int wm = w >> 1, wn = w & 1;
  const int lr = l & 15, lg = l >> 4;
  const f32x4 zf = {0.f, 0.f, 0.f, 0.f};
  f32x4 acc[2][2];
#pragma unroll
  for (int i = 0; i < 2; ++i)
#pragma unroll
    for (int j = 0; j < 2; ++j) acc[i][j] = zf;

  if (bid < 3072) {
    const int sel = bid >> 8;
    const int rem = bid & 255;
    const int by = rem >> 3, bx = rem & 7;
    const int m0 = by << 6, n0 = bx << 6;
    gemm_core64(Al, Bl, p.A + (size_t)m0 * DD, p.B[sel] + (size_t)n0 * DD, DD, 8, acc);
    unsigned short* Dmat = p.D[sel];
    if (sel & 1) {
#pragma unroll
      for (int mf = 0; mf < 2; ++mf) {
        const int growb = m0 + wm * 32 + mf * 16 + (lg << 2);
        const int b = growb >> 10, s = growb & 1023;
#pragma unroll
        for (int nf = 0; nf < 2; ++nf) {
          const int gcol = n0 + wn * 32 + nf * 16 + lr;
          const int h = gcol >> 6, d = gcol & 63;
          us4 t;
#pragma unroll
          for (int r = 0; r < 4; ++r) t[r] = f2bf(acc[mf][nf][r]);
          *(us4*)(Dmat + (((size_t)(b * HH) + h) * DKK + d) * SS + s) = t;
        }
      }
    } else {
#pragma unroll
      for (int mf = 0; mf < 2; ++mf)
#pragma unroll
        for (int r = 0; r < 4; ++r) {
          const int grow = m0 + wm * 32 + mf * 16 + (lg << 2) + r;
#pragma unroll
          for (int nf = 0; nf < 2; ++nf) {
            const int gcol = n0 + wn * 32 + nf * 16 + lr;
            Dmat[(size_t)grow * DD + gcol] = f2bf(acc[mf][nf][r]);
          }
        }
    }
  } else if (bid < 3360) {
    const int local = bid - 3072;
    const int by = local / 9, bx = local - by * 9;
    const int m0 = by << 6, n0 = bx << 6;
    gemm_core64(Al, Bl, p.eA + (size_t)m0 * VP, p.eB + (size_t)n0 * VP, VP, 9, acc);
#pragma unroll
    for (int mf = 0; mf < 2; ++mf)
#pragma unroll
      for (int r = 0; r < 4; ++r) {
        const int grow = m0 + wm * 32 + mf * 16 + (lg << 2) + r;
#pragma unroll
        for (int nf = 0; nf < 2; ++nf) {
          const int gcol = n0 + wn * 32 + nf * 16 + lr;
          float v = acc[mf][nf][r];
          if (gcol < VV) v += p.ebias[gcol];
          v = fmaxf(v, 0.f);
          p.eD[(size_t)grow * VP + gcol] = f2bf(v);
        }
      }
  } else {
    const int local = bid - 3360;
    const int by = local >> 3, bx = local & 7;
    const int m0 = by << 6, n0 = bx << 6;
    gemm_core64(Al, Bl, p.gA + (size_t)m0 * SS, p.gB + (size_t)n0 * SS, SS, 16, acc);
#pragma unroll
    for (int mf = 0; mf < 2; ++mf)
#pragma unroll
      for (int r = 0; r < 4; ++r) {
        const int grow = m0 + wm * 32 + mf * 16 + (lg << 2) + r;
#pragma unroll
        for (int nf = 0; nf < 2; ++nf) {
          const int gcol = n0 + wn * 32 + nf * 16 + lr;
          p.gC[(size_t)grow * DD + gcol] = acc[mf][nf][r];
        }
      }
  }
}

// ---------------------------------------------------------------------------
// Self-attention (causal): QBLK=32, 2 waves split KV (wave w: tiles ≡w mod 2).
// ---------------------------------------------------------------------------
__global__ __launch_bounds__(128)
void attn_kernel(const unsigned short* __restrict__ Qb,
                 const unsigned short* __restrict__ Kb,
                 const unsigned short* __restrict__ VbT,
                 unsigned short* __restrict__ Ob,
                 const float* __restrict__ maskadd)
{
  __shared__ unsigned short Kl[2][2][64 * 64];
  __shared__ unsigned short Vl[2][2][64 * 64];
  __shared__ char PC[9216];
  unsigned short* Pl = (unsigned short*)PC;
  float (*comb)[66] = (float(*)[66])PC;

  const int tid = threadIdx.x;
  const int l = tid & 63, w = tid >> 6;
  const int qt = blockIdx.x, h = blockIdx.y, b = blockIdx.z;
  const int lr = l & 15, lg = l >> 4;

  bf16x8 qf[2][2];
#pragma unroll
  for (int mf = 0; mf < 2; ++mf) {
    const unsigned short* qrow = Qb + ((size_t)(b * SS) + qt * 32 + mf * 16 + lr) * DD + h * DKK;
    qf[mf][0] = ldfrag(qrow + (lg << 3));
    qf[mf][1] = ldfrag(qrow + 32 + (lg << 3));
  }

  const unsigned short* Kbase = Kb + (size_t)(b * SS) * DD + h * DKK;
  const unsigned short* Vbase = VbT + ((size_t)(b * HH) + h) * DKK * SS;

  auto stage = [&](int buf, int kt) {
#pragma unroll
    for (int j = 0; j < 8; ++j) {
      const int ti = j * 64 + l;
      const int row = ti >> 3;
      const int ch = (ti & 7) ^ (row & 7);
      gl_lds16(Kbase + (size_t)(kt * 64 + row) * DD + ch * 8, &Kl[w][buf][ti * 8]);
    }
#pragma unroll
    for (int j = 0; j < 8; ++j) {
      const int ti = j * 64 + l;
      const int row = ti >> 3;
      const int ch = (ti & 7) ^ (row & 7);
      gl_lds16(Vbase + (size_t)row * SS + kt * 64 + ch * 8, &Vl[w][buf][ti * 8]);
    }
  };

  f32x4 accO[2][4];
  const f32x4 zf = {0.f, 0.f, 0.f, 0.f};
#pragma unroll
  for (int mf = 0; mf < 2; ++mf)
#pragma unroll
    for (int nf = 0; nf < 4; ++nf) accO[mf][nf] = zf;
  float mold[2][4], lsum[2][4];
#pragma unroll
  for (int mf = 0; mf < 2; ++mf)
#pragma unroll
    for (int r = 0; r < 4; ++r) { mold[mf][r] = -1e30f; lsum[mf][r] = 0.f; }

  const int ktmax = (qt >> 1) + 1;
  const int myn = (ktmax - w + 1) >> 1;

  if (myn > 0) stage(0, w);
  int buf = 0;

  for (int i = 0; i < myn; ++i) {
    const int kt = w + 2 * i;
    if (i + 1 < myn) {
      stage(buf ^ 1, kt + 2);
      asm volatile("s_waitcnt vmcnt(16)" ::: "memory");
    } else {
      asm volatile("s_waitcnt vmcnt(0)" ::: "memory");
    }
    const unsigned short* KB = &Kl[w][buf][0];
    const unsigned short* VB = &Vl[w][buf][0];
    float sc[2][4][4];
    __builtin_amdgcn_s_setprio(1);
#pragma unroll
    for (int nf = 0; nf < 4; ++nf) {
      bf16x8 k0 = ldfrag_swz(KB, nf * 16 + lr, lg * 8);
      bf16x8 k1 = ldfrag_swz(KB, nf * 16 + lr, 32 + lg * 8);
      const int kglob = kt * 64 + nf * 16 + lr;
      const float madd = maskadd[b * SS + kglob];
#pragma unroll
      for (int mf = 0; mf < 2; ++mf) {
        f32x4 s = zf;
        s = __builtin_amdgcn_mfma_f32_16x16x32_bf16(qf[mf][0], k0, s, 0, 0, 0);
        s = __builtin_amdgcn_mfma_f32_16x16x32_bf16(qf[mf][1], k1, s, 0, 0, 0);
#pragma unroll
        for (int r = 0; r < 4; ++r) {
          const int qglob = qt * 32 + mf * 16 + (lg << 2) + r;
          sc[mf][nf][r] = (kglob > qglob) ? -1e9f : s[r] * 0.125f + madd;
        }
      }
    }
    __builtin_amdgcn_s_setprio(0);
#pragma unroll
    for (int mf = 0; mf < 2; ++mf)
#pragma unroll
      for (int r = 0; r < 4; ++r) {
        float mloc = fmaxf(fmaxf(sc[mf][0][r], sc[mf][1][r]), fmaxf(sc[mf][2][r], sc[mf][3][r]));
#pragma unroll
        for (int off = 1; off < 16; off <<= 1)
          mloc = fmaxf(mloc, __shfl_xor(mloc, off, 64));
        const float mnew = fmaxf(mold[mf][r], mloc);
        const float corr = __expf(mold[mf][r] - mnew);
        float ps = 0.f;
#pragma unroll
        for (int nf = 0; nf < 4; ++nf) {
          const float pv = __expf(sc[mf][nf][r] - mnew);
          sc[mf][nf][r] = pv;
          ps += pv;
        }
#pragma unroll
        for (int off = 1; off < 16; off <<= 1)
          ps += __shfl_xor(ps, off, 64);
        lsum[mf][r] = lsum[mf][r] * corr + ps;
#pragma unroll
        for (int nf = 0; nf < 4; ++nf) accO[mf][nf][r] *= corr;
        mold[mf][r] = mnew;
      }
    unsigned short* pw = Pl + w * 32 * 72;
#pragma unroll
    for (int mf = 0; mf < 2; ++mf)
#pragma unroll
      for (int nf = 0; nf < 4; ++nf)
#pragma unroll
        for (int r = 0; r < 4; ++r)
          pw[(mf * 16 + (lg << 2) + r) * 72 + nf * 16 + lr] = f2bf(sc[mf][nf][r]);
    bf16x8 pa[2][2];
#pragma unroll
    for (int mf = 0; mf < 2; ++mf) {
      pa[mf][0] = ldfrag(&pw[(mf * 16 + lr) * 72 + (lg << 3)]);
      pa[mf][1] = ldfrag(&pw[(mf * 16 + lr) * 72 + 32 + (lg << 3)]);
    }
    __builtin_amdgcn_s_setprio(1);
#pragma unroll
    for (int nf = 0; nf < 4; ++nf) {
      bf16x8 v0 = ldfrag_swz(VB, nf * 16 + lr, lg * 8);
      bf16x8 v1 = ldfrag_swz(VB, nf * 16 + lr, 32 + lg * 8);
#pragma unroll
      for (int mf = 0; mf < 2; ++mf) {
        accO[mf][nf] = __builtin_amdgcn_mfma_f32_16x16x32_bf16(pa[mf][0], v0, accO[mf][nf], 0, 0, 0);
        accO[mf][nf] = __builtin_amdgcn_mfma_f32_16x16x32_bf16(pa[mf][1], v1, accO[mf][nf], 0, 0, 0);
      }
    }
    __builtin_amdgcn_s_setprio(0);
    buf ^= 1;
  }

  __syncthreads();
  if (w == 1) {
#pragma unroll
    for (int mf = 0; mf < 2; ++mf)
#pragma unroll
      for (int r = 0; r < 4; ++r) {
        const int qrow = mf * 16 + (lg << 2) + r;
#pragma unroll
        for (int nf = 0; nf < 4; ++nf)
          comb[qrow][nf * 16 + lr] = accO[mf][nf][r];
        if (lr == 0) { comb[qrow][64] = mold[mf][r]; comb[qrow][65] = lsum[mf][r]; }
      }
  }
  __syncthreads();
  if (w == 0) {
#pragma unroll
    for (int mf = 0; mf < 2; ++mf)
#pragma unroll
      for (int r = 0; r < 4; ++r) {
        const int qrow = mf * 16 + (lg << 2) + r;
        const float m1 = comb[qrow][64], l1 = comb[qrow][65];
        const float m0v = mold[mf][r], l0 = lsum[mf][r];
        const float ms = fmaxf(m0v, m1);
        const float f0 = __expf(m0v - ms), f1 = __expf(m1 - ms);
        const float inv = 1.f / (l0 * f0 + l1 * f1);
        const size_t orow = ((size_t)(b * SS) + qt * 32 + mf * 16 + (lg << 2) + r) * DD + h * DKK;
#pragma unroll
        for (int nf = 0; nf < 4; ++nf)
          Ob[orow + nf * 16 + lr] =
              f2bf((accO[mf][nf][r] * f0 + comb[qrow][nf * 16 + lr] * f1) * inv);
      }
  }
}

// ---------------------------------------------------------------------------
// Cross-attention with FUSED Q-projection (scale folded into Q).
// ---------------------------------------------------------------------------
__global__ __launch_bounds__(128)
void attnx_kernel(const unsigned short* __restrict__ Hb,
                  const unsigned short* __restrict__ Wq,
                  const unsigned short* __restrict__ Kb,
                  const unsigned short* __restrict__ VbT,
                  unsigned short* __restrict__ Ob,
                  const float* __restrict__ maskadd)
{
  __shared__ unsigned short Kl[2][2][64 * 64];
  __shared__ unsigned short Vl[2][2][64 * 64];
  __shared__ char PC[9216];
  unsigned short* Pl = (unsigned short*)PC;
  float (*comb)[66] = (float(*)[66])PC;
  unsigned short* QA = &Kl[0][0][0];
  unsigned short* QB = &Vl[0][0][0];
  unsigned short* Ql = (unsigned short*)PC;

  const int tid = threadIdx.x;
  const int l = tid & 63, w = tid >> 6;
  const int qt = blockIdx.x, h = blockIdx.y, b = blockIdx.z;
  const int lr = l & 15, lg = l >> 4;

  {
    const unsigned short* Abase = Hb + ((size_t)(b * SS) + qt * 32) * DD;
    const unsigned short* Bbase = Wq + (size_t)(h * DKK) * DD;
    auto stage_q = [&](int buf, int kt) {
      const int k0 = kt << 6;
#pragma unroll
      for (int j = 0; j < 2; ++j) {
        const int ti = j * 128 + tid;
        const int row = ti >> 3;
        const int ch = (ti & 7) ^ (row & 7);
        gl_lds16(Abase + (size_t)row * DD + k0 + ch * 8, &QA[buf * 2048 + ti * 8]);
      }
#pragma unroll
      for (int j = 0; j < 4; ++j) {
        const int ti = j * 128 + tid;
        const int row = ti >> 3;
        const int ch = (ti & 7) ^ (row & 7);
        gl_lds16(Bbase + (size_t)row * DD + k0 + ch * 8, &QB[buf * 4096 + ti * 8]);
      }
    };
    f32x4 qacc[2][2];
    const f32x4 zf = {0.f, 0.f, 0.f, 0.f};
#pragma unroll
    for (int i = 0; i < 2; ++i)
#pragma unroll
      for (int j = 0; j < 2; ++j) qacc[i][j] = zf;

    stage_q(0, 0);
    for (int kt = 0; kt < 8; ++kt) {
      if (kt + 1 < 8) {
        stage_q((kt + 1) & 1, kt + 1);
        asm volatile("s_waitcnt vmcnt(6)" ::: "memory");
      } else {
        asm volatile("s_waitcnt vmcnt(0)" ::: "memory");
      }
      __builtin_amdgcn_s_barrier();
      const unsigned short* qa = &QA[(kt & 1) * 2048];
      const unsigned short* qbuf = &QB[(kt & 1) * 4096];
#pragma unroll
      for (int ks = 0; ks < 2; ++ks) {
        bf16x8 af[2], bfv[2];
#pragma unroll
        for (int mf = 0; mf < 2; ++mf)
          af[mf] = ldfrag_swz(qa, mf * 16 + lr, ks * 32 + lg * 8);
#pragma unroll
        for (int nf = 0; nf < 2; ++nf)
          bfv[nf] = ldfrag_swz(qbuf, w * 32 + nf * 16 + lr, ks * 32 + lg * 8);
#pragma unroll
        for (int mf = 0; mf < 2; ++mf)
#pragma unroll
          for (int nf = 0; nf < 2; ++nf)
            qacc[mf][nf] = __builtin_amdgcn_mfma_f32_16x16x32_bf16(af[mf], bfv[nf], qacc[mf][nf], 0, 0, 0);
      }
      __builtin_amdgcn_s_barrier();
    }
#pragma unroll
    for (int mf = 0; mf < 2; ++mf)
#pragma unroll
      for (int nf = 0; nf < 2; ++nf)
#pragma unroll
        for (int r = 0; r < 4; ++r)
          Ql[(mf * 16 + (lg << 2) + r) * 72 + w * 32 + nf * 16 + lr] = f2bf(qacc[mf][nf][r] * 0.125f);
    __syncthreads();
  }
  bf16x8 qf[2][2];
#pragma unroll
  for (int mf = 0; mf < 2; ++mf) {
    qf[mf][0] = ldfrag(&Ql[(mf * 16 + lr) * 72 + (lg << 3)]);
    qf[mf][1] = ldfrag(&Ql[(mf * 16 + lr) * 72 + 32 + (lg << 3)]);
  }
  __syncthreads();

  const unsigned short* Kbase = Kb + (size_t)(b * SS) * DD + h * DKK;
  const unsigned short* Vbase = VbT + ((size_t)(b * HH) + h) * DKK * SS;

  auto stage = [&](int buf, int kt) {
#pragma unroll
    for (int j = 0; j < 8; ++j) {
      const int ti = j * 64 + l;
      const int row = ti >> 3;
      const int ch = (ti & 7) ^ (row & 7);
      gl_lds16(Kbase + (size_t)(kt * 64 + row) * DD + ch * 8, &Kl[w][buf][ti * 8]);
    }
#pragma unroll
    for (int j = 0; j < 8; ++j) {
      const int ti = j * 64 + l;
      const int row = ti >> 3;
      const int ch = (ti & 7) ^ (row & 7);
      gl_lds16(Vbase + (size_t)row * SS + kt * 64 + ch * 8, &Vl[w][buf][ti * 8]);
    }
  };

  f32x4 accO[2][4];
  const f32x4 zf = {0.f, 0.f, 0.f, 0.f};
#pragma unroll
  for (int mf = 0; mf < 2; ++mf)
#pragma unroll
    for (int nf = 0; nf < 4; ++nf) accO[mf][nf] = zf;
  float mold[2][4], lsum[2][4];
#pragma unroll
  for (int mf = 0; mf < 2; ++mf)
#pragma unroll
    for (int r = 0; r < 4; ++r) { mold[mf][r] = -1e30f; lsum[mf][r] = 0.f; }

  const int myn = (SS / 64 - w + 1) >> 1;
  stage(0, w);
  int buf = 0;

  for (int i = 0; i < myn; ++i) {
    const int kt = w + 2 * i;
    if (i + 1 < myn) {
      stage(buf ^ 1, kt + 2);
      asm volatile("s_waitcnt vmcnt(16)" ::: "memory");
    } else {
      asm volatile("s_waitcnt vmcnt(0)" ::: "memory");
    }
    const unsigned short* KB = &Kl[w][buf][0];
    const unsigned short* VB = &Vl[w][buf][0];
    float sc[2][4][4];
    __builtin_amdgcn_s_setprio(1);
#pragma unroll
    for (int nf = 0; nf < 4; ++nf) {
      bf16x8 k0 = ldfrag_swz(KB, nf * 16 + lr, lg * 8);
      bf16x8 k1 = ldfrag_swz(KB, nf * 16 + lr, 32 + lg * 8);
      const int kglob = kt * 64 + nf * 16 + lr;
      const float madd = maskadd[b * SS + kglob];
#pragma unroll
      for (int mf = 0; mf < 2; ++mf) {
        f32x4 s = zf;
        s = __builtin_amdgcn_mfma_f32_16x16x32_bf16(qf[mf][0], k0, s, 0, 0, 0);
        s = __builtin_amdgcn_mfma_f32_16x16x32_bf16(qf[mf][1], k1, s, 0, 0, 0);
#pragma unroll
        for (int r = 0; r < 4; ++r)
          sc[mf][nf][r] = s[r] + madd;
      }
    }
    __builtin_amdgcn_s_setprio(0);
#pragma unroll
    for (int mf = 0; mf < 2; ++mf)
#pragma unroll
      for (int r = 0; r < 4; ++r) {
        float mloc = fmaxf(fmaxf(sc[mf][0][r], sc[mf][1][r]), fmaxf(sc[mf][2][r], sc[mf][3][r]));
#pragma unroll
        for (int off = 1; off < 16; off <<= 1)
          mloc = fmaxf(mloc, __shfl_xor(mloc, off, 64));
        const float mnew = fmaxf(mold[mf][r], mloc);
        const float corr = __expf(mold[mf][r] - mnew);
        float ps = 0.f;
#pragma unroll
        for (int nf = 0; nf < 4; ++nf) {
          const float pv = __expf(sc[mf][nf][r] - mnew);
          sc[mf][nf][r] = pv;
          ps += pv;
        }
#pragma unroll
        for (int off = 1; off < 16; off <<= 1)
          ps += __shfl_xor(ps, off, 64);
        lsum[mf][r] = lsum[mf][r] * corr + ps;
#pragma unroll
        for (int nf = 0; nf < 4; ++nf) accO[mf][nf][r] *= corr;
        mold[mf][r] = mnew;
      }
    unsigned short* pw = Pl + w * 32 * 72;
#pragma unroll
    for (int mf = 0; mf < 2; ++mf)
#pragma unroll
      for (int nf = 0; nf < 4; ++nf)
#pragma unroll
        for (int r = 0; r < 4; ++r)
          pw[(mf * 16 + (lg << 2) + r) * 72 + nf * 16 + lr] = f2bf(sc[mf][nf][r]);
    bf16x8 pa[2][2];
#pragma unroll
    for (int mf = 0; mf < 2; ++mf) {
      pa[mf][0] = ldfrag(&pw[(mf * 16 + lr) * 72 + (lg << 3)]);
      pa[mf][1] = ldfrag(&pw[(mf * 16 + lr) * 72 + 32 + (lg << 3)]);
    }
    __builtin_amdgcn_s_setprio(1);
#pragma unroll
    for (int nf = 0; nf < 4; ++nf) {
      bf16x8 v0 = ldfrag_swz(VB, nf * 16 + lr, lg * 8);
      bf16x8 v1 = ldfrag_swz(VB, nf * 16 + lr, 32 + lg * 8);
#pragma unroll
      for (int mf = 0; mf < 2; ++mf) {
        accO[mf][nf] = __builtin_amdgcn_mfma_f32_16x16x32_bf16(pa[mf][0], v0, accO[mf][nf], 0, 0, 0);
        accO[mf][nf] = __builtin_amdgcn_mfma_f32_16x16x32_bf16(pa[mf][1], v1, accO[mf][nf], 0, 0, 0);
      }
    }
    __builtin_amdgcn_s_setprio(0);
    buf ^= 1;
  }

  __syncthreads();
  if (w == 1) {
#pragma unroll
    for (int mf = 0; mf < 2; ++mf)
#pragma unroll
      for (int r = 0; r < 4; ++r) {
        const int qrow = mf * 16 + (lg << 2) + r;
#pragma unroll
        for (int nf = 0; nf < 4; ++nf)
          comb[qrow][nf * 16 + lr] = accO[mf][nf][r];
        if (lr == 0) { comb[qrow][64] = mold[mf][r]; comb[qrow][65] = lsum[mf][r]; }
      }
  }
  __syncthreads();
  if (w == 0) {
#pragma unroll
    for (int mf = 0; mf < 2; ++mf)
#pragma unroll
      for (int r = 0; r < 4; ++r) {
        const int qrow = mf * 16 + (lg << 2) + r;
        const float m1 = comb[qrow][64], l1 = comb[qrow][65];
        const float m0v = mold[mf][r], l0 = lsum[mf][r];
        const float ms = fmaxf(m0v, m1);
        const float f0 = __expf(m0v - ms), f1 = __expf(m1 - ms);
        const float inv = 1.f / (l0 * f0 + l1 * f1);
        const size_t orow = ((size_t)(b * SS) + qt * 32 + mf * 16 + (lg << 2) + r) * DD + h * DKK;
#pragma unroll
        for (int nf = 0; nf < 4; ++nf)
          Ob[orow + nf * 16 + lr] =
              f2bf((accO[mf][nf][r] * f0 + comb[qrow][nf * 16 + lr] * f1) * inv);
      }
  }
}

// ---------------------------------------------------------------------------
// out = LN(a + sum_p c_p); 4 rows per block, vectorized. P = #partials.
// ---------------------------------------------------------------------------
template<int P>
__global__ __launch_bounds__(256)
void addln_kernel(const float* __restrict__ a, const float* __restrict__ c,
                  const float* __restrict__ g, const float* __restrict__ bb,
                  float* __restrict__ hf, unsigned short* __restrict__ hb)
{
  const int row = blockIdx.x * 4 + (threadIdx.x >> 6);
  const int l = threadIdx.x & 63;
  const float* ar = a + (size_t)row * DD + l * 8;
  f32x4 x0 = *(const f32x4*)ar;
  f32x4 x1 = *(const f32x4*)(ar + 4);
#pragma unroll
  for (int pp = 0; pp < P; ++pp) {
    const float* cr = c + (size_t)pp * MM * DD + (size_t)row * DD + l * 8;
    x0 += *(const f32x4*)cr;
    x1 += *(const f32x4*)(cr + 4);
  }
  float sum = x0[0] + x0[1] + x0[2] + x0[3] + x1[0] + x1[1] + x1[2] + x1[3];
#pragma unroll
  for (int off = 1; off < 64; off <<= 1) sum += __shfl_xor(sum, off, 64);
  const float mean = sum * (1.f / 512.f);
  float vs = 0.f;
#pragma unroll
  for (int j = 0; j < 4; ++j) { float d0 = x0[j] - mean; float d1 = x1[j] - mean; vs += d0 * d0 + d1 * d1; }
#pragma unroll
  for (int off = 1; off < 64; off <<= 1) vs += __shfl_xor(vs, off, 64);
  const float rs = rsqrtf(vs * (1.f / 512.f) + 1e-6f);
  const f32x4 g0 = *(const f32x4*)(g + l * 8), g1 = *(const f32x4*)(g + l * 8 + 4);
  const f32x4 b0 = *(const f32x4*)(bb + l * 8), b1 = *(const f32x4*)(bb + l * 8 + 4);
  f32x4 o0, o1;
  us8 ob;
#pragma unroll
  for (int j = 0; j < 4; ++j) {
    o0[j] = (x0[j] - mean) * rs * g0[j] + b0[j];
    o1[j] = (x1[j] - mean) * rs * g1[j] + b1[j];
    ob[j] = f2bf(o0[j]); ob[j + 4] = f2bf(o1[j]);
  }
  float* of = hf + (size_t)row * DD + l * 8;
  *(f32x4*)of = o0; *(f32x4*)(of + 4) = o1;
  *(us8*)(hb + (size_t)row * DD + l * 8) = ob;
}

// ---------------------------------------------------------------------------
// Mega prologue: prep (1024) + postable (2048) + gpec (8192) + wconv8 (3072)
// + wconv jobs (rest). One launch.
// ---------------------------------------------------------------------------
struct ProP {
  const float *dec_in, *prev, *gk;
  unsigned short *decb, *prevb, *tabT, *Mb;
  float *kvs, *kve;
  const float* W8[8]; unsigned short* WT8[8];
  const float* W[8]; unsigned short* WT[8];
  int K[8], N[8], Kp[8], Np[8], nbx[8], nby[8];
  int off[9];
};

__global__ __launch_bounds__(256)
void prologue_all(ProP p)
{
  __shared__ float t[64][65];
  const int bid = blockIdx.x, tid = threadIdx.x;
  if (bid < 1024) {
    const int isdec = bid < 512;
    const int row = (isdec ? bid : bid - 512) * 4 + (tid >> 6);
    const int l = tid & 63;
    const int NC = isdec ? VV : DD, NP = isdec ? VP : DD;
    const float* xr = (isdec ? p.dec_in : p.prev) + (size_t)row * NC;
    unsigned short* ob = (isdec ? p.decb : p.prevb) + (size_t)row * NP;
    int ok = 1;
    for (int j = l; j < NP; j += 64) {
      if (j < NC) {
        const float v = xr[j];
        ok &= (v != -1.0f) ? 1 : 0;
        ob[j] = f2bf(v);
      } else ob[j] = 0;
    }
    ok = __all(ok) ? 1 : 0;
    if (l == 0) (isdec ? p.kvs : p.kve)[row] = ok ? 0.f : -1e9f;
  } else if (bid < 3072) {
    const int i = (bid - 1024) * 256 + tid;
    const int d = i >> 10, s = i & 1023;
    const float ex = (float)(2 * (d >> 1)) * (1.0f / (float)DD);
    const float ang = (float)s * exp2f(ex * -13.287712379549449f);
    p.tabT[i] = f2bf((d & 1) ? cosf(ang) : sinf(ang));
  } else if (bid < 11264) {
    const int i = (bid - 3072) * 256 + tid;
    const int b = i / (SS * SS);
    const int rem = i - b * (SS * SS);
    const float* q = p.gk + (size_t)b * 3 * SS * SS + rem;
    p.Mb[i] = f2bf((q[0] + 0.9f * q[SS * SS] + 0.81f * q[2 * SS * SS]) * (1.0f / 2.71f));
  } else if (bid < 11264 + 3072) {
    const int idx = bid - 11264;
    const int z = idx >> 6;
    const int rem = idx & 63;
    const int by = rem >> 3, bx = rem & 7;
    const int wi = z / LL, li = z - wi * LL;
    const float* Wl = p.W8[wi] + (size_t)li * DD * DD;
    unsigned short* WTl = p.WT8[wi] + (size_t)li * DD * DD;
    const int n0 = bx << 6, k0 = by << 6;
    const int cx = tid & 63, ry = tid >> 6;
#pragma unroll
    for (int i = 0; i < 16; ++i)
      t[ry + i * 4][cx] = Wl[(size_t)(k0 + ry + i * 4) * DD + n0 + cx];
    __syncthreads();
#pragma unroll
    for (int i = 0; i < 16; ++i)
      WTl[(size_t)(n0 + ry + i * 4) * DD + k0 + cx] = f2bf(t[cx][ry + i * 4]);
  } else {
    const int bid2 = bid - 11264 - 3072;
    int j = 0;
#pragma unroll
    for (int i = 0; i < 8; ++i) if (bid2 >= p.off[i + 1]) j = i + 1;
    const int local = bid2 - p.off[j];
    const int per = p.nbx[j] * p.nby[j];
    const int z = local / per;
    const int rem = local - z * per;
    const int by = rem / p.nbx[j];
    const int bx = rem - by * p.nbx[j];
    const int K = p.K[j], N = p.N[j], Kp = p.Kp[j], Np = p.Np[j];
    const float* Wl = p.W[j] + (size_t)z * K * N;
    unsigned short* WTl = p.WT[j] + (size_t)z * Np * Kp;
    const int n0 = bx << 6, k0 = by << 6;
    const int cx = tid & 63, ry = tid >> 6;
#pragma unroll
    for (int i = 0; i < 16; ++i) {
      const int kk = k0 + ry + i * 4, nn = n0 + cx;
      t[ry + i * 4][cx] = (kk < K && nn < N) ? Wl[(size_t)kk * N + nn] : 0.f;
    }
    __syncthreads();
#pragma unroll
    for (int i = 0; i < 16; ++i) {
      const int nn = n0 + ry + i * 4, kk = k0 + cx;
      if (nn < Np && kk < Kp) WTl[(size_t)nn * Kp + kk] = f2bf(t[cx][ry + i * 4]);
    }
  }
}

// ---------------------------------------------------------------------------
static inline void g1(hipStream_t s, const unsigned short* A, const unsigned short* B,
                      const float* bias, float* C, unsigned short* D,
                      int Kp, int Np, int ldc, int Nreal, int relu)
{
  GemmP p{};
  p.A = A; p.B0 = B; p.bias = bias; p.C = C; p.D0 = D;
  p.Kp = Kp; p.Np = Np; p.ldc = ldc; p.Nreal = Nreal; p.relu = relu;
  gemm_tpl<1, 64, 0, 1><<<dim3(Np >> 6, MM >> 6), 256, 0, s>>>(p);
}

static inline void g1w(hipStream_t s, const unsigned short* A, const unsigned short* B,
                       const float* bias, unsigned short* D, int Kp, int Np, int relu)
{
  GemmP p{};
  p.A = A; p.B0 = B; p.bias = bias; p.D0 = D;
  p.Kp = Kp; p.Np = Np; p.ldc = Np; p.Nreal = Np; p.relu = relu;
  gemm_tpl<1, 128, 0, 1><<<dim3(Np >> 7, MM >> 6), 256, 0, s>>>(p);
}

// split-K: f32 partials to C + z*MM*DD
template<int KS>
static inline void g1k(hipStream_t s, const unsigned short* A, const unsigned short* B,
                       const float* bias, float* C, int Kp)
{
  GemmP p{};
  p.A = A; p.B0 = B; p.bias = bias; p.C = C;
  p.Kp = Kp; p.Np = DD; p.ldc = DD; p.Nreal = DD; p.relu = 0;
  gemm_tpl<1, 64, 0, KS><<<dim3(DD >> 6, MM >> 6, KS), 256, 0, s>>>(p);
}

// QKV fused: D0=Q rows, D1=K rows, D2=V transposed
static inline void g3t(hipStream_t s, const unsigned short* A, const unsigned short* B0,
                       const unsigned short* B1, const unsigned short* B2,
                       unsigned short* D0, unsigned short* D1, unsigned short* D2T)
{
  GemmP p{};
  p.A = A; p.B0 = B0; p.B1 = B1; p.B2 = B2; p.D0 = D0; p.D1 = D1; p.D2 = D2T;
  p.Kp = DD; p.Np = DD; p.ldc = DD; p.Nreal = DD; p.relu = 0;
  gemm_tpl<3, 64, 1, 1><<<dim3(3 * (DD >> 6), MM >> 6), 256, 0, s>>>(p);
}

extern "C" void kernel_launch(void* const* d_in, const int* in_sizes, int n_in,
                              void* d_out, int out_size, void* d_ws, size_t ws_size,
                              hipStream_t stream)
{
  (void)in_sizes; (void)n_in; (void)out_size; (void)ws_size;
  const float* dec_in = (const float*)d_in[0];
  const float* prev   = (const float*)d_in[1];
  const float* gk     = (const float*)d_in[6];
  const float* emb_w1 = (const float*)d_in[7];
  const float* emb_b1 = (const float*)d_in[8];
  const float* emb_w2 = (const float*)d_in[9];
  const float* emb_b2 = (const float*)d_in[10];
  const float* emb_w3 = (const float*)d_in[11];
  const float* emb_b3 = (const float*)d_in[12];
  const float* ln0_g  = (const float*)d_in[13];
  const float* ln0_b  = (const float*)d_in[14];
  const float* wq     = (const float*)d_in[15];
  const float* wk     = (const float*)d_in[16];
  const float* wv     = (const float*)d_in[17];
  const float* wo     = (const float*)d_in[18];
  const float* cq     = (const float*)d_in[19];
  const float* ck     = (const float*)d_in[20];
  const float* cv     = (const float*)d_in[21];
  const float* co     = (const float*)d_in[22];
  const float* ffn_w1 = (const float*)d_in[23];
  const float* ffn_w2 = (const float*)d_in[24];
  const float* ffn_b1 = (const float*)d_in[25];
  const float* ffn_b2 = (const float*)d_in[26];
  const float* ln1_g  = (const float*)d_in[27];
  const float* ln1_b  = (const float*)d_in[28];
  const float* ln2_g  = (const float*)d_in[29];
  const float* ln2_b  = (const float*)d_in[30];
  const float* ln3_g  = (const float*)d_in[31];
  const float* ln3_b  = (const float*)d_in[32];
  const float* p_w1   = (const float*)d_in[33];
  const float* p_b1   = (const float*)d_in[34];
  const float* p_w2   = (const float*)d_in[35];
  const float* p_b2   = (const float*)d_in[36];
  const float* p_w3   = (const float*)d_in[37];
  const float* p_b3   = (const float*)d_in[38];

  // ---- workspace carve ----
  char* wsp = (char*)d_ws;
  auto carve = [&](size_t bytes) { char* r = wsp; wsp += (bytes + 255) & ~(size_t)255; return r; };

  unsigned short* decb  = (unsigned short*)carve((size_t)MM * VP * 2);
  unsigned short* prevb = (unsigned short*)carve((size_t)MM * DD * 2);
  float*          hf    = (float*)carve((size_t)MM * DD * 4);
  unsigned short* hb    = (unsigned short*)carve((size_t)MM * DD * 2);
  float*          xf1   = (float*)carve((size_t)MM * DD * 4);
  unsigned short* tb1   = (unsigned short*)carve((size_t)MM * DFFN * 2);   // 8 MB
  unsigned short* Mbb   = tb1;                                   // alias: first 4 MB
  float*          xf2   = (float*)((char*)tb1 + (size_t)MM * SS * 2);      // alias: last 4 MB
  unsigned short* tb2a  = (unsigned short*)carve((size_t)MM * VP * 2);
  unsigned short* tb2b  = (unsigned short*)carve((size_t)MM * VP * 2);
  unsigned short* qb    = (unsigned short*)carve((size_t)MM * DD * 2);
  unsigned short* kb    = (unsigned short*)carve((size_t)MM * DD * 2);
  unsigned short* vbT   = (unsigned short*)carve((size_t)MM * DD * 2);
  float* kvs = (float*)carve((size_t)MM * 4);
  float* kve = (float*)carve((size_t)MM * 4);
  unsigned short* postabt = (unsigned short*)carve((size_t)DD * SS * 2);
  unsigned short* ew1t  = (unsigned short*)carve((size_t)VP * VP * 2);
  unsigned short* ew2t  = (unsigned short*)carve((size_t)VP * VP * 2);
  unsigned short* ew3t  = (unsigned short*)carve((size_t)DD * VP * 2);
  unsigned short* wqt   = (unsigned short*)carve((size_t)LL * DD * DD * 2);
  unsigned short* wkt   = (unsigned short*)carve((size_t)LL * DD * DD * 2);
  unsigned short* wvt   = (unsigned short*)carve((size_t)LL * DD * DD * 2);
  unsigned short* wot   = (unsigned short*)carve((size_t)LL * DD * DD * 2);
  unsigned short* cqt   = (unsigned short*)carve((size_t)LL * DD * DD * 2);
  unsigned short* ckt   = (unsigned short*)carve((size_t)LL * DD * DD * 2);
  unsigned short* cvt   = (unsigned short*)carve((size_t)LL * DD * DD * 2);
  unsigned short* cot   = (unsigned short*)carve((size_t)LL * DD * DD * 2);
  unsigned short* f1t   = (unsigned short*)carve((size_t)LL * DFFN * DD * 2);
  unsigned short* f2t   = (unsigned short*)carve((size_t)LL * DD * DFFN * 2);
  unsigned short* p1t   = (unsigned short*)carve((size_t)VP * DD * 2);
  unsigned short* p2t   = (unsigned short*)carve((size_t)VP * VP * 2);
  unsigned short* p3t   = (unsigned short*)carve((size_t)VP * VP * 2);
  unsigned short* ckall = (unsigned short*)carve((size_t)LL * MM * DD * 2);  // 12 MB
  unsigned short* cvbT  = (unsigned short*)carve((size_t)LL * MM * DD * 2);  // 12 MB
  float*          xk4   = (float*)carve((size_t)4 * MM * DD * 4);            // 16 MB

  const dim3 agrid(SS / 32, HH, BB);

  // ---- mega prologue (1 launch) ----
  {
    ProP pp{};
    pp.dec_in = dec_in; pp.prev = prev; pp.gk = gk;
    pp.decb = decb; pp.prevb = prevb; pp.tabT = postabt; pp.Mb = Mbb;
    pp.kvs = kvs; pp.kve = kve;
    const float* W8s[8] = {wq, wk, wv, wo, cq, ck, cv, co};
    unsigned short* WT8s[8] = {wqt, wkt, wvt, wot, cqt, ckt, cvt, cot};
    for (int i = 0; i < 8; ++i) { pp.W8[i] = W8s[i]; pp.WT8[i] = WT8s[i]; }
    const float* Ws[8]    = {emb_w1, emb_w2, emb_w3, ffn_w1, ffn_w2, p_w1, p_w2, p_w3};
    unsigned short* Ds[8] = {ew1t, ew2t, ew3t, f1t, f2t, p1t, p2t, p3t};
    const int Ks[8]  = {VV, VV, VV, DD, DFFN, DD, VV, VV};
    const int Ns[8]  = {VV, VV, DD, DFFN, DD, VV, VV, VV};
    const int Kps[8] = {VP, VP, VP, DD, DFFN, DD, VP, VP};
    const int Nps[8] = {VP, VP, DD, DFFN, DD, VP, VP, VP};
    const int nls[8] = {1, 1, 1, LL, LL, 1, 1, 1};
    int off = 0;
    for (int j = 0; j < 8; ++j) {
      pp.W[j] = Ws[j]; pp.WT[j] = Ds[j];
      pp.K[j] = Ks[j]; pp.N[j] = Ns[j]; pp.Kp[j] = Kps[j]; pp.Np[j] = Nps[j];
      pp.nbx[j] = (Nps[j] + 63) / 64; pp.nby[j] = (Kps[j] + 63) / 64;
      pp.off[j] = off;
      off += pp.nbx[j] * pp.nby[j] * nls[j];
    }
    pp.off[8] = off;
    prologue_all<<<11264 + 3072 + off, 256, 0, stream>>>(pp);
  }

  // ---- cross-KV bat (3072) + emb1 (288) + GPE (256) in ONE launch ----
  {
    GemmMultiP p{};
    p.A = prevb;
    for (int i = 0; i < LL; ++i) {
      p.B[2 * i]     = ckt + (size_t)i * DD * DD;
      p.B[2 * i + 1] = cvt + (size_t)i * DD * DD;
      p.D[2 * i]     = ckall + (size_t)i * MM * DD;
      p.D[2 * i + 1] = cvbT + (size_t)i * MM * DD;
    }
    p.eA = decb; p.eB = ew1t; p.ebias = emb_b1; p.eD = tb2a;
    p.gA = Mbb; p.gB = postabt; p.gC = xf2;
    gemm_multi<<<3616, 256, 0, stream>>>(p);
  }

  // ---- rest of embedding MLP ----
  g1(stream, tb2a, ew2t, emb_b2, nullptr, tb2b, VP, VP, VP, VV, 1);
  g1(stream, tb2b, ew3t, emb_b3, xf1, nullptr, VP, DD, DD, DD, 0);
  addln_kernel<1><<<MM / 4, 256, 0, stream>>>(xf1, xf2, ln0_g, ln0_b, hf, hb);

  for (int i = 0; i < LL; ++i) {
    const size_t od = (size_t)i * DD * DD;
    // self attention (V written transposed by the QKV GEMM)
    g3t(stream, hb, wqt + od, wkt + od, wvt + od, qb, kb, vbT);
    attn_kernel<<<agrid, 128, 0, stream>>>(qb, kb, vbT, qb, kvs);
    g1k<2>(stream, qb, wot + od, nullptr, xk4, DD);
    addln_kernel<2><<<MM / 4, 256, 0, stream>>>(hf, xk4, ln1_g + i * DD, ln1_b + i * DD, hf, hb);
    // cross attention with fused Q-projection (K/V precomputed)
    attnx_kernel<<<agrid, 128, 0, stream>>>(hb, cqt + od, ckall + (size_t)i * MM * DD,
                                            cvbT + (size_t)i * MM * DD, qb, kve);
    g1k<2>(stream, qb, cot + od, nullptr, xk4, DD);
    addln_kernel<2><<<MM / 4, 256, 0, stream>>>(hf, xk4, ln2_g + i * DD, ln2_b + i * DD, hf, hb);
    // FFN (ffn2 split-K x4)
    g1w(stream, hb, f1t + (size_t)i * DFFN * DD, ffn_b1 + i * DFFN, tb1, DD, DFFN, 1);
    g1k<4>(stream, tb1, f2t + (size_t)i * DD * DFFN, ffn_b2 + i * DD, xk4, DFFN);
    addln_kernel<4><<<MM / 4, 256, 0, stream>>>(hf, xk4, ln3_g + i * DD, ln3_b + i * DD, hf, hb);
  }

  // ---- output head ----
  g1(stream, hb, p1t, p_b1, nullptr, tb2a, DD, VP, VP, VV, 1);
  g1(stream, tb2a, p2t, p_b2, nullptr, tb2b, VP, VP, VP, VV, 1);
  g1(stream, tb2b, p3t, p_b3, (float*)d_out, nullptr, VP, VP, VV, VV, 0);
}

// Round 14
// 967.215 us; speedup vs baseline: 2.4232x; 1.0045x over previous
//
#include <hip/hip_runtime.h>
#include <hip/hip_bf16.h>
#include <stdint.h>

#define BB 2
#define SS 1024
#define VV 513
#define VP 576          // 513 padded to 9*64
#define DD 512
#define HH 8
#define DKK 64
#define DFFN 2048
#define LL 6
#define MM (BB * SS)    // 2048

typedef __bf16 bf16x8 __attribute__((ext_vector_type(8)));
typedef float f32x4 __attribute__((ext_vector_type(4)));
typedef unsigned short us8 __attribute__((ext_vector_type(8)));
typedef unsigned short us4 __attribute__((ext_vector_type(4)));

static __device__ inline unsigned short f2bf(float f) {
  union { float f; unsigned u; } v; v.f = f;
  unsigned u = v.u;
  unsigned r = (u + 0x7FFFu + ((u >> 16) & 1u)) >> 16;
  return (unsigned short)r;
}

static __device__ inline bf16x8 ldfrag(const unsigned short* p) {
  us8 r = *(const us8*)p;
  return __builtin_bit_cast(bf16x8, r);
}

typedef __attribute__((address_space(3))) void lds_void;
typedef const __attribute__((address_space(1))) void glb_void;
static __device__ inline void gl_lds16(const void* g, void* l) {
  __builtin_amdgcn_global_load_lds((glb_void*)g, (lds_void*)l, 16, 0, 0);
}

// swizzled LDS fragment read: tile rows are linear 128B, byte ^= (row&7)<<4
static __device__ inline bf16x8 ldfrag_swz(const unsigned short* base, int row, int kloc) {
  const unsigned byte = (unsigned)(row * 128 + kloc * 2) ^ (unsigned)((row & 7) << 4);
  return ldfrag((const unsigned short*)((const char*)base + byte));
}

static __device__ inline int rot3(int x) { return (x == 2) ? 0 : x + 1; }

// ---------------------------------------------------------------------------
// core 64x64xK pipelined MFMA accumulate (3-deep counted-vmcnt staging)
// ---------------------------------------------------------------------------
__device__ __forceinline__ void gemm_core64(
    unsigned short* Al, unsigned short* Bl,
    const unsigned short* Abase, const unsigned short* Bbase, int Kp, int nt,
    f32x4 (&acc)[2][2])
{
  const int tid = threadIdx.x;
  const int l = tid & 63, w = tid >> 6;
  const int wm = w >> 1, wn = w & 1;
  const int lr = l & 15, lg = l >> 4;

  auto stage = [&](int buf, int kt) {
    const int k0 = kt << 6;
#pragma unroll
    for (int j = 0; j < 2; ++j) {
      const int ti = j * 256 + tid;
      const int row = ti >> 3;
      const int ch = (ti & 7) ^ (row & 7);
      gl_lds16(Abase + (size_t)row * Kp + k0 + ch * 8, &Al[buf * 4096 + ti * 8]);
    }
#pragma unroll
    for (int j = 0; j < 2; ++j) {
      const int ti = j * 256 + tid;
      const int row = ti >> 3;
      const int ch = (ti & 7) ^ (row & 7);
      gl_lds16(Bbase + (size_t)row * Kp + k0 + ch * 8, &Bl[buf * 4096 + ti * 8]);
    }
  };

  stage(0, 0);
  if (nt > 1) stage(1, 1);
  int cb = 0, sb = 2;
  for (int kt = 0; kt < nt; ++kt) {
    if (kt + 1 < nt) asm volatile("s_waitcnt vmcnt(4)" ::: "memory");
    else             asm volatile("s_waitcnt vmcnt(0)" ::: "memory");
    __builtin_amdgcn_s_barrier();
    if (kt + 2 < nt) { stage(sb, kt + 2); sb = rot3(sb); }
#pragma unroll
    for (int ks = 0; ks < 2; ++ks) {
      bf16x8 af[2], bfv[2];
#pragma unroll
      for (int mf = 0; mf < 2; ++mf)
        af[mf] = ldfrag_swz(Al + cb * 4096, wm * 32 + mf * 16 + lr, ks * 32 + lg * 8);
#pragma unroll
      for (int nf = 0; nf < 2; ++nf)
        bfv[nf] = ldfrag_swz(Bl + cb * 4096, wn * 32 + nf * 16 + lr, ks * 32 + lg * 8);
#pragma unroll
      for (int mf = 0; mf < 2; ++mf)
#pragma unroll
        for (int nf = 0; nf < 2; ++nf)
          acc[mf][nf] = __builtin_amdgcn_mfma_f32_16x16x32_bf16(af[mf], bfv[nf], acc[mf][nf], 0, 0, 0);
    }
    cb = rot3(cb);
  }
}

// ---------------------------------------------------------------------------
// GEMM: C = A[M][Kp](bf16) * B^T, B stored [N][Kp] bf16 (padded).
// TRV: sel==2 output stored transposed into [b][h][dk][s].
// KS: split-K factor (grid.z); partials go to p.C + z*MM*ldc (f32).
// ---------------------------------------------------------------------------
struct GemmP {
  const unsigned short* A;
  const unsigned short* B0; const unsigned short* B1; const unsigned short* B2;
  const float* bias;
  float* C;
  unsigned short* D0; unsigned short* D1; unsigned short* D2;
  int Kp, Np, ldc, Nreal, relu;
};

template<int NB, int NT, int TRV, int KS>
__global__ __launch_bounds__(256)
void gemm_tpl(GemmP p)
{
  constexpr int FN = NT / 32;
  __shared__ unsigned short Al[3][64 * 64];
  __shared__ unsigned short Bl[3][NT * 64];
  const int tid = threadIdx.x;
  const int l = tid & 63, w = tid >> 6;
  const int wm = w >> 1, wn = w & 1;
  const int lr = l & 15, lg = l >> 4;

  const int nbn = p.Np / NT;
  int sel = 0, bx = blockIdx.x;
  if (NB > 1) { sel = bx / nbn; bx -= sel * nbn; }
  const unsigned short* Bmat = p.B0;
  if (NB > 1 && sel == 1) Bmat = p.B1;
  if (NB > 2 && sel == 2) Bmat = p.B2;
  const int m0 = blockIdx.y << 6, n0 = bx * NT;
  const int kz = (KS > 1) ? blockIdx.z : 0;

  f32x4 acc[2][FN];
  const f32x4 zf = {0.f, 0.f, 0.f, 0.f};
#pragma unroll
  for (int i = 0; i < 2; ++i)
#pragma unroll
    for (int j = 0; j < FN; ++j) acc[i][j] = zf;

  const size_t Kp = (size_t)p.Kp;
  const unsigned short* Abase = p.A + (size_t)m0 * Kp;
  const unsigned short* Bbase = Bmat + (size_t)n0 * Kp;
  const int nt = (p.Kp >> 6) / KS;
  const int kb0 = kz * nt;

  auto stage = [&](int buf, int kt) {
    const int k0 = (kb0 + kt) << 6;
#pragma unroll
    for (int j = 0; j < 2; ++j) {
      const int ti = j * 256 + tid;
      const int row = ti >> 3;
      const int ch = (ti & 7) ^ (row & 7);
      gl_lds16(Abase + (size_t)row * Kp + k0 + ch * 8, &Al[buf][ti * 8]);
    }
#pragma unroll
    for (int j = 0; j < FN; ++j) {
      const int ti = j * 256 + tid;
      const int row = ti >> 3;
      const int ch = (ti & 7) ^ (row & 7);
      gl_lds16(Bbase + (size_t)row * Kp + k0 + ch * 8, &Bl[buf][ti * 8]);
    }
  };

  stage(0, 0);
  if (nt > 1) stage(1, 1);
  int cb = 0, sb = 2;

  for (int kt = 0; kt < nt; ++kt) {
    if (kt + 1 < nt) {
      if constexpr (FN == 2) asm volatile("s_waitcnt vmcnt(4)" ::: "memory");
      else                   asm volatile("s_waitcnt vmcnt(6)" ::: "memory");
    } else {
      asm volatile("s_waitcnt vmcnt(0)" ::: "memory");
    }
    __builtin_amdgcn_s_barrier();
    if (kt + 2 < nt) { stage(sb, kt + 2); sb = rot3(sb); }
#pragma unroll
    for (int ks = 0; ks < 2; ++ks) {
      bf16x8 af[2], bfv[FN];
#pragma unroll
      for (int mf = 0; mf < 2; ++mf)
        af[mf] = ldfrag_swz(Al[cb], wm * 32 + mf * 16 + lr, ks * 32 + lg * 8);
#pragma unroll
      for (int nf = 0; nf < FN; ++nf)
        bfv[nf] = ldfrag_swz(Bl[cb], wn * (NT / 2) + nf * 16 + lr, ks * 32 + lg * 8);
#pragma unroll
      for (int mf = 0; mf < 2; ++mf)
#pragma unroll
        for (int nf = 0; nf < FN; ++nf)
          acc[mf][nf] = __builtin_amdgcn_mfma_f32_16x16x32_bf16(af[mf], bfv[nf], acc[mf][nf], 0, 0, 0);
    }
    cb = rot3(cb);
  }

  unsigned short* Dsel = p.D0;
  if (NB > 1 && sel == 1) Dsel = p.D1;
  if (NB > 2 && sel == 2) Dsel = p.D2;

  if (TRV && sel == 2) {
#pragma unroll
    for (int mf = 0; mf < 2; ++mf) {
      const int growb = m0 + wm * 32 + mf * 16 + (lg << 2);
      const int b = growb >> 10, s = growb & 1023;
#pragma unroll
      for (int nf = 0; nf < FN; ++nf) {
        const int gcol = n0 + wn * (NT / 2) + nf * 16 + lr;
        const int h = gcol >> 6, d = gcol & 63;
        us4 t;
#pragma unroll
        for (int r = 0; r < 4; ++r) t[r] = f2bf(acc[mf][nf][r]);
        *(us4*)(Dsel + (((size_t)(b * HH) + h) * DKK + d) * SS + s) = t;
      }
    }
    return;
  }

  float* Cz = p.C ? (p.C + (size_t)kz * MM * p.ldc) : nullptr;
#pragma unroll
  for (int mf = 0; mf < 2; ++mf) {
#pragma unroll
    for (int r = 0; r < 4; ++r) {
      const int grow = m0 + wm * 32 + mf * 16 + (lg << 2) + r;
#pragma unroll
      for (int nf = 0; nf < FN; ++nf) {
        const int gcol = n0 + wn * (NT / 2) + nf * 16 + lr;
        float v = acc[mf][nf][r];
        if (p.bias && kz == 0 && gcol < p.Nreal) v += p.bias[gcol];
        if (p.relu) v = fmaxf(v, 0.f);
        if (Dsel) Dsel[(size_t)grow * p.Np + gcol] = f2bf(v);
        if (Cz && gcol < p.Nreal) Cz[(size_t)grow * p.ldc + gcol] = v;
      }
    }
  }
}

// ---------------------------------------------------------------------------
// Mega GEMM launch: flat job decode.
//   bid <  3072 : cross-KV batched GEMM (12 sel, odd sel -> transposed V)
//   bid <  3360 : emb1  (decb @ ew1t^T, relu+bias, bf16 out, Kp=Np=576)
//   bid <  3616 : GPE   (Mbb @ postabt^T, f32 out, Kp=1024, Np=512)
// ---------------------------------------------------------------------------
struct GemmMultiP {
  const unsigned short* A;            // prevb
  const unsigned short* B[12];
  unsigned short* D[12];
  const unsigned short* eA; const unsigned short* eB; const float* ebias;
  unsigned short* eD;
  const unsigned short* gA; const unsigned short* gB; float* gC;
};

__global__ __launch_bounds__(256)
void gemm_multi(GemmMultiP p)
{
  __shared__ unsigned short Al[3 * 4096];
  __shared__ unsigned short Bl[3 * 4096];
  const int bid = blockIdx.x;
  const int tid = threadIdx.x;
  const int l = tid & 63, w = tid >> 6;
  const int wm = w >> 1, wn = w & 1;
  const int lr = l & 15, lg = l >> 4;
  const f32x4 zf = {0.f, 0.f, 0.f, 0.f};
  f32x4 acc[2][2];
#pragma unroll
  for (int i = 0; i < 2; ++i)
#pragma unroll
    for (int j = 0; j < 2; ++j) acc[i][j] = zf;

  if (bid < 3072) {
    const int sel = bid >> 8;
    const int rem = bid & 255;
    const int by = rem >> 3, bx = rem & 7;
    const int m0 = by << 6, n0 = bx << 6;
    gemm_core64(Al, Bl, p.A + (size_t)m0 * DD, p.B[sel] + (size_t)n0 * DD, DD, 8, acc);
    unsigned short* Dmat = p.D[sel];
    if (sel & 1) {
#pragma unroll
      for (int mf = 0; mf < 2; ++mf) {
        const int growb = m0 + wm * 32 + mf * 16 + (lg << 2);
        const int b = growb >> 10, s = growb & 1023;
#pragma unroll
        for (int nf = 0; nf < 2; ++nf) {
          const int gcol = n0 + wn * 32 + nf * 16 + lr;
          const int h = gcol >> 6, d = gcol & 63;
          us4 t;
#pragma unroll
          for (int r = 0; r < 4; ++r) t[r] = f2bf(acc[mf][nf][r]);
          *(us4*)(Dmat + (((size_t)(b * HH) + h) * DKK + d) * SS + s) = t;
        }
      }
    } else {
#pragma unroll
      for (int mf = 0; mf < 2; ++mf)
#pragma unroll
        for (int r = 0; r < 4; ++r) {
          const int grow = m0 + wm * 32 + mf * 16 + (lg << 2) + r;
#pragma unroll
          for (int nf = 0; nf < 2; ++nf) {
            const int gcol = n0 + wn * 32 + nf * 16 + lr;
            Dmat[(size_t)grow * DD + gcol] = f2bf(acc[mf][nf][r]);
          }
        }
    }
  } else if (bid < 3360) {
    const int local = bid - 3072;
    const int by = local / 9, bx = local - by * 9;
    const int m0 = by << 6, n0 = bx << 6;
    gemm_core64(Al, Bl, p.eA + (size_t)m0 * VP, p.eB + (size_t)n0 * VP, VP, 9, acc);
#pragma unroll
    for (int mf = 0; mf < 2; ++mf)
#pragma unroll
      for (int r = 0; r < 4; ++r) {
        const int grow = m0 + wm * 32 + mf * 16 + (lg << 2) + r;
#pragma unroll
        for (int nf = 0; nf < 2; ++nf) {
          const int gcol = n0 + wn * 32 + nf * 16 + lr;
          float v = acc[mf][nf][r];
          if (gcol < VV) v += p.ebias[gcol];
          v = fmaxf(v, 0.f);
          p.eD[(size_t)grow * VP + gcol] = f2bf(v);
        }
      }
  } else {
    const int local = bid - 3360;
    const int by = local >> 3, bx = local & 7;
    const int m0 = by << 6, n0 = bx << 6;
    gemm_core64(Al, Bl, p.gA + (size_t)m0 * SS, p.gB + (size_t)n0 * SS, SS, 16, acc);
#pragma unroll
    for (int mf = 0; mf < 2; ++mf)
#pragma unroll
      for (int r = 0; r < 4; ++r) {
        const int grow = m0 + wm * 32 + mf * 16 + (lg << 2) + r;
#pragma unroll
        for (int nf = 0; nf < 2; ++nf) {
          const int gcol = n0 + wn * 32 + nf * 16 + lr;
          p.gC[(size_t)grow * DD + gcol] = acc[mf][nf][r];
        }
      }
  }
}

// ---------------------------------------------------------------------------
// Self-attention (causal): QBLK=32, 2 waves split KV (wave w: tiles ≡w mod 2).
// ---------------------------------------------------------------------------
__global__ __launch_bounds__(128)
void attn_kernel(const unsigned short* __restrict__ Qb,
                 const unsigned short* __restrict__ Kb,
                 const unsigned short* __restrict__ VbT,
                 unsigned short* __restrict__ Ob,
                 const float* __restrict__ maskadd)
{
  __shared__ unsigned short Kl[2][2][64 * 64];
  __shared__ unsigned short Vl[2][2][64 * 64];
  __shared__ char PC[9216];
  unsigned short* Pl = (unsigned short*)PC;
  float (*comb)[66] = (float(*)[66])PC;

  const int tid = threadIdx.x;
  const int l = tid & 63, w = tid >> 6;
  const int qt = blockIdx.x, h = blockIdx.y, b = blockIdx.z;
  const int lr = l & 15, lg = l >> 4;

  bf16x8 qf[2][2];
#pragma unroll
  for (int mf = 0; mf < 2; ++mf) {
    const unsigned short* qrow = Qb + ((size_t)(b * SS) + qt * 32 + mf * 16 + lr) * DD + h * DKK;
    qf[mf][0] = ldfrag(qrow + (lg << 3));
    qf[mf][1] = ldfrag(qrow + 32 + (lg << 3));
  }

  const unsigned short* Kbase = Kb + (size_t)(b * SS) * DD + h * DKK;
  const unsigned short* Vbase = VbT + ((size_t)(b * HH) + h) * DKK * SS;

  auto stage = [&](int buf, int kt) {
#pragma unroll
    for (int j = 0; j < 8; ++j) {
      const int ti = j * 64 + l;
      const int row = ti >> 3;
      const int ch = (ti & 7) ^ (row & 7);
      gl_lds16(Kbase + (size_t)(kt * 64 + row) * DD + ch * 8, &Kl[w][buf][ti * 8]);
    }
#pragma unroll
    for (int j = 0; j < 8; ++j) {
      const int ti = j * 64 + l;
      const int row = ti >> 3;
      const int ch = (ti & 7) ^ (row & 7);
      gl_lds16(Vbase + (size_t)row * SS + kt * 64 + ch * 8, &Vl[w][buf][ti * 8]);
    }
  };

  f32x4 accO[2][4];
  const f32x4 zf = {0.f, 0.f, 0.f, 0.f};
#pragma unroll
  for (int mf = 0; mf < 2; ++mf)
#pragma unroll
    for (int nf = 0; nf < 4; ++nf) accO[mf][nf] = zf;
  float mold[2][4], lsum[2][4];
#pragma unroll
  for (int mf = 0; mf < 2; ++mf)
#pragma unroll
    for (int r = 0; r < 4; ++r) { mold[mf][r] = -1e30f; lsum[mf][r] = 0.f; }

  const int ktmax = (qt >> 1) + 1;
  const int myn = (ktmax - w + 1) >> 1;

  if (myn > 0) stage(0, w);
  int buf = 0;

  for (int i = 0; i < myn; ++i) {
    const int kt = w + 2 * i;
    if (i + 1 < myn) {
      stage(buf ^ 1, kt + 2);
      asm volatile("s_waitcnt vmcnt(16)" ::: "memory");
    } else {
      asm volatile("s_waitcnt vmcnt(0)" ::: "memory");
    }
    const unsigned short* KB = &Kl[w][buf][0];
    const unsigned short* VB = &Vl[w][buf][0];
    float sc[2][4][4];
    __builtin_amdgcn_s_setprio(1);
#pragma unroll
    for (int nf = 0; nf < 4; ++nf) {
      bf16x8 k0 = ldfrag_swz(KB, nf * 16 + lr, lg * 8);
      bf16x8 k1 = ldfrag_swz(KB, nf * 16 + lr, 32 + lg * 8);
      const int kglob = kt * 64 + nf * 16 + lr;
      const float madd = maskadd[b * SS + kglob];
#pragma unroll
      for (int mf = 0; mf < 2; ++mf) {
        f32x4 s = zf;
        s = __builtin_amdgcn_mfma_f32_16x16x32_bf16(qf[mf][0], k0, s, 0, 0, 0);
        s = __builtin_amdgcn_mfma_f32_16x16x32_bf16(qf[mf][1], k1, s, 0, 0, 0);
#pragma unroll
        for (int r = 0; r < 4; ++r) {
          const int qglob = qt * 32 + mf * 16 + (lg << 2) + r;
          sc[mf][nf][r] = (kglob > qglob) ? -1e9f : s[r] * 0.125f + madd;
        }
      }
    }
    __builtin_amdgcn_s_setprio(0);
#pragma unroll
    for (int mf = 0; mf < 2; ++mf)
#pragma unroll
      for (int r = 0; r < 4; ++r) {
        float mloc = fmaxf(fmaxf(sc[mf][0][r], sc[mf][1][r]), fmaxf(sc[mf][2][r], sc[mf][3][r]));
#pragma unroll
        for (int off = 1; off < 16; off <<= 1)
          mloc = fmaxf(mloc, __shfl_xor(mloc, off, 64));
        const float mnew = fmaxf(mold[mf][r], mloc);
        const float corr = __expf(mold[mf][r] - mnew);
        float ps = 0.f;
#pragma unroll
        for (int nf = 0; nf < 4; ++nf) {
          const float pv = __expf(sc[mf][nf][r] - mnew);
          sc[mf][nf][r] = pv;
          ps += pv;
        }
#pragma unroll
        for (int off = 1; off < 16; off <<= 1)
          ps += __shfl_xor(ps, off, 64);
        lsum[mf][r] = lsum[mf][r] * corr + ps;
#pragma unroll
        for (int nf = 0; nf < 4; ++nf) accO[mf][nf][r] *= corr;
        mold[mf][r] = mnew;
      }
    unsigned short* pw = Pl + w * 32 * 72;
#pragma unroll
    for (int mf = 0; mf < 2; ++mf)
#pragma unroll
      for (int nf = 0; nf < 4; ++nf)
#pragma unroll
        for (int r = 0; r < 4; ++r)
          pw[(mf * 16 + (lg << 2) + r) * 72 + nf * 16 + lr] = f2bf(sc[mf][nf][r]);
    bf16x8 pa[2][2];
#pragma unroll
    for (int mf = 0; mf < 2; ++mf) {
      pa[mf][0] = ldfrag(&pw[(mf * 16 + lr) * 72 + (lg << 3)]);
      pa[mf][1] = ldfrag(&pw[(mf * 16 + lr) * 72 + 32 + (lg << 3)]);
    }
    __builtin_amdgcn_s_setprio(1);
#pragma unroll
    for (int nf = 0; nf < 4; ++nf) {
      bf16x8 v0 = ldfrag_swz(VB, nf * 16 + lr, lg * 8);
      bf16x8 v1 = ldfrag_swz(VB, nf * 16 + lr, 32 + lg * 8);
#pragma unroll
      for (int mf = 0; mf < 2; ++mf) {
        accO[mf][nf] = __builtin_amdgcn_mfma_f32_16x16x32_bf16(pa[mf][0], v0, accO[mf][nf], 0, 0, 0);
        accO[mf][nf] = __builtin_amdgcn_mfma_f32_16x16x32_bf16(pa[mf][1], v1, accO[mf][nf], 0, 0, 0);
      }
    }
    __builtin_amdgcn_s_setprio(0);
    buf ^= 1;
  }

  __syncthreads();
  if (w == 1) {
#pragma unroll
    for (int mf = 0; mf < 2; ++mf)
#pragma unroll
      for (int r = 0; r < 4; ++r) {
        const int qrow = mf * 16 + (lg << 2) + r;
#pragma unroll
        for (int nf = 0; nf < 4; ++nf)
          comb[qrow][nf * 16 + lr] = accO[mf][nf][r];
        if (lr == 0) { comb[qrow][64] = mold[mf][r]; comb[qrow][65] = lsum[mf][r]; }
      }
  }
  __syncthreads();
  if (w == 0) {
#pragma unroll
    for (int mf = 0; mf < 2; ++mf)
#pragma unroll
      for (int r = 0; r < 4; ++r) {
        const int qrow = mf * 16 + (lg << 2) + r;
        const float m1 = comb[qrow][64], l1 = comb[qrow][65];
        const float m0v = mold[mf][r], l0 = lsum[mf][r];
        const float ms = fmaxf(m0v, m1);
        const float f0 = __expf(m0v - ms), f1 = __expf(m1 - ms);
        const float inv = 1.f / (l0 * f0 + l1 * f1);
        const size_t orow = ((size_t)(b * SS) + qt * 32 + mf * 16 + (lg << 2) + r) * DD + h * DKK;
#pragma unroll
        for (int nf = 0; nf < 4; ++nf)
          Ob[orow + nf * 16 + lr] =
              f2bf((accO[mf][nf][r] * f0 + comb[qrow][nf * 16 + lr] * f1) * inv);
      }
  }
}

// ---------------------------------------------------------------------------
// Cross-attention with FUSED Q-projection (scale folded into Q).
// ---------------------------------------------------------------------------
__global__ __launch_bounds__(128)
void attnx_kernel(const unsigned short* __restrict__ Hb,
                  const unsigned short* __restrict__ Wq,
                  const unsigned short* __restrict__ Kb,
                  const unsigned short* __restrict__ VbT,
                  unsigned short* __restrict__ Ob,
                  const float* __restrict__ maskadd)
{
  __shared__ unsigned short Kl[2][2][64 * 64];
  __shared__ unsigned short Vl[2][2][64 * 64];
  __shared__ char PC[9216];
  unsigned short* Pl = (unsigned short*)PC;
  float (*comb)[66] = (float(*)[66])PC;
  unsigned short* QA = &Kl[0][0][0];
  unsigned short* QB = &Vl[0][0][0];
  unsigned short* Ql = (unsigned short*)PC;

  const int tid = threadIdx.x;
  const int l = tid & 63, w = tid >> 6;
  const int qt = blockIdx.x, h = blockIdx.y, b = blockIdx.z;
  const int lr = l & 15, lg = l >> 4;

  {
    const unsigned short* Abase = Hb + ((size_t)(b * SS) + qt * 32) * DD;
    const unsigned short* Bbase = Wq + (size_t)(h * DKK) * DD;
    auto stage_q = [&](int buf, int kt) {
      const int k0 = kt << 6;
#pragma unroll
      for (int j = 0; j < 2; ++j) {
        const int ti = j * 128 + tid;
        const int row = ti >> 3;
        const int ch = (ti & 7) ^ (row & 7);
        gl_lds16(Abase + (size_t)row * DD + k0 + ch * 8, &QA[buf * 2048 + ti * 8]);
      }
#pragma unroll
      for (int j = 0; j < 4; ++j) {
        const int ti = j * 128 + tid;
        const int row = ti >> 3;
        const int ch = (ti & 7) ^ (row & 7);
        gl_lds16(Bbase + (size_t)row * DD + k0 + ch * 8, &QB[buf * 4096 + ti * 8]);
      }
    };
    f32x4 qacc[2][2];
    const f32x4 zf = {0.f, 0.f, 0.f, 0.f};
#pragma unroll
    for (int i = 0; i < 2; ++i)
#pragma unroll
      for (int j = 0; j < 2; ++j) qacc[i][j] = zf;

    stage_q(0, 0);
    for (int kt = 0; kt < 8; ++kt) {
      if (kt + 1 < 8) {
        stage_q((kt + 1) & 1, kt + 1);
        asm volatile("s_waitcnt vmcnt(6)" ::: "memory");
      } else {
        asm volatile("s_waitcnt vmcnt(0)" ::: "memory");
      }
      __builtin_amdgcn_s_barrier();
      const unsigned short* qa = &QA[(kt & 1) * 2048];
      const unsigned short* qbuf = &QB[(kt & 1) * 4096];
#pragma unroll
      for (int ks = 0; ks < 2; ++ks) {
        bf16x8 af[2], bfv[2];
#pragma unroll
        for (int mf = 0; mf < 2; ++mf)
          af[mf] = ldfrag_swz(qa, mf * 16 + lr, ks * 32 + lg * 8);
#pragma unroll
        for (int nf = 0; nf < 2; ++nf)
          bfv[nf] = ldfrag_swz(qbuf, w * 32 + nf * 16 + lr, ks * 32 + lg * 8);
#pragma unroll
        for (int mf = 0; mf < 2; ++mf)
#pragma unroll
          for (int nf = 0; nf < 2; ++nf)
            qacc[mf][nf] = __builtin_amdgcn_mfma_f32_16x16x32_bf16(af[mf], bfv[nf], qacc[mf][nf], 0, 0, 0);
      }
      __builtin_amdgcn_s_barrier();
    }
#pragma unroll
    for (int mf = 0; mf < 2; ++mf)
#pragma unroll
      for (int nf = 0; nf < 2; ++nf)
#pragma unroll
        for (int r = 0; r < 4; ++r)
          Ql[(mf * 16 + (lg << 2) + r) * 72 + w * 32 + nf * 16 + lr] = f2bf(qacc[mf][nf][r] * 0.125f);
    __syncthreads();
  }
  bf16x8 qf[2][2];
#pragma unroll
  for (int mf = 0; mf < 2; ++mf) {
    qf[mf][0] = ldfrag(&Ql[(mf * 16 + lr) * 72 + (lg << 3)]);
    qf[mf][1] = ldfrag(&Ql[(mf * 16 + lr) * 72 + 32 + (lg << 3)]);
  }
  __syncthreads();

  const unsigned short* Kbase = Kb + (size_t)(b * SS) * DD + h * DKK;
  const unsigned short* Vbase = VbT + ((size_t)(b * HH) + h) * DKK * SS;

  auto stage = [&](int buf, int kt) {
#pragma unroll
    for (int j = 0; j < 8; ++j) {
      const int ti = j * 64 + l;
      const int row = ti >> 3;
      const int ch = (ti & 7) ^ (row & 7);
      gl_lds16(Kbase + (size_t)(kt * 64 + row) * DD + ch * 8, &Kl[w][buf][ti * 8]);
    }
#pragma unroll
    for (int j = 0; j < 8; ++j) {
      const int ti = j * 64 + l;
      const int row = ti >> 3;
      const int ch = (ti & 7) ^ (row & 7);
      gl_lds16(Vbase + (size_t)row * SS + kt * 64 + ch * 8, &Vl[w][buf][ti * 8]);
    }
  };

  f32x4 accO[2][4];
  const f32x4 zf = {0.f, 0.f, 0.f, 0.f};
#pragma unroll
  for (int mf = 0; mf < 2; ++mf)
#pragma unroll
    for (int nf = 0; nf < 4; ++nf) accO[mf][nf] = zf;
  float mold[2][4], lsum[2][4];
#pragma unroll
  for (int mf = 0; mf < 2; ++mf)
#pragma unroll
    for (int r = 0; r < 4; ++r) { mold[mf][r] = -1e30f; lsum[mf][r] = 0.f; }

  const int myn = (SS / 64 - w + 1) >> 1;
  stage(0, w);
  int buf = 0;

  for (int i = 0; i < myn; ++i) {
    const int kt = w + 2 * i;
    if (i + 1 < myn) {
      stage(buf ^ 1, kt + 2);
      asm volatile("s_waitcnt vmcnt(16)" ::: "memory");
    } else {
      asm volatile("s_waitcnt vmcnt(0)" ::: "memory");
    }
    const unsigned short* KB = &Kl[w][buf][0];
    const unsigned short* VB = &Vl[w][buf][0];
    float sc[2][4][4];
    __builtin_amdgcn_s_setprio(1);
#pragma unroll
    for (int nf = 0; nf < 4; ++nf) {
      bf16x8 k0 = ldfrag_swz(KB, nf * 16 + lr, lg * 8);
      bf16x8 k1 = ldfrag_swz(KB, nf * 16 + lr, 32 + lg * 8);
      const int kglob = kt * 64 + nf * 16 + lr;
      const float madd = maskadd[b * SS + kglob];
#pragma unroll
      for (int mf = 0; mf < 2; ++mf) {
        f32x4 s = zf;
        s = __builtin_amdgcn_mfma_f32_16x16x32_bf16(qf[mf][0], k0, s, 0, 0, 0);
        s = __builtin_amdgcn_mfma_f32_16x16x32_bf16(qf[mf][1], k1, s, 0, 0, 0);
#pragma unroll
        for (int r = 0; r < 4; ++r)
          sc[mf][nf][r] = s[r] + madd;
      }
    }
    __builtin_amdgcn_s_setprio(0);
#pragma unroll
    for (int mf = 0; mf < 2; ++mf)
#pragma unroll
      for (int r = 0; r < 4; ++r) {
        float mloc = fmaxf(fmaxf(sc[mf][0][r], sc[mf][1][r]), fmaxf(sc[mf][2][r], sc[mf][3][r]));
#pragma unroll
        for (int off = 1; off < 16; off <<= 1)
          mloc = fmaxf(mloc, __shfl_xor(mloc, off, 64));
        const float mnew = fmaxf(mold[mf][r], mloc);
        const float corr = __expf(mold[mf][r] - mnew);
        float ps = 0.f;
#pragma unroll
        for (int nf = 0; nf < 4; ++nf) {
          const float pv = __expf(sc[mf][nf][r] - mnew);
          sc[mf][nf][r] = pv;
          ps += pv;
        }
#pragma unroll
        for (int off = 1; off < 16; off <<= 1)
          ps += __shfl_xor(ps, off, 64);
        lsum[mf][r] = lsum[mf][r] * corr + ps;
#pragma unroll
        for (int nf = 0; nf < 4; ++nf) accO[mf][nf][r] *= corr;
        mold[mf][r] = mnew;
      }
    unsigned short* pw = Pl + w * 32 * 72;
#pragma unroll
    for (int mf = 0; mf < 2; ++mf)
#pragma unroll
      for (int nf = 0; nf < 4; ++nf)
#pragma unroll
        for (int r = 0; r < 4; ++r)
          pw[(mf * 16 + (lg << 2) + r) * 72 + nf * 16 + lr] = f2bf(sc[mf][nf][r]);
    bf16x8 pa[2][2];
#pragma unroll
    for (int mf = 0; mf < 2; ++mf) {
      pa[mf][0] = ldfrag(&pw[(mf * 16 + lr) * 72 + (lg << 3)]);
      pa[mf][1] = ldfrag(&pw[(mf * 16 + lr) * 72 + 32 + (lg << 3)]);
    }
    __builtin_amdgcn_s_setprio(1);
#pragma unroll
    for (int nf = 0; nf < 4; ++nf) {
      bf16x8 v0 = ldfrag_swz(VB, nf * 16 + lr, lg * 8);
      bf16x8 v1 = ldfrag_swz(VB, nf * 16 + lr, 32 + lg * 8);
#pragma unroll
      for (int mf = 0; mf < 2; ++mf) {
        accO[mf][nf] = __builtin_amdgcn_mfma_f32_16x16x32_bf16(pa[mf][0], v0, accO[mf][nf], 0, 0, 0);
        accO[mf][nf] = __builtin_amdgcn_mfma_f32_16x16x32_bf16(pa[mf][1], v1, accO[mf][nf], 0, 0, 0);
      }
    }
    __builtin_amdgcn_s_setprio(0);
    buf ^= 1;
  }

  __syncthreads();
  if (w == 1) {
#pragma unroll
    for (int mf = 0; mf < 2; ++mf)
#pragma unroll
      for (int r = 0; r < 4; ++r) {
        const int qrow = mf * 16 + (lg << 2) + r;
#pragma unroll
        for (int nf = 0; nf < 4; ++nf)
          comb[qrow][nf * 16 + lr] = accO[mf][nf][r];
        if (lr == 0) { comb[qrow][64] = mold[mf][r]; comb[qrow][65] = lsum[mf][r]; }
      }
  }
  __syncthreads();
  if (w == 0) {
#pragma unroll
    for (int mf = 0; mf < 2; ++mf)
#pragma unroll
      for (int r = 0; r < 4; ++r) {
        const int qrow = mf * 16 + (lg << 2) + r;
        const float m1 = comb[qrow][64], l1 = comb[qrow][65];
        const float m0v = mold[mf][r], l0 = lsum[mf][r];
        const float ms = fmaxf(m0v, m1);
        const float f0 = __expf(m0v - ms), f1 = __expf(m1 - ms);
        const float inv = 1.f / (l0 * f0 + l1 * f1);
        const size_t orow = ((size_t)(b * SS) + qt * 32 + mf * 16 + (lg << 2) + r) * DD + h * DKK;
#pragma unroll
        for (int nf = 0; nf < 4; ++nf)
          Ob[orow + nf * 16 + lr] =
              f2bf((accO[mf][nf][r] * f0 + comb[qrow][nf * 16 + lr] * f1) * inv);
      }
  }
}

// ---------------------------------------------------------------------------
// out = LN(a + sum_p c_p); 4 rows per block, vectorized. P = #partials.
// ---------------------------------------------------------------------------
template<int P>
__global__ __launch_bounds__(256)
void addln_kernel(const float* __restrict__ a, const float* __restrict__ c,
                  const float* __restrict__ g, const float* __restrict__ bb,
                  float* __restrict__ hf, unsigned short* __restrict__ hb)
{
  const int row = blockIdx.x * 4 + (threadIdx.x >> 6);
  const int l = threadIdx.x & 63;
  const float* ar = a + (size_t)row * DD + l * 8;
  f32x4 x0 = *(const f32x4*)ar;
  f32x4 x1 = *(const f32x4*)(ar + 4);
#pragma unroll
  for (int pp = 0; pp < P; ++pp) {
    const float* cr = c + (size_t)pp * MM * DD + (size_t)row * DD + l * 8;
    x0 += *(const f32x4*)cr;
    x1 += *(const f32x4*)(cr + 4);
  }
  float sum = x0[0] + x0[1] + x0[2] + x0[3] + x1[0] + x1[1] + x1[2] + x1[3];
#pragma unroll
  for (int off = 1; off < 64; off <<= 1) sum += __shfl_xor(sum, off, 64);
  const float mean = sum * (1.f / 512.f);
  float vs = 0.f;
#pragma unroll
  for (int j = 0; j < 4; ++j) { float d0 = x0[j] - mean; float d1 = x1[j] - mean; vs += d0 * d0 + d1 * d1; }
#pragma unroll
  for (int off = 1; off < 64; off <<= 1) vs += __shfl_xor(vs, off, 64);
  const float rs = rsqrtf(vs * (1.f / 512.f) + 1e-6f);
  const f32x4 g0 = *(const f32x4*)(g + l * 8), g1 = *(const f32x4*)(g + l * 8 + 4);
  const f32x4 b0 = *(const f32x4*)(bb + l * 8), b1 = *(const f32x4*)(bb + l * 8 + 4);
  f32x4 o0, o1;
  us8 ob;
#pragma unroll
  for (int j = 0; j < 4; ++j) {
    o0[j] = (x0[j] - mean) * rs * g0[j] + b0[j];
    o1[j] = (x1[j] - mean) * rs * g1[j] + b1[j];
    ob[j] = f2bf(o0[j]); ob[j + 4] = f2bf(o1[j]);
  }
  float* of = hf + (size_t)row * DD + l * 8;
  *(f32x4*)of = o0; *(f32x4*)(of + 4) = o1;
  *(us8*)(hb + (size_t)row * DD + l * 8) = ob;
}

// ---------------------------------------------------------------------------
// Mega prologue (vectorized stores):
//   [0,1024)        prep rows (dec/prev -> bf16 + mask)
//   [1024,1280)     postable: 8 elems/thread, us8 store
//   [1280,2304)     gpec: 8 elems/thread, f32x4 loads, us8 store
//   [2304,5376)     wconv8: 64x64 transpose, us8 store
//   [5376,...)      wconv jobs: guarded transpose, us8 store
// ---------------------------------------------------------------------------
struct ProP {
  const float *dec_in, *prev, *gk;
  unsigned short *decb, *prevb, *tabT, *Mb;
  float *kvs, *kve;
  const float* W8[8]; unsigned short* WT8[8];
  const float* W[8]; unsigned short* WT[8];
  int K[8], N[8], Kp[8], Np[8], nbx[8], nby[8];
  int off[9];
};

__global__ __launch_bounds__(256)
void prologue_all(ProP p)
{
  __shared__ float t[64][65];
  const int bid = blockIdx.x, tid = threadIdx.x;
  if (bid < 1024) {
    const int isdec = bid < 512;
    const int row = (isdec ? bid : bid - 512) * 4 + (tid >> 6);
    const int l = tid & 63;
    const int NC = isdec ? VV : DD, NP = isdec ? VP : DD;
    const float* xr = (isdec ? p.dec_in : p.prev) + (size_t)row * NC;
    unsigned short* ob = (isdec ? p.decb : p.prevb) + (size_t)row * NP;
    int ok = 1;
    for (int j = l; j < NP; j += 64) {
      if (j < NC) {
        const float v = xr[j];
        ok &= (v != -1.0f) ? 1 : 0;
        ob[j] = f2bf(v);
      } else ob[j] = 0;
    }
    ok = __all(ok) ? 1 : 0;
    if (l == 0) (isdec ? p.kvs : p.kve)[row] = ok ? 0.f : -1e9f;
  } else if (bid < 1280) {
    const int base = (bid - 1024) * 2048 + tid * 8;
    const int d = base >> 10;
    const float ex = (float)(2 * (d >> 1)) * (1.0f / (float)DD);
    const float freq = exp2f(ex * -13.287712379549449f);
    us8 o;
#pragma unroll
    for (int e = 0; e < 8; ++e) {
      const int s = (base + e) & 1023;
      const float ang = (float)s * freq;
      o[e] = f2bf((d & 1) ? cosf(ang) : sinf(ang));
    }
    *(us8*)(p.tabT + base) = o;
  } else if (bid < 2304) {
    const int base = (bid - 1280) * 2048 + tid * 8;
    const int b = base / (SS * SS);
    const int rem = base - b * (SS * SS);
    const float* q = p.gk + (size_t)b * 3 * SS * SS + rem;
    f32x4 a0 = *(const f32x4*)q,               a1 = *(const f32x4*)(q + 4);
    f32x4 b0 = *(const f32x4*)(q + SS * SS),   b1 = *(const f32x4*)(q + SS * SS + 4);
    f32x4 c0 = *(const f32x4*)(q + 2 * SS * SS), c1 = *(const f32x4*)(q + 2 * SS * SS + 4);
    us8 o;
#pragma unroll
    for (int e = 0; e < 4; ++e) {
      o[e]     = f2bf((a0[e] + 0.9f * b0[e] + 0.81f * c0[e]) * (1.0f / 2.71f));
      o[e + 4] = f2bf((a1[e] + 0.9f * b1[e] + 0.81f * c1[e]) * (1.0f / 2.71f));
    }
    *(us8*)(p.Mb + base) = o;
  } else if (bid < 5376) {
    const int idx = bid - 2304;
    const int z = idx >> 6;
    const int rem = idx & 63;
    const int by = rem >> 3, bx = rem & 7;
    const int wi = z / LL, li = z - wi * LL;
    const float* Wl = p.W8[wi] + (size_t)li * DD * DD;
    unsigned short* WTl = p.WT8[wi] + (size_t)li * DD * DD;
    const int n0 = bx << 6, k0 = by << 6;
    const int cx = tid & 63, ry = tid >> 6;
#pragma unroll
    for (int i = 0; i < 16; ++i)
      t[ry + i * 4][cx] = Wl[(size_t)(k0 + ry + i * 4) * DD + n0 + cx];
    __syncthreads();
#pragma unroll
    for (int i = 0; i < 2; ++i) {
      const int flat = i * 2048 + tid * 8;
      const int nn = flat >> 6, kk = flat & 63;
      us8 o;
#pragma unroll
      for (int e = 0; e < 8; ++e) o[e] = f2bf(t[kk + e][nn]);
      *(us8*)(WTl + (size_t)(n0 + nn) * DD + k0 + kk) = o;
    }
  } else {
    const int bid2 = bid - 5376;
    int j = 0;
#pragma unroll
    for (int i = 0; i < 8; ++i) if (bid2 >= p.off[i + 1]) j = i + 1;
    const int local = bid2 - p.off[j];
    const int per = p.nbx[j] * p.nby[j];
    const int z = local / per;
    const int rem = local - z * per;
    const int by = rem / p.nbx[j];
    const int bx = rem - by * p.nbx[j];
    const int K = p.K[j], N = p.N[j], Kp = p.Kp[j], Np = p.Np[j];
    const float* Wl = p.W[j] + (size_t)z * K * N;
    unsigned short* WTl = p.WT[j] + (size_t)z * Np * Kp;
    const int n0 = bx << 6, k0 = by << 6;
    const int cx = tid & 63, ry = tid >> 6;
#pragma unroll
    for (int i = 0; i < 16; ++i) {
      const int kk = k0 + ry + i * 4, nn = n0 + cx;
      t[ry + i * 4][cx] = (kk < K && nn < N) ? Wl[(size_t)kk * N + nn] : 0.f;
    }
    __syncthreads();
#pragma unroll
    for (int i = 0; i < 2; ++i) {
      const int flat = i * 2048 + tid * 8;
      const int nn = flat >> 6, kk = flat & 63;
      us8 o;
#pragma unroll
      for (int e = 0; e < 8; ++e) o[e] = f2bf(t[kk + e][nn]);
      *(us8*)(WTl + (size_t)(n0 + nn) * Kp + k0 + kk) = o;
    }
  }
}

// ---------------------------------------------------------------------------
static inline void g1(hipStream_t s, const unsigned short* A, const unsigned short* B,
                      const float* bias, float* C, unsigned short* D,
                      int Kp, int Np, int ldc, int Nreal, int relu)
{
  GemmP p{};
  p.A = A; p.B0 = B; p.bias = bias; p.C = C; p.D0 = D;
  p.Kp = Kp; p.Np = Np; p.ldc = ldc; p.Nreal = Nreal; p.relu = relu;
  gemm_tpl<1, 64, 0, 1><<<dim3(Np >> 6, MM >> 6), 256, 0, s>>>(p);
}

static inline void g1w(hipStream_t s, const unsigned short* A, const unsigned short* B,
                       const float* bias, unsigned short* D, int Kp, int Np, int relu)
{
  GemmP p{};
  p.A = A; p.B0 = B; p.bias = bias; p.D0 = D;
  p.Kp = Kp; p.Np = Np; p.ldc = Np; p.Nreal = Np; p.relu = relu;
  gemm_tpl<1, 128, 0, 1><<<dim3(Np >> 7, MM >> 6), 256, 0, s>>>(p);
}

// split-K: f32 partials to C + z*MM*DD
template<int KS>
static inline void g1k(hipStream_t s, const unsigned short* A, const unsigned short* B,
                       const float* bias, float* C, int Kp)
{
  GemmP p{};
  p.A = A; p.B0 = B; p.bias = bias; p.C = C;
  p.Kp = Kp; p.Np = DD; p.ldc = DD; p.Nreal = DD; p.relu = 0;
  gemm_tpl<1, 64, 0, KS><<<dim3(DD >> 6, MM >> 6, KS), 256, 0, s>>>(p);
}

// QKV fused: D0=Q rows, D1=K rows, D2=V transposed
static inline void g3t(hipStream_t s, const unsigned short* A, const unsigned short* B0,
                       const unsigned short* B1, const unsigned short* B2,
                       unsigned short* D0, unsigned short* D1, unsigned short* D2T)
{
  GemmP p{};
  p.A = A; p.B0 = B0; p.B1 = B1; p.B2 = B2; p.D0 = D0; p.D1 = D1; p.D2 = D2T;
  p.Kp = DD; p.Np = DD; p.ldc = DD; p.Nreal = DD; p.relu = 0;
  gemm_tpl<3, 64, 1, 1><<<dim3(3 * (DD >> 6), MM >> 6), 256, 0, s>>>(p);
}

extern "C" void kernel_launch(void* const* d_in, const int* in_sizes, int n_in,
                              void* d_out, int out_size, void* d_ws, size_t ws_size,
                              hipStream_t stream)
{
  (void)in_sizes; (void)n_in; (void)out_size; (void)ws_size;
  const float* dec_in = (const float*)d_in[0];
  const float* prev   = (const float*)d_in[1];
  const float* gk     = (const float*)d_in[6];
  const float* emb_w1 = (const float*)d_in[7];
  const float* emb_b1 = (const float*)d_in[8];
  const float* emb_w2 = (const float*)d_in[9];
  const float* emb_b2 = (const float*)d_in[10];
  const float* emb_w3 = (const float*)d_in[11];
  const float* emb_b3 = (const float*)d_in[12];
  const float* ln0_g  = (const float*)d_in[13];
  const float* ln0_b  = (const float*)d_in[14];
  const float* wq     = (const float*)d_in[15];
  const float* wk     = (const float*)d_in[16];
  const float* wv     = (const float*)d_in[17];
  const float* wo     = (const float*)d_in[18];
  const float* cq     = (const float*)d_in[19];
  const float* ck     = (const float*)d_in[20];
  const float* cv     = (const float*)d_in[21];
  const float* co     = (const float*)d_in[22];
  const float* ffn_w1 = (const float*)d_in[23];
  const float* ffn_w2 = (const float*)d_in[24];
  const float* ffn_b1 = (const float*)d_in[25];
  const float* ffn_b2 = (const float*)d_in[26];
  const float* ln1_g  = (const float*)d_in[27];
  const float* ln1_b  = (const float*)d_in[28];
  const float* ln2_g  = (const float*)d_in[29];
  const float* ln2_b  = (const float*)d_in[30];
  const float* ln3_g  = (const float*)d_in[31];
  const float* ln3_b  = (const float*)d_in[32];
  const float* p_w1   = (const float*)d_in[33];
  const float* p_b1   = (const float*)d_in[34];
  const float* p_w2   = (const float*)d_in[35];
  const float* p_b2   = (const float*)d_in[36];
  const float* p_w3   = (const float*)d_in[37];
  const float* p_b3   = (const float*)d_in[38];

  // ---- workspace carve ----
  char* wsp = (char*)d_ws;
  auto carve = [&](size_t bytes) { char* r = wsp; wsp += (bytes + 255) & ~(size_t)255; return r; };

  unsigned short* decb  = (unsigned short*)carve((size_t)MM * VP * 2);
  unsigned short* prevb = (unsigned short*)carve((size_t)MM * DD * 2);
  float*          hf    = (float*)carve((size_t)MM * DD * 4);
  unsigned short* hb    = (unsigned short*)carve((size_t)MM * DD * 2);
  float*          xf1   = (float*)carve((size_t)MM * DD * 4);
  unsigned short* tb1   = (unsigned short*)carve((size_t)MM * DFFN * 2);   // 8 MB
  unsigned short* Mbb   = tb1;                                   // alias: first 4 MB
  float*          xf2   = (float*)((char*)tb1 + (size_t)MM * SS * 2);      // alias: last 4 MB
  unsigned short* tb2a  = (unsigned short*)carve((size_t)MM * VP * 2);
  unsigned short* tb2b  = (unsigned short*)carve((size_t)MM * VP * 2);
  unsigned short* qb    = (unsigned short*)carve((size_t)MM * DD * 2);
  unsigned short* kb    = (unsigned short*)carve((size_t)MM * DD * 2);
  unsigned short* vbT   = (unsigned short*)carve((size_t)MM * DD * 2);
  float* kvs = (float*)carve((size_t)MM * 4);
  float* kve = (float*)carve((size_t)MM * 4);
  unsigned short* postabt = (unsigned short*)carve((size_t)DD * SS * 2);
  unsigned short* ew1t  = (unsigned short*)carve((size_t)VP * VP * 2);
  unsigned short* ew2t  = (unsigned short*)carve((size_t)VP * VP * 2);
  unsigned short* ew3t  = (unsigned short*)carve((size_t)DD * VP * 2);
  unsigned short* wqt   = (unsigned short*)carve((size_t)LL * DD * DD * 2);
  unsigned short* wkt   = (unsigned short*)carve((size_t)LL * DD * DD * 2);
  unsigned short* wvt   = (unsigned short*)carve((size_t)LL * DD * DD * 2);
  unsigned short* wot   = (unsigned short*)carve((size_t)LL * DD * DD * 2);
  unsigned short* cqt   = (unsigned short*)carve((size_t)LL * DD * DD * 2);
  unsigned short* ckt   = (unsigned short*)carve((size_t)LL * DD * DD * 2);
  unsigned short* cvt   = (unsigned short*)carve((size_t)LL * DD * DD * 2);
  unsigned short* cot   = (unsigned short*)carve((size_t)LL * DD * DD * 2);
  unsigned short* f1t   = (unsigned short*)carve((size_t)LL * DFFN * DD * 2);
  unsigned short* f2t   = (unsigned short*)carve((size_t)LL * DD * DFFN * 2);
  unsigned short* p1t   = (unsigned short*)carve((size_t)VP * DD * 2);
  unsigned short* p2t   = (unsigned short*)carve((size_t)VP * VP * 2);
  unsigned short* p3t   = (unsigned short*)carve((size_t)VP * VP * 2);
  unsigned short* ckall = (unsigned short*)carve((size_t)LL * MM * DD * 2);  // 12 MB
  unsigned short* cvbT  = (unsigned short*)carve((size_t)LL * MM * DD * 2);  // 12 MB
  float*          xk4   = (float*)carve((size_t)4 * MM * DD * 4);            // 16 MB

  const dim3 agrid(SS / 32, HH, BB);

  // ---- mega prologue (1 launch, vectorized stores) ----
  {
    ProP pp{};
    pp.dec_in = dec_in; pp.prev = prev; pp.gk = gk;
    pp.decb = decb; pp.prevb = prevb; pp.tabT = postabt; pp.Mb = Mbb;
    pp.kvs = kvs; pp.kve = kve;
    const float* W8s[8] = {wq, wk, wv, wo, cq, ck, cv, co};
    unsigned short* WT8s[8] = {wqt, wkt, wvt, wot, cqt, ckt, cvt, cot};
    for (int i = 0; i < 8; ++i) { pp.W8[i] = W8s[i]; pp.WT8[i] = WT8s[i]; }
    const float* Ws[8]    = {emb_w1, emb_w2, emb_w3, ffn_w1, ffn_w2, p_w1, p_w2, p_w3};
    unsigned short* Ds[8] = {ew1t, ew2t, ew3t, f1t, f2t, p1t, p2t, p3t};
    const int Ks[8]  = {VV, VV, VV, DD, DFFN, DD, VV, VV};
    const int Ns[8]  = {VV, VV, DD, DFFN, DD, VV, VV, VV};
    const int Kps[8] = {VP, VP, VP, DD, DFFN, DD, VP, VP};
    const int Nps[8] = {VP, VP, DD, DFFN, DD, VP, VP, VP};
    const int nls[8] = {1, 1, 1, LL, LL, 1, 1, 1};
    int off = 0;
    for (int j = 0; j < 8; ++j) {
      pp.W[j] = Ws[j]; pp.WT[j] = Ds[j];
      pp.K[j] = Ks[j]; pp.N[j] = Ns[j]; pp.Kp[j] = Kps[j]; pp.Np[j] = Nps[j];
      pp.nbx[j] = (Nps[j] + 63) / 64; pp.nby[j] = (Kps[j] + 63) / 64;
      pp.off[j] = off;
      off += pp.nbx[j] * pp.nby[j] * nls[j];
    }
    pp.off[8] = off;
    prologue_all<<<5376 + off, 256, 0, stream>>>(pp);
  }

  // ---- cross-KV bat (3072) + emb1 (288) + GPE (256) in ONE launch ----
  {
    GemmMultiP p{};
    p.A = prevb;
    for (int i = 0; i < LL; ++i) {
      p.B[2 * i]     = ckt + (size_t)i * DD * DD;
      p.B[2 * i + 1] = cvt + (size_t)i * DD * DD;
      p.D[2 * i]     = ckall + (size_t)i * MM * DD;
      p.D[2 * i + 1] = cvbT + (size_t)i * MM * DD;
    }
    p.eA = decb; p.eB = ew1t; p.ebias = emb_b1; p.eD = tb2a;
    p.gA = Mbb; p.gB = postabt; p.gC = xf2;
    gemm_multi<<<3616, 256, 0, stream>>>(p);
  }

  // ---- rest of embedding MLP ----
  g1(stream, tb2a, ew2t, emb_b2, nullptr, tb2b, VP, VP, VP, VV, 1);
  g1(stream, tb2b, ew3t, emb_b3, xf1, nullptr, VP, DD, DD, DD, 0);
  addln_kernel<1><<<MM / 4, 256, 0, stream>>>(xf1, xf2, ln0_g, ln0_b, hf, hb);

  for (int i = 0; i < LL; ++i) {
    const size_t od = (size_t)i * DD * DD;
    // self attention (V written transposed by the QKV GEMM)
    g3t(stream, hb, wqt + od, wkt + od, wvt + od, qb, kb, vbT);
    attn_kernel<<<agrid, 128, 0, stream>>>(qb, kb, vbT, qb, kvs);
    g1k<2>(stream, qb, wot + od, nullptr, xk4, DD);
    addln_kernel<2><<<MM / 4, 256, 0, stream>>>(hf, xk4, ln1_g + i * DD, ln1_b + i * DD, hf, hb);
    // cross attention with fused Q-projection (K/V precomputed)
    attnx_kernel<<<agrid, 128, 0, stream>>>(hb, cqt + od, ckall + (size_t)i * MM * DD,
                                            cvbT + (size_t)i * MM * DD, qb, kve);
    g1k<2>(stream, qb, cot + od, nullptr, xk4, DD);
    addln_kernel<2><<<MM / 4, 256, 0, stream>>>(hf, xk4, ln2_g + i * DD, ln2_b + i * DD, hf, hb);
    // FFN (ffn2 split-K x4)
    g1w(stream, hb, f1t + (size_t)i * DFFN * DD, ffn_b1 + i * DFFN, tb1, DD, DFFN, 1);
    g1k<4>(stream, tb1, f2t + (size_t)i * DD * DFFN, ffn_b2 + i * DD, xk4, DFFN);
    addln_kernel<4><<<MM / 4, 256, 0, stream>>>(hf, xk4, ln3_g + i * DD, ln3_b + i * DD, hf, hb);
  }

  // ---- output head ----
  g1(stream, hb, p1t, p_b1, nullptr, tb2a, DD, VP, VP, VV, 1);
  g1(stream, tb2a, p2t, p_b2, nullptr, tb2b, VP, VP, VP, VV, 1);
  g1(stream, tb2b, p3t, p_b3, (float*)d_out, nullptr, VP, VP, VV, VV, 0);
}

// Round 15
// 959.698 us; speedup vs baseline: 2.4421x; 1.0078x over previous
//
#include <hip/hip_runtime.h>
#include <hip/hip_bf16.h>
#include <stdint.h>

#define BB 2
#define SS 1024
#define VV 513
#define VP 576          // 513 padded to 9*64
#define DD 512
#define HH 8
#define DKK 64
#define DFFN 2048
#define LL 6
#define MM (BB * SS)    // 2048

typedef __bf16 bf16x8 __attribute__((ext_vector_type(8)));
typedef float f32x4 __attribute__((ext_vector_type(4)));
typedef unsigned short us8 __attribute__((ext_vector_type(8)));
typedef unsigned short us4 __attribute__((ext_vector_type(4)));

static __device__ inline unsigned short f2bf(float f) {
  union { float f; unsigned u; } v; v.f = f;
  unsigned u = v.u;
  unsigned r = (u + 0x7FFFu + ((u >> 16) & 1u)) >> 16;
  return (unsigned short)r;
}

static __device__ inline bf16x8 ldfrag(const unsigned short* p) {
  us8 r = *(const us8*)p;
  return __builtin_bit_cast(bf16x8, r);
}

typedef __attribute__((address_space(3))) void lds_void;
typedef const __attribute__((address_space(1))) void glb_void;
static __device__ inline void gl_lds16(const void* g, void* l) {
  __builtin_amdgcn_global_load_lds((glb_void*)g, (lds_void*)l, 16, 0, 0);
}

// swizzled LDS fragment read: tile rows are linear 128B, byte ^= (row&7)<<4
static __device__ inline bf16x8 ldfrag_swz(const unsigned short* base, int row, int kloc) {
  const unsigned byte = (unsigned)(row * 128 + kloc * 2) ^ (unsigned)((row & 7) << 4);
  return ldfrag((const unsigned short*)((const char*)base + byte));
}

static __device__ inline int rot3(int x) { return (x == 2) ? 0 : x + 1; }

// ---------------------------------------------------------------------------
// core 64x64xK pipelined MFMA accumulate (3-deep counted-vmcnt staging)
// ---------------------------------------------------------------------------
__device__ __forceinline__ void gemm_core64(
    unsigned short* Al, unsigned short* Bl,
    const unsigned short* Abase, const unsigned short* Bbase, int Kp, int nt,
    f32x4 (&acc)[2][2])
{
  const int tid = threadIdx.x;
  const int l = tid & 63, w = tid >> 6;
  const int wm = w >> 1, wn = w & 1;
  const int lr = l & 15, lg = l >> 4;

  auto stage = [&](int buf, int kt) {
    const int k0 = kt << 6;
#pragma unroll
    for (int j = 0; j < 2; ++j) {
      const int ti = j * 256 + tid;
      const int row = ti >> 3;
      const int ch = (ti & 7) ^ (row & 7);
      gl_lds16(Abase + (size_t)row * Kp + k0 + ch * 8, &Al[buf * 4096 + ti * 8]);
    }
#pragma unroll
    for (int j = 0; j < 2; ++j) {
      const int ti = j * 256 + tid;
      const int row = ti >> 3;
      const int ch = (ti & 7) ^ (row & 7);
      gl_lds16(Bbase + (size_t)row * Kp + k0 + ch * 8, &Bl[buf * 4096 + ti * 8]);
    }
  };

  stage(0, 0);
  if (nt > 1) stage(1, 1);
  int cb = 0, sb = 2;
  for (int kt = 0; kt < nt; ++kt) {
    if (kt + 1 < nt) asm volatile("s_waitcnt vmcnt(4)" ::: "memory");
    else             asm volatile("s_waitcnt vmcnt(0)" ::: "memory");
    __builtin_amdgcn_s_barrier();
    if (kt + 2 < nt) { stage(sb, kt + 2); sb = rot3(sb); }
#pragma unroll
    for (int ks = 0; ks < 2; ++ks) {
      bf16x8 af[2], bfv[2];
#pragma unroll
      for (int mf = 0; mf < 2; ++mf)
        af[mf] = ldfrag_swz(Al + cb * 4096, wm * 32 + mf * 16 + lr, ks * 32 + lg * 8);
#pragma unroll
      for (int nf = 0; nf < 2; ++nf)
        bfv[nf] = ldfrag_swz(Bl + cb * 4096, wn * 32 + nf * 16 + lr, ks * 32 + lg * 8);
#pragma unroll
      for (int mf = 0; mf < 2; ++mf)
#pragma unroll
        for (int nf = 0; nf < 2; ++nf)
          acc[mf][nf] = __builtin_amdgcn_mfma_f32_16x16x32_bf16(af[mf], bfv[nf], acc[mf][nf], 0, 0, 0);
    }
    cb = rot3(cb);
  }
}

// ---------------------------------------------------------------------------
// GEMM: C = A[M][Kp](bf16) * B^T, B stored [N][Kp] bf16 (padded).
// TRV: sel==2 output stored transposed into [b][h][dk][s].
// KS: split-K factor (grid.z); partials go to p.C + z*MM*ldc (f32).
// ---------------------------------------------------------------------------
struct GemmP {
  const unsigned short* A;
  const unsigned short* B0; const unsigned short* B1; const unsigned short* B2;
  const float* bias;
  float* C;
  unsigned short* D0; unsigned short* D1; unsigned short* D2;
  int Kp, Np, ldc, Nreal, relu;
};

template<int NB, int NT, int TRV, int KS>
__global__ __launch_bounds__(256)
void gemm_tpl(GemmP p)
{
  constexpr int FN = NT / 32;
  __shared__ unsigned short Al[3][64 * 64];
  __shared__ unsigned short Bl[3][NT * 64];
  const int tid = threadIdx.x;
  const int l = tid & 63, w = tid >> 6;
  const int wm = w >> 1, wn = w & 1;
  const int lr = l & 15, lg = l >> 4;

  const int nbn = p.Np / NT;
  int sel = 0, bx = blockIdx.x;
  if (NB > 1) { sel = bx / nbn; bx -= sel * nbn; }
  const unsigned short* Bmat = p.B0;
  if (NB > 1 && sel == 1) Bmat = p.B1;
  if (NB > 2 && sel == 2) Bmat = p.B2;
  const int m0 = blockIdx.y << 6, n0 = bx * NT;
  const int kz = (KS > 1) ? blockIdx.z : 0;

  f32x4 acc[2][FN];
  const f32x4 zf = {0.f, 0.f, 0.f, 0.f};
#pragma unroll
  for (int i = 0; i < 2; ++i)
#pragma unroll
    for (int j = 0; j < FN; ++j) acc[i][j] = zf;

  const size_t Kp = (size_t)p.Kp;
  const unsigned short* Abase = p.A + (size_t)m0 * Kp;
  const unsigned short* Bbase = Bmat + (size_t)n0 * Kp;
  const int nt = (p.Kp >> 6) / KS;
  const int kb0 = kz * nt;

  auto stage = [&](int buf, int kt) {
    const int k0 = (kb0 + kt) << 6;
#pragma unroll
    for (int j = 0; j < 2; ++j) {
      const int ti = j * 256 + tid;
      const int row = ti >> 3;
      const int ch = (ti & 7) ^ (row & 7);
      gl_lds16(Abase + (size_t)row * Kp + k0 + ch * 8, &Al[buf][ti * 8]);
    }
#pragma unroll
    for (int j = 0; j < FN; ++j) {
      const int ti = j * 256 + tid;
      const int row = ti >> 3;
      const int ch = (ti & 7) ^ (row & 7);
      gl_lds16(Bbase + (size_t)row * Kp + k0 + ch * 8, &Bl[buf][ti * 8]);
    }
  };

  stage(0, 0);
  if (nt > 1) stage(1, 1);
  int cb = 0, sb = 2;

  for (int kt = 0; kt < nt; ++kt) {
    if (kt + 1 < nt) {
      if constexpr (FN == 2) asm volatile("s_waitcnt vmcnt(4)" ::: "memory");
      else                   asm volatile("s_waitcnt vmcnt(6)" ::: "memory");
    } else {
      asm volatile("s_waitcnt vmcnt(0)" ::: "memory");
    }
    __builtin_amdgcn_s_barrier();
    if (kt + 2 < nt) { stage(sb, kt + 2); sb = rot3(sb); }
#pragma unroll
    for (int ks = 0; ks < 2; ++ks) {
      bf16x8 af[2], bfv[FN];
#pragma unroll
      for (int mf = 0; mf < 2; ++mf)
        af[mf] = ldfrag_swz(Al[cb], wm * 32 + mf * 16 + lr, ks * 32 + lg * 8);
#pragma unroll
      for (int nf = 0; nf < FN; ++nf)
        bfv[nf] = ldfrag_swz(Bl[cb], wn * (NT / 2) + nf * 16 + lr, ks * 32 + lg * 8);
#pragma unroll
      for (int mf = 0; mf < 2; ++mf)
#pragma unroll
        for (int nf = 0; nf < FN; ++nf)
          acc[mf][nf] = __builtin_amdgcn_mfma_f32_16x16x32_bf16(af[mf], bfv[nf], acc[mf][nf], 0, 0, 0);
    }
    cb = rot3(cb);
  }

  unsigned short* Dsel = p.D0;
  if (NB > 1 && sel == 1) Dsel = p.D1;
  if (NB > 2 && sel == 2) Dsel = p.D2;

  if (TRV && sel == 2) {
#pragma unroll
    for (int mf = 0; mf < 2; ++mf) {
      const int growb = m0 + wm * 32 + mf * 16 + (lg << 2);
      const int b = growb >> 10, s = growb & 1023;
#pragma unroll
      for (int nf = 0; nf < FN; ++nf) {
        const int gcol = n0 + wn * (NT / 2) + nf * 16 + lr;
        const int h = gcol >> 6, d = gcol & 63;
        us4 t;
#pragma unroll
        for (int r = 0; r < 4; ++r) t[r] = f2bf(acc[mf][nf][r]);
        *(us4*)(Dsel + (((size_t)(b * HH) + h) * DKK + d) * SS + s) = t;
      }
    }
    return;
  }

  float* Cz = p.C ? (p.C + (size_t)kz * MM * p.ldc) : nullptr;
#pragma unroll
  for (int mf = 0; mf < 2; ++mf) {
#pragma unroll
    for (int r = 0; r < 4; ++r) {
      const int grow = m0 + wm * 32 + mf * 16 + (lg << 2) + r;
#pragma unroll
      for (int nf = 0; nf < FN; ++nf) {
        const int gcol = n0 + wn * (NT / 2) + nf * 16 + lr;
        float v = acc[mf][nf][r];
        if (p.bias && kz == 0 && gcol < p.Nreal) v += p.bias[gcol];
        if (p.relu) v = fmaxf(v, 0.f);
        if (Dsel) Dsel[(size_t)grow * p.Np + gcol] = f2bf(v);
        if (Cz && gcol < p.Nreal) Cz[(size_t)grow * p.ldc + gcol] = v;
      }
    }
  }
}

// ---------------------------------------------------------------------------
// Mega GEMM launch: flat job decode.
//   bid <  3072 : cross-KV batched GEMM (12 sel, odd sel -> transposed V)
//   bid <  3360 : emb1  (decb @ ew1t^T, relu+bias, bf16 out, Kp=Np=576)
//   bid <  3616 : GPE   (Mbb @ postabt^T, f32 out, Kp=1024, Np=512)
// ---------------------------------------------------------------------------
struct GemmMultiP {
  const unsigned short* A;            // prevb
  const unsigned short* B[12];
  unsigned short* D[12];
  const unsigned short* eA; const unsigned short* eB; const float* ebias;
  unsigned short* eD;
  const unsigned short* gA; const unsigned short* gB; float* gC;
};

__global__ __launch_bounds__(256)
void gemm_multi(GemmMultiP p)
{
  __shared__ unsigned short Al[3 * 4096];
  __shared__ unsigned short Bl[3 * 4096];
  const int bid = blockIdx.x;
  const int tid = threadIdx.x;
  const int l = tid & 63, w = tid >> 6;
  const int wm = w >> 1, wn = w & 1;
  const int lr = l & 15, lg = l >> 4;
  const f32x4 zf = {0.f, 0.f, 0.f, 0.f};
  f32x4 acc[2][2];
#pragma unroll
  for (int i = 0; i < 2; ++i)
#pragma unroll
    for (int j = 0; j < 2; ++j) acc[i][j] = zf;

  if (bid < 3072) {
    const int sel = bid >> 8;
    const int rem = bid & 255;
    const int by = rem >> 3, bx = rem & 7;
    const int m0 = by << 6, n0 = bx << 6;
    gemm_core64(Al, Bl, p.A + (size_t)m0 * DD, p.B[sel] + (size_t)n0 * DD, DD, 8, acc);
    unsigned short* Dmat = p.D[sel];
    if (sel & 1) {
#pragma unroll
      for (int mf = 0; mf < 2; ++mf) {
        const int growb = m0 + wm * 32 + mf * 16 + (lg << 2);
        const int b = growb >> 10, s = growb & 1023;
#pragma unroll
        for (int nf = 0; nf < 2; ++nf) {
          const int gcol = n0 + wn * 32 + nf * 16 + lr;
          const int h = gcol >> 6, d = gcol & 63;
          us4 t;
#pragma unroll
          for (int r = 0; r < 4; ++r) t[r] = f2bf(acc[mf][nf][r]);
          *(us4*)(Dmat + (((size_t)(b * HH) + h) * DKK + d) * SS + s) = t;
        }
      }
    } else {
#pragma unroll
      for (int mf = 0; mf < 2; ++mf)
#pragma unroll
        for (int r = 0; r < 4; ++r) {
          const int grow = m0 + wm * 32 + mf * 16 + (lg << 2) + r;
#pragma unroll
          for (int nf = 0; nf < 2; ++nf) {
            const int gcol = n0 + wn * 32 + nf * 16 + lr;
            Dmat[(size_t)grow * DD + gcol] = f2bf(acc[mf][nf][r]);
          }
        }
    }
  } else if (bid < 3360) {
    const int local = bid - 3072;
    const int by = local / 9, bx = local - by * 9;
    const int m0 = by << 6, n0 = bx << 6;
    gemm_core64(Al, Bl, p.eA + (size_t)m0 * VP, p.eB + (size_t)n0 * VP, VP, 9, acc);
#pragma unroll
    for (int mf = 0; mf < 2; ++mf)
#pragma unroll
      for (int r = 0; r < 4; ++r) {
        const int grow = m0 + wm * 32 + mf * 16 + (lg << 2) + r;
#pragma unroll
        for (int nf = 0; nf < 2; ++nf) {
          const int gcol = n0 + wn * 32 + nf * 16 + lr;
          float v = acc[mf][nf][r];
          if (gcol < VV) v += p.ebias[gcol];
          v = fmaxf(v, 0.f);
          p.eD[(size_t)grow * VP + gcol] = f2bf(v);
        }
      }
  } else {
    const int local = bid - 3360;
    const int by = local >> 3, bx = local & 7;
    const int m0 = by << 6, n0 = bx << 6;
    gemm_core64(Al, Bl, p.gA + (size_t)m0 * SS, p.gB + (size_t)n0 * SS, SS, 16, acc);
#pragma unroll
    for (int mf = 0; mf < 2; ++mf)
#pragma unroll
      for (int r = 0; r < 4; ++r) {
        const int grow = m0 + wm * 32 + mf * 16 + (lg << 2) + r;
#pragma unroll
        for (int nf = 0; nf < 2; ++nf) {
          const int gcol = n0 + wn * 32 + nf * 16 + lr;
          p.gC[(size_t)grow * DD + gcol] = acc[mf][nf][r];
        }
      }
  }
}

// ---------------------------------------------------------------------------
// Self-attention (causal): QBLK=32, 2 waves split KV (wave w: tiles ≡w mod 2).
// ---------------------------------------------------------------------------
__global__ __launch_bounds__(128)
void attn_kernel(const unsigned short* __restrict__ Qb,
                 const unsigned short* __restrict__ Kb,
                 const unsigned short* __restrict__ VbT,
                 unsigned short* __restrict__ Ob,
                 const float* __restrict__ maskadd)
{
  __shared__ unsigned short Kl[2][2][64 * 64];
  __shared__ unsigned short Vl[2][2][64 * 64];
  __shared__ char PC[9216];
  unsigned short* Pl = (unsigned short*)PC;
  float (*comb)[66] = (float(*)[66])PC;

  const int tid = threadIdx.x;
  const int l = tid & 63, w = tid >> 6;
  const int qt = blockIdx.x, h = blockIdx.y, b = blockIdx.z;
  const int lr = l & 15, lg = l >> 4;

  bf16x8 qf[2][2];
#pragma unroll
  for (int mf = 0; mf < 2; ++mf) {
    const unsigned short* qrow = Qb + ((size_t)(b * SS) + qt * 32 + mf * 16 + lr) * DD + h * DKK;
    qf[mf][0] = ldfrag(qrow + (lg << 3));
    qf[mf][1] = ldfrag(qrow + 32 + (lg << 3));
  }

  const unsigned short* Kbase = Kb + (size_t)(b * SS) * DD + h * DKK;
  const unsigned short* Vbase = VbT + ((size_t)(b * HH) + h) * DKK * SS;

  auto stage = [&](int buf, int kt) {
#pragma unroll
    for (int j = 0; j < 8; ++j) {
      const int ti = j * 64 + l;
      const int row = ti >> 3;
      const int ch = (ti & 7) ^ (row & 7);
      gl_lds16(Kbase + (size_t)(kt * 64 + row) * DD + ch * 8, &Kl[w][buf][ti * 8]);
    }
#pragma unroll
    for (int j = 0; j < 8; ++j) {
      const int ti = j * 64 + l;
      const int row = ti >> 3;
      const int ch = (ti & 7) ^ (row & 7);
      gl_lds16(Vbase + (size_t)row * SS + kt * 64 + ch * 8, &Vl[w][buf][ti * 8]);
    }
  };

  f32x4 accO[2][4];
  const f32x4 zf = {0.f, 0.f, 0.f, 0.f};
#pragma unroll
  for (int mf = 0; mf < 2; ++mf)
#pragma unroll
    for (int nf = 0; nf < 4; ++nf) accO[mf][nf] = zf;
  float mold[2][4], lsum[2][4];
#pragma unroll
  for (int mf = 0; mf < 2; ++mf)
#pragma unroll
    for (int r = 0; r < 4; ++r) { mold[mf][r] = -1e30f; lsum[mf][r] = 0.f; }

  const int ktmax = (qt >> 1) + 1;
  const int myn = (ktmax - w + 1) >> 1;

  if (myn > 0) stage(0, w);
  int buf = 0;

  for (int i = 0; i < myn; ++i) {
    const int kt = w + 2 * i;
    if (i + 1 < myn) {
      stage(buf ^ 1, kt + 2);
      asm volatile("s_waitcnt vmcnt(16)" ::: "memory");
    } else {
      asm volatile("s_waitcnt vmcnt(0)" ::: "memory");
    }
    const unsigned short* KB = &Kl[w][buf][0];
    const unsigned short* VB = &Vl[w][buf][0];
    float sc[2][4][4];
    __builtin_amdgcn_s_setprio(1);
#pragma unroll
    for (int nf = 0; nf < 4; ++nf) {
      bf16x8 k0 = ldfrag_swz(KB, nf * 16 + lr, lg * 8);
      bf16x8 k1 = ldfrag_swz(KB, nf * 16 + lr, 32 + lg * 8);
      const int kglob = kt * 64 + nf * 16 + lr;
      const float madd = maskadd[b * SS + kglob];
#pragma unroll
      for (int mf = 0; mf < 2; ++mf) {
        f32x4 s = zf;
        s = __builtin_amdgcn_mfma_f32_16x16x32_bf16(qf[mf][0], k0, s, 0, 0, 0);
        s = __builtin_amdgcn_mfma_f32_16x16x32_bf16(qf[mf][1], k1, s, 0, 0, 0);
#pragma unroll
        for (int r = 0; r < 4; ++r) {
          const int qglob = qt * 32 + mf * 16 + (lg << 2) + r;
          sc[mf][nf][r] = (kglob > qglob) ? -1e9f : s[r] * 0.125f + madd;
        }
      }
    }
    __builtin_amdgcn_s_setprio(0);
#pragma unroll
    for (int mf = 0; mf < 2; ++mf)
#pragma unroll
      for (int r = 0; r < 4; ++r) {
        float mloc = fmaxf(fmaxf(sc[mf][0][r], sc[mf][1][r]), fmaxf(sc[mf][2][r], sc[mf][3][r]));
#pragma unroll
        for (int off = 1; off < 16; off <<= 1)
          mloc = fmaxf(mloc, __shfl_xor(mloc, off, 64));
        const float mnew = fmaxf(mold[mf][r], mloc);
        const float corr = __expf(mold[mf][r] - mnew);
        float ps = 0.f;
#pragma unroll
        for (int nf = 0; nf < 4; ++nf) {
          const float pv = __expf(sc[mf][nf][r] - mnew);
          sc[mf][nf][r] = pv;
          ps += pv;
        }
#pragma unroll
        for (int off = 1; off < 16; off <<= 1)
          ps += __shfl_xor(ps, off, 64);
        lsum[mf][r] = lsum[mf][r] * corr + ps;
#pragma unroll
        for (int nf = 0; nf < 4; ++nf) accO[mf][nf][r] *= corr;
        mold[mf][r] = mnew;
      }
    unsigned short* pw = Pl + w * 32 * 72;
#pragma unroll
    for (int mf = 0; mf < 2; ++mf)
#pragma unroll
      for (int nf = 0; nf < 4; ++nf)
#pragma unroll
        for (int r = 0; r < 4; ++r)
          pw[(mf * 16 + (lg << 2) + r) * 72 + nf * 16 + lr] = f2bf(sc[mf][nf][r]);
    bf16x8 pa[2][2];
#pragma unroll
    for (int mf = 0; mf < 2; ++mf) {
      pa[mf][0] = ldfrag(&pw[(mf * 16 + lr) * 72 + (lg << 3)]);
      pa[mf][1] = ldfrag(&pw[(mf * 16 + lr) * 72 + 32 + (lg << 3)]);
    }
    __builtin_amdgcn_s_setprio(1);
#pragma unroll
    for (int nf = 0; nf < 4; ++nf) {
      bf16x8 v0 = ldfrag_swz(VB, nf * 16 + lr, lg * 8);
      bf16x8 v1 = ldfrag_swz(VB, nf * 16 + lr, 32 + lg * 8);
#pragma unroll
      for (int mf = 0; mf < 2; ++mf) {
        accO[mf][nf] = __builtin_amdgcn_mfma_f32_16x16x32_bf16(pa[mf][0], v0, accO[mf][nf], 0, 0, 0);
        accO[mf][nf] = __builtin_amdgcn_mfma_f32_16x16x32_bf16(pa[mf][1], v1, accO[mf][nf], 0, 0, 0);
      }
    }
    __builtin_amdgcn_s_setprio(0);
    buf ^= 1;
  }

  __syncthreads();
  if (w == 1) {
#pragma unroll
    for (int mf = 0; mf < 2; ++mf)
#pragma unroll
      for (int r = 0; r < 4; ++r) {
        const int qrow = mf * 16 + (lg << 2) + r;
#pragma unroll
        for (int nf = 0; nf < 4; ++nf)
          comb[qrow][nf * 16 + lr] = accO[mf][nf][r];
        if (lr == 0) { comb[qrow][64] = mold[mf][r]; comb[qrow][65] = lsum[mf][r]; }
      }
  }
  __syncthreads();
  if (w == 0) {
#pragma unroll
    for (int mf = 0; mf < 2; ++mf)
#pragma unroll
      for (int r = 0; r < 4; ++r) {
        const int qrow = mf * 16 + (lg << 2) + r;
        const float m1 = comb[qrow][64], l1 = comb[qrow][65];
        const float m0v = mold[mf][r], l0 = lsum[mf][r];
        const float ms = fmaxf(m0v, m1);
        const float f0 = __expf(m0v - ms), f1 = __expf(m1 - ms);
        const float inv = 1.f / (l0 * f0 + l1 * f1);
        const size_t orow = ((size_t)(b * SS) + qt * 32 + mf * 16 + (lg << 2) + r) * DD + h * DKK;
#pragma unroll
        for (int nf = 0; nf < 4; ++nf)
          Ob[orow + nf * 16 + lr] =
              f2bf((accO[mf][nf][r] * f0 + comb[qrow][nf * 16 + lr] * f1) * inv);
      }
  }
}

// ---------------------------------------------------------------------------
// Cross-attention with FUSED Q-projection (scale folded into Q).
// ---------------------------------------------------------------------------
__global__ __launch_bounds__(128)
void attnx_kernel(const unsigned short* __restrict__ Hb,
                  const unsigned short* __restrict__ Wq,
                  const unsigned short* __restrict__ Kb,
                  const unsigned short* __restrict__ VbT,
                  unsigned short* __restrict__ Ob,
                  const float* __restrict__ maskadd)
{
  __shared__ unsigned short Kl[2][2][64 * 64];
  __shared__ unsigned short Vl[2][2][64 * 64];
  __shared__ char PC[9216];
  unsigned short* Pl = (unsigned short*)PC;
  float (*comb)[66] = (float(*)[66])PC;
  unsigned short* QA = &Kl[0][0][0];
  unsigned short* QB = &Vl[0][0][0];
  unsigned short* Ql = (unsigned short*)PC;

  const int tid = threadIdx.x;
  const int l = tid & 63, w = tid >> 6;
  const int qt = blockIdx.x, h = blockIdx.y, b = blockIdx.z;
  const int lr = l & 15, lg = l >> 4;

  {
    const unsigned short* Abase = Hb + ((size_t)(b * SS) + qt * 32) * DD;
    const unsigned short* Bbase = Wq + (size_t)(h * DKK) * DD;
    auto stage_q = [&](int buf, int kt) {
      const int k0 = kt << 6;
#pragma unroll
      for (int j = 0; j < 2; ++j) {
        const int ti = j * 128 + tid;
        const int row = ti >> 3;
        const int ch = (ti & 7) ^ (row & 7);
        gl_lds16(Abase + (size_t)row * DD + k0 + ch * 8, &QA[buf * 2048 + ti * 8]);
      }
#pragma unroll
      for (int j = 0; j < 4; ++j) {
        const int ti = j * 128 + tid;
        const int row = ti >> 3;
        const int ch = (ti & 7) ^ (row & 7);
        gl_lds16(Bbase + (size_t)row * DD + k0 + ch * 8, &QB[buf * 4096 + ti * 8]);
      }
    };
    f32x4 qacc[2][2];
    const f32x4 zf = {0.f, 0.f, 0.f, 0.f};
#pragma unroll
    for (int i = 0; i < 2; ++i)
#pragma unroll
      for (int j = 0; j < 2; ++j) qacc[i][j] = zf;

    stage_q(0, 0);
    for (int kt = 0; kt < 8; ++kt) {
      if (kt + 1 < 8) {
        stage_q((kt + 1) & 1, kt + 1);
        asm volatile("s_waitcnt vmcnt(6)" ::: "memory");
      } else {
        asm volatile("s_waitcnt vmcnt(0)" ::: "memory");
      }
      __builtin_amdgcn_s_barrier();
      const unsigned short* qa = &QA[(kt & 1) * 2048];
      const unsigned short* qbuf = &QB[(kt & 1) * 4096];
#pragma unroll
      for (int ks = 0; ks < 2; ++ks) {
        bf16x8 af[2], bfv[2];
#pragma unroll
        for (int mf = 0; mf < 2; ++mf)
          af[mf] = ldfrag_swz(qa, mf * 16 + lr, ks * 32 + lg * 8);
#pragma unroll
        for (int nf = 0; nf < 2; ++nf)
          bfv[nf] = ldfrag_swz(qbuf, w * 32 + nf * 16 + lr, ks * 32 + lg * 8);
#pragma unroll
        for (int mf = 0; mf < 2; ++mf)
#pragma unroll
          for (int nf = 0; nf < 2; ++nf)
            qacc[mf][nf] = __builtin_amdgcn_mfma_f32_16x16x32_bf16(af[mf], bfv[nf], qacc[mf][nf], 0, 0, 0);
      }
      __builtin_amdgcn_s_barrier();
    }
#pragma unroll
    for (int mf = 0; mf < 2; ++mf)
#pragma unroll
      for (int nf = 0; nf < 2; ++nf)
#pragma unroll
        for (int r = 0; r < 4; ++r)
          Ql[(mf * 16 + (lg << 2) + r) * 72 + w * 32 + nf * 16 + lr] = f2bf(qacc[mf][nf][r] * 0.125f);
    __syncthreads();
  }
  bf16x8 qf[2][2];
#pragma unroll
  for (int mf = 0; mf < 2; ++mf) {
    qf[mf][0] = ldfrag(&Ql[(mf * 16 + lr) * 72 + (lg << 3)]);
    qf[mf][1] = ldfrag(&Ql[(mf * 16 + lr) * 72 + 32 + (lg << 3)]);
  }
  __syncthreads();

  const unsigned short* Kbase = Kb + (size_t)(b * SS) * DD + h * DKK;
  const unsigned short* Vbase = VbT + ((size_t)(b * HH) + h) * DKK * SS;

  auto stage = [&](int buf, int kt) {
#pragma unroll
    for (int j = 0; j < 8; ++j) {
      const int ti = j * 64 + l;
      const int row = ti >> 3;
      const int ch = (ti & 7) ^ (row & 7);
      gl_lds16(Kbase + (size_t)(kt * 64 + row) * DD + ch * 8, &Kl[w][buf][ti * 8]);
    }
#pragma unroll
    for (int j = 0; j < 8; ++j) {
      const int ti = j * 64 + l;
      const int row = ti >> 3;
      const int ch = (ti & 7) ^ (row & 7);
      gl_lds16(Vbase + (size_t)row * SS + kt * 64 + ch * 8, &Vl[w][buf][ti * 8]);
    }
  };

  f32x4 accO[2][4];
  const f32x4 zf = {0.f, 0.f, 0.f, 0.f};
#pragma unroll
  for (int mf = 0; mf < 2; ++mf)
#pragma unroll
    for (int nf = 0; nf < 4; ++nf) accO[mf][nf] = zf;
  float mold[2][4], lsum[2][4];
#pragma unroll
  for (int mf = 0; mf < 2; ++mf)
#pragma unroll
    for (int r = 0; r < 4; ++r) { mold[mf][r] = -1e30f; lsum[mf][r] = 0.f; }

  const int myn = (SS / 64 - w + 1) >> 1;
  stage(0, w);
  int buf = 0;

  for (int i = 0; i < myn; ++i) {
    const int kt = w + 2 * i;
    if (i + 1 < myn) {
      stage(buf ^ 1, kt + 2);
      asm volatile("s_waitcnt vmcnt(16)" ::: "memory");
    } else {
      asm volatile("s_waitcnt vmcnt(0)" ::: "memory");
    }
    const unsigned short* KB = &Kl[w][buf][0];
    const unsigned short* VB = &Vl[w][buf][0];
    float sc[2][4][4];
    __builtin_amdgcn_s_setprio(1);
#pragma unroll
    for (int nf = 0; nf < 4; ++nf) {
      bf16x8 k0 = ldfrag_swz(KB, nf * 16 + lr, lg * 8);
      bf16x8 k1 = ldfrag_swz(KB, nf * 16 + lr, 32 + lg * 8);
      const int kglob = kt * 64 + nf * 16 + lr;
      const float madd = maskadd[b * SS + kglob];
#pragma unroll
      for (int mf = 0; mf < 2; ++mf) {
        f32x4 s = zf;
        s = __builtin_amdgcn_mfma_f32_16x16x32_bf16(qf[mf][0], k0, s, 0, 0, 0);
        s = __builtin_amdgcn_mfma_f32_16x16x32_bf16(qf[mf][1], k1, s, 0, 0, 0);
#pragma unroll
        for (int r = 0; r < 4; ++r)
          sc[mf][nf][r] = s[r] + madd;
      }
    }
    __builtin_amdgcn_s_setprio(0);
#pragma unroll
    for (int mf = 0; mf < 2; ++mf)
#pragma unroll
      for (int r = 0; r < 4; ++r) {
        float mloc = fmaxf(fmaxf(sc[mf][0][r], sc[mf][1][r]), fmaxf(sc[mf][2][r], sc[mf][3][r]));
#pragma unroll
        for (int off = 1; off < 16; off <<= 1)
          mloc = fmaxf(mloc, __shfl_xor(mloc, off, 64));
        const float mnew = fmaxf(mold[mf][r], mloc);
        const float corr = __expf(mold[mf][r] - mnew);
        float ps = 0.f;
#pragma unroll
        for (int nf = 0; nf < 4; ++nf) {
          const float pv = __expf(sc[mf][nf][r] - mnew);
          sc[mf][nf][r] = pv;
          ps += pv;
        }
#pragma unroll
        for (int off = 1; off < 16; off <<= 1)
          ps += __shfl_xor(ps, off, 64);
        lsum[mf][r] = lsum[mf][r] * corr + ps;
#pragma unroll
        for (int nf = 0; nf < 4; ++nf) accO[mf][nf][r] *= corr;
        mold[mf][r] = mnew;
      }
    unsigned short* pw = Pl + w * 32 * 72;
#pragma unroll
    for (int mf = 0; mf < 2; ++mf)
#pragma unroll
      for (int nf = 0; nf < 4; ++nf)
#pragma unroll
        for (int r = 0; r < 4; ++r)
          pw[(mf * 16 + (lg << 2) + r) * 72 + nf * 16 + lr] = f2bf(sc[mf][nf][r]);
    bf16x8 pa[2][2];
#pragma unroll
    for (int mf = 0; mf < 2; ++mf) {
      pa[mf][0] = ldfrag(&pw[(mf * 16 + lr) * 72 + (lg << 3)]);
      pa[mf][1] = ldfrag(&pw[(mf * 16 + lr) * 72 + 32 + (lg << 3)]);
    }
    __builtin_amdgcn_s_setprio(1);
#pragma unroll
    for (int nf = 0; nf < 4; ++nf) {
      bf16x8 v0 = ldfrag_swz(VB, nf * 16 + lr, lg * 8);
      bf16x8 v1 = ldfrag_swz(VB, nf * 16 + lr, 32 + lg * 8);
#pragma unroll
      for (int mf = 0; mf < 2; ++mf) {
        accO[mf][nf] = __builtin_amdgcn_mfma_f32_16x16x32_bf16(pa[mf][0], v0, accO[mf][nf], 0, 0, 0);
        accO[mf][nf] = __builtin_amdgcn_mfma_f32_16x16x32_bf16(pa[mf][1], v1, accO[mf][nf], 0, 0, 0);
      }
    }
    __builtin_amdgcn_s_setprio(0);
    buf ^= 1;
  }

  __syncthreads();
  if (w == 1) {
#pragma unroll
    for (int mf = 0; mf < 2; ++mf)
#pragma unroll
      for (int r = 0; r < 4; ++r) {
        const int qrow = mf * 16 + (lg << 2) + r;
#pragma unroll
        for (int nf = 0; nf < 4; ++nf)
          comb[qrow][nf * 16 + lr] = accO[mf][nf][r];
        if (lr == 0) { comb[qrow][64] = mold[mf][r]; comb[qrow][65] = lsum[mf][r]; }
      }
  }
  __syncthreads();
  if (w == 0) {
#pragma unroll
    for (int mf = 0; mf < 2; ++mf)
#pragma unroll
      for (int r = 0; r < 4; ++r) {
        const int qrow = mf * 16 + (lg << 2) + r;
        const float m1 = comb[qrow][64], l1 = comb[qrow][65];
        const float m0v = mold[mf][r], l0 = lsum[mf][r];
        const float ms = fmaxf(m0v, m1);
        const float f0 = __expf(m0v - ms), f1 = __expf(m1 - ms);
        const float inv = 1.f / (l0 * f0 + l1 * f1);
        const size_t orow = ((size_t)(b * SS) + qt * 32 + mf * 16 + (lg << 2) + r) * DD + h * DKK;
#pragma unroll
        for (int nf = 0; nf < 4; ++nf)
          Ob[orow + nf * 16 + lr] =
              f2bf((accO[mf][nf][r] * f0 + comb[qrow][nf * 16 + lr] * f1) * inv);
      }
  }
}

// ---------------------------------------------------------------------------
// out = LN(a + sum_p c_p); 4 rows per block, vectorized. P = #partials.
// ---------------------------------------------------------------------------
template<int P>
__global__ __launch_bounds__(256)
void addln_kernel(const float* __restrict__ a, const float* __restrict__ c,
                  const float* __restrict__ g, const float* __restrict__ bb,
                  float* __restrict__ hf, unsigned short* __restrict__ hb)
{
  const int row = blockIdx.x * 4 + (threadIdx.x >> 6);
  const int l = threadIdx.x & 63;
  const float* ar = a + (size_t)row * DD + l * 8;
  f32x4 x0 = *(const f32x4*)ar;
  f32x4 x1 = *(const f32x4*)(ar + 4);
#pragma unroll
  for (int pp = 0; pp < P; ++pp) {
    const float* cr = c + (size_t)pp * MM * DD + (size_t)row * DD + l * 8;
    x0 += *(const f32x4*)cr;
    x1 += *(const f32x4*)(cr + 4);
  }
  float sum = x0[0] + x0[1] + x0[2] + x0[3] + x1[0] + x1[1] + x1[2] + x1[3];
#pragma unroll
  for (int off = 1; off < 64; off <<= 1) sum += __shfl_xor(sum, off, 64);
  const float mean = sum * (1.f / 512.f);
  float vs = 0.f;
#pragma unroll
  for (int j = 0; j < 4; ++j) { float d0 = x0[j] - mean; float d1 = x1[j] - mean; vs += d0 * d0 + d1 * d1; }
#pragma unroll
  for (int off = 1; off < 64; off <<= 1) vs += __shfl_xor(vs, off, 64);
  const float rs = rsqrtf(vs * (1.f / 512.f) + 1e-6f);
  const f32x4 g0 = *(const f32x4*)(g + l * 8), g1 = *(const f32x4*)(g + l * 8 + 4);
  const f32x4 b0 = *(const f32x4*)(bb + l * 8), b1 = *(const f32x4*)(bb + l * 8 + 4);
  f32x4 o0, o1;
  us8 ob;
#pragma unroll
  for (int j = 0; j < 4; ++j) {
    o0[j] = (x0[j] - mean) * rs * g0[j] + b0[j];
    o1[j] = (x1[j] - mean) * rs * g1[j] + b1[j];
    ob[j] = f2bf(o0[j]); ob[j + 4] = f2bf(o1[j]);
  }
  float* of = hf + (size_t)row * DD + l * 8;
  *(f32x4*)of = o0; *(f32x4*)(of + 4) = o1;
  *(us8*)(hb + (size_t)row * DD + l * 8) = ob;
}

// ---------------------------------------------------------------------------
// Mega prologue (vectorized loads AND stores):
//   [0,1024)        prep rows (dec/prev -> bf16 + mask)
//   [1024,1280)     postable: 8 elems/thread, us8 store
//   [1280,2304)     gpec: 8 elems/thread, f32x4 loads, us8 store
//   [2304,5376)     wconv8: 64x64 transpose, f32x4 loads, us8 store
//   [5376,...)      wconv jobs: guarded transpose, f32x4 fast path, us8 store
// ---------------------------------------------------------------------------
struct ProP {
  const float *dec_in, *prev, *gk;
  unsigned short *decb, *prevb, *tabT, *Mb;
  float *kvs, *kve;
  const float* W8[8]; unsigned short* WT8[8];
  const float* W[8]; unsigned short* WT[8];
  int K[8], N[8], Kp[8], Np[8], nbx[8], nby[8];
  int off[9];
};

__global__ __launch_bounds__(256)
void prologue_all(ProP p)
{
  __shared__ float t[64][65];
  const int bid = blockIdx.x, tid = threadIdx.x;
  if (bid < 1024) {
    const int isdec = bid < 512;
    const int row = (isdec ? bid : bid - 512) * 4 + (tid >> 6);
    const int l = tid & 63;
    const int NC = isdec ? VV : DD, NP = isdec ? VP : DD;
    const float* xr = (isdec ? p.dec_in : p.prev) + (size_t)row * NC;
    unsigned short* ob = (isdec ? p.decb : p.prevb) + (size_t)row * NP;
    int ok = 1;
    for (int j = l; j < NP; j += 64) {
      if (j < NC) {
        const float v = xr[j];
        ok &= (v != -1.0f) ? 1 : 0;
        ob[j] = f2bf(v);
      } else ob[j] = 0;
    }
    ok = __all(ok) ? 1 : 0;
    if (l == 0) (isdec ? p.kvs : p.kve)[row] = ok ? 0.f : -1e9f;
  } else if (bid < 1280) {
    const int base = (bid - 1024) * 2048 + tid * 8;
    const int d = base >> 10;
    const float ex = (float)(2 * (d >> 1)) * (1.0f / (float)DD);
    const float freq = exp2f(ex * -13.287712379549449f);
    us8 o;
#pragma unroll
    for (int e = 0; e < 8; ++e) {
      const int s = (base + e) & 1023;
      const float ang = (float)s * freq;
      o[e] = f2bf((d & 1) ? cosf(ang) : sinf(ang));
    }
    *(us8*)(p.tabT + base) = o;
  } else if (bid < 2304) {
    const int base = (bid - 1280) * 2048 + tid * 8;
    const int b = base / (SS * SS);
    const int rem = base - b * (SS * SS);
    const float* q = p.gk + (size_t)b * 3 * SS * SS + rem;
    f32x4 a0 = *(const f32x4*)q,               a1 = *(const f32x4*)(q + 4);
    f32x4 b0 = *(const f32x4*)(q + SS * SS),   b1 = *(const f32x4*)(q + SS * SS + 4);
    f32x4 c0 = *(const f32x4*)(q + 2 * SS * SS), c1 = *(const f32x4*)(q + 2 * SS * SS + 4);
    us8 o;
#pragma unroll
    for (int e = 0; e < 4; ++e) {
      o[e]     = f2bf((a0[e] + 0.9f * b0[e] + 0.81f * c0[e]) * (1.0f / 2.71f));
      o[e + 4] = f2bf((a1[e] + 0.9f * b1[e] + 0.81f * c1[e]) * (1.0f / 2.71f));
    }
    *(us8*)(p.Mb + base) = o;
  } else if (bid < 5376) {
    const int idx = bid - 2304;
    const int z = idx >> 6;
    const int rem = idx & 63;
    const int by = rem >> 3, bx = rem & 7;
    const int wi = z / LL, li = z - wi * LL;
    const float* Wl = p.W8[wi] + (size_t)li * DD * DD;
    unsigned short* WTl = p.WT8[wi] + (size_t)li * DD * DD;
    const int n0 = bx << 6, k0 = by << 6;
    const int ry4 = tid >> 4, cx4 = (tid & 15) << 2;
#pragma unroll
    for (int i = 0; i < 4; ++i) {
      const int kk = k0 + ry4 + i * 16;
      const f32x4 v = *(const f32x4*)(Wl + (size_t)kk * DD + n0 + cx4);
      t[ry4 + i * 16][cx4] = v[0]; t[ry4 + i * 16][cx4 + 1] = v[1];
      t[ry4 + i * 16][cx4 + 2] = v[2]; t[ry4 + i * 16][cx4 + 3] = v[3];
    }
    __syncthreads();
#pragma unroll
    for (int i = 0; i < 2; ++i) {
      const int flat = i * 2048 + tid * 8;
      const int nn = flat >> 6, kk = flat & 63;
      us8 o;
#pragma unroll
      for (int e = 0; e < 8; ++e) o[e] = f2bf(t[kk + e][nn]);
      *(us8*)(WTl + (size_t)(n0 + nn) * DD + k0 + kk) = o;
    }
  } else {
    const int bid2 = bid - 5376;
    int j = 0;
#pragma unroll
    for (int i = 0; i < 8; ++i) if (bid2 >= p.off[i + 1]) j = i + 1;
    const int local = bid2 - p.off[j];
    const int per = p.nbx[j] * p.nby[j];
    const int z = local / per;
    const int rem = local - z * per;
    const int by = rem / p.nbx[j];
    const int bx = rem - by * p.nbx[j];
    const int K = p.K[j], N = p.N[j], Kp = p.Kp[j], Np = p.Np[j];
    const float* Wl = p.W[j] + (size_t)z * K * N;
    unsigned short* WTl = p.WT[j] + (size_t)z * Np * Kp;
    const int n0 = bx << 6, k0 = by << 6;
    const int ry4 = tid >> 4, cx4 = (tid & 15) << 2;
#pragma unroll
    for (int i = 0; i < 4; ++i) {
      const int kk = k0 + ry4 + i * 16;
      const int nnb = n0 + cx4;
      f32x4 v;
      if (kk < K && nnb + 3 < N) {
        v = *(const f32x4*)(Wl + (size_t)kk * N + nnb);
      } else {
#pragma unroll
        for (int e = 0; e < 4; ++e)
          v[e] = (kk < K && nnb + e < N) ? Wl[(size_t)kk * N + nnb + e] : 0.f;
      }
      t[ry4 + i * 16][cx4] = v[0]; t[ry4 + i * 16][cx4 + 1] = v[1];
      t[ry4 + i * 16][cx4 + 2] = v[2]; t[ry4 + i * 16][cx4 + 3] = v[3];
    }
    __syncthreads();
#pragma unroll
    for (int i = 0; i < 2; ++i) {
      const int flat = i * 2048 + tid * 8;
      const int nn = flat >> 6, kk = flat & 63;
      us8 o;
#pragma unroll
      for (int e = 0; e < 8; ++e) o[e] = f2bf(t[kk + e][nn]);
      *(us8*)(WTl + (size_t)(n0 + nn) * Kp + k0 + kk) = o;
    }
  }
}

// ---------------------------------------------------------------------------
static inline void g1(hipStream_t s, const unsigned short* A, const unsigned short* B,
                      const float* bias, float* C, unsigned short* D,
                      int Kp, int Np, int ldc, int Nreal, int relu)
{
  GemmP p{};
  p.A = A; p.B0 = B; p.bias = bias; p.C = C; p.D0 = D;
  p.Kp = Kp; p.Np = Np; p.ldc = ldc; p.Nreal = Nreal; p.relu = relu;
  gemm_tpl<1, 64, 0, 1><<<dim3(Np >> 6, MM >> 6), 256, 0, s>>>(p);
}

static inline void g1w(hipStream_t s, const unsigned short* A, const unsigned short* B,
                       const float* bias, unsigned short* D, int Kp, int Np, int relu)
{
  GemmP p{};
  p.A = A; p.B0 = B; p.bias = bias; p.D0 = D;
  p.Kp = Kp; p.Np = Np; p.ldc = Np; p.Nreal = Np; p.relu = relu;
  gemm_tpl<1, 128, 0, 1><<<dim3(Np >> 7, MM >> 6), 256, 0, s>>>(p);
}

// split-K: f32 partials to C + z*MM*DD
template<int KS>
static inline void g1k(hipStream_t s, const unsigned short* A, const unsigned short* B,
                       const float* bias, float* C, int Kp)
{
  GemmP p{};
  p.A = A; p.B0 = B; p.bias = bias; p.C = C;
  p.Kp = Kp; p.Np = DD; p.ldc = DD; p.Nreal = DD; p.relu = 0;
  gemm_tpl<1, 64, 0, KS><<<dim3(DD >> 6, MM >> 6, KS), 256, 0, s>>>(p);
}

// QKV fused: D0=Q rows, D1=K rows, D2=V transposed
static inline void g3t(hipStream_t s, const unsigned short* A, const unsigned short* B0,
                       const unsigned short* B1, const unsigned short* B2,
                       unsigned short* D0, unsigned short* D1, unsigned short* D2T)
{
  GemmP p{};
  p.A = A; p.B0 = B0; p.B1 = B1; p.B2 = B2; p.D0 = D0; p.D1 = D1; p.D2 = D2T;
  p.Kp = DD; p.Np = DD; p.ldc = DD; p.Nreal = DD; p.relu = 0;
  gemm_tpl<3, 64, 1, 1><<<dim3(3 * (DD >> 6), MM >> 6), 256, 0, s>>>(p);
}

extern "C" void kernel_launch(void* const* d_in, const int* in_sizes, int n_in,
                              void* d_out, int out_size, void* d_ws, size_t ws_size,
                              hipStream_t stream)
{
  (void)in_sizes; (void)n_in; (void)out_size; (void)ws_size;
  const float* dec_in = (const float*)d_in[0];
  const float* prev   = (const float*)d_in[1];
  const float* gk     = (const float*)d_in[6];
  const float* emb_w1 = (const float*)d_in[7];
  const float* emb_b1 = (const float*)d_in[8];
  const float* emb_w2 = (const float*)d_in[9];
  const float* emb_b2 = (const float*)d_in[10];
  const float* emb_w3 = (const float*)d_in[11];
  const float* emb_b3 = (const float*)d_in[12];
  const float* ln0_g  = (const float*)d_in[13];
  const float* ln0_b  = (const float*)d_in[14];
  const float* wq     = (const float*)d_in[15];
  const float* wk     = (const float*)d_in[16];
  const float* wv     = (const float*)d_in[17];
  const float* wo     = (const float*)d_in[18];
  const float* cq     = (const float*)d_in[19];
  const float* ck     = (const float*)d_in[20];
  const float* cv     = (const float*)d_in[21];
  const float* co     = (const float*)d_in[22];
  const float* ffn_w1 = (const float*)d_in[23];
  const float* ffn_w2 = (const float*)d_in[24];
  const float* ffn_b1 = (const float*)d_in[25];
  const float* ffn_b2 = (const float*)d_in[26];
  const float* ln1_g  = (const float*)d_in[27];
  const float* ln1_b  = (const float*)d_in[28];
  const float* ln2_g  = (const float*)d_in[29];
  const float* ln2_b  = (const float*)d_in[30];
  const float* ln3_g  = (const float*)d_in[31];
  const float* ln3_b  = (const float*)d_in[32];
  const float* p_w1   = (const float*)d_in[33];
  const float* p_b1   = (const float*)d_in[34];
  const float* p_w2   = (const float*)d_in[35];
  const float* p_b2   = (const float*)d_in[36];
  const float* p_w3   = (const float*)d_in[37];
  const float* p_b3   = (const float*)d_in[38];

  // ---- workspace carve ----
  char* wsp = (char*)d_ws;
  auto carve = [&](size_t bytes) { char* r = wsp; wsp += (bytes + 255) & ~(size_t)255; return r; };

  unsigned short* decb  = (unsigned short*)carve((size_t)MM * VP * 2);
  unsigned short* prevb = (unsigned short*)carve((size_t)MM * DD * 2);
  float*          hf    = (float*)carve((size_t)MM * DD * 4);
  unsigned short* hb    = (unsigned short*)carve((size_t)MM * DD * 2);
  float*          xf1   = (float*)carve((size_t)MM * DD * 4);
  unsigned short* tb1   = (unsigned short*)carve((size_t)MM * DFFN * 2);   // 8 MB
  unsigned short* Mbb   = tb1;                                   // alias: first 4 MB
  float*          xf2   = (float*)((char*)tb1 + (size_t)MM * SS * 2);      // alias: last 4 MB
  unsigned short* tb2a  = (unsigned short*)carve((size_t)MM * VP * 2);
  unsigned short* tb2b  = (unsigned short*)carve((size_t)MM * VP * 2);
  unsigned short* qb    = (unsigned short*)carve((size_t)MM * DD * 2);
  unsigned short* kb    = (unsigned short*)carve((size_t)MM * DD * 2);
  unsigned short* vbT   = (unsigned short*)carve((size_t)MM * DD * 2);
  float* kvs = (float*)carve((size_t)MM * 4);
  float* kve = (float*)carve((size_t)MM * 4);
  unsigned short* postabt = (unsigned short*)carve((size_t)DD * SS * 2);
  unsigned short* ew1t  = (unsigned short*)carve((size_t)VP * VP * 2);
  unsigned short* ew2t  = (unsigned short*)carve((size_t)VP * VP * 2);
  unsigned short* ew3t  = (unsigned short*)carve((size_t)DD * VP * 2);
  unsigned short* wqt   = (unsigned short*)carve((size_t)LL * DD * DD * 2);
  unsigned short* wkt   = (unsigned short*)carve((size_t)LL * DD * DD * 2);
  unsigned short* wvt   = (unsigned short*)carve((size_t)LL * DD * DD * 2);
  unsigned short* wot   = (unsigned short*)carve((size_t)LL * DD * DD * 2);
  unsigned short* cqt   = (unsigned short*)carve((size_t)LL * DD * DD * 2);
  unsigned short* ckt   = (unsigned short*)carve((size_t)LL * DD * DD * 2);
  unsigned short* cvt   = (unsigned short*)carve((size_t)LL * DD * DD * 2);
  unsigned short* cot   = (unsigned short*)carve((size_t)LL * DD * DD * 2);
  unsigned short* f1t   = (unsigned short*)carve((size_t)LL * DFFN * DD * 2);
  unsigned short* f2t   = (unsigned short*)carve((size_t)LL * DD * DFFN * 2);
  unsigned short* p1t   = (unsigned short*)carve((size_t)VP * DD * 2);
  unsigned short* p2t   = (unsigned short*)carve((size_t)VP * VP * 2);
  unsigned short* p3t   = (unsigned short*)carve((size_t)VP * VP * 2);
  unsigned short* ckall = (unsigned short*)carve((size_t)LL * MM * DD * 2);  // 12 MB
  unsigned short* cvbT  = (unsigned short*)carve((size_t)LL * MM * DD * 2);  // 12 MB
  float*          xk4   = (float*)carve((size_t)4 * MM * DD * 4);            // 16 MB

  const dim3 agrid(SS / 32, HH, BB);

  // ---- mega prologue (1 launch, vectorized loads + stores) ----
  {
    ProP pp{};
    pp.dec_in = dec_in; pp.prev = prev; pp.gk = gk;
    pp.decb = decb; pp.prevb = prevb; pp.tabT = postabt; pp.Mb = Mbb;
    pp.kvs = kvs; pp.kve = kve;
    const float* W8s[8] = {wq, wk, wv, wo, cq, ck, cv, co};
    unsigned short* WT8s[8] = {wqt, wkt, wvt, wot, cqt, ckt, cvt, cot};
    for (int i = 0; i < 8; ++i) { pp.W8[i] = W8s[i]; pp.WT8[i] = WT8s[i]; }
    const float* Ws[8]    = {emb_w1, emb_w2, emb_w3, ffn_w1, ffn_w2, p_w1, p_w2, p_w3};
    unsigned short* Ds[8] = {ew1t, ew2t, ew3t, f1t, f2t, p1t, p2t, p3t};
    const int Ks[8]  = {VV, VV, VV, DD, DFFN, DD, VV, VV};
    const int Ns[8]  = {VV, VV, DD, DFFN, DD, VV, VV, VV};
    const int Kps[8] = {VP, VP, VP, DD, DFFN, DD, VP, VP};
    const int Nps[8] = {VP, VP, DD, DFFN, DD, VP, VP, VP};
    const int nls[8] = {1, 1, 1, LL, LL, 1, 1, 1};
    int off = 0;
    for (int j = 0; j < 8; ++j) {
      pp.W[j] = Ws[j]; pp.WT[j] = Ds[j];
      pp.K[j] = Ks[j]; pp.N[j] = Ns[j]; pp.Kp[j] = Kps[j]; pp.Np[j] = Nps[j];
      pp.nbx[j] = (Nps[j] + 63) / 64; pp.nby[j] = (Kps[j] + 63) / 64;
      pp.off[j] = off;
      off += pp.nbx[j] * pp.nby[j] * nls[j];
    }
    pp.off[8] = off;
    prologue_all<<<5376 + off, 256, 0, stream>>>(pp);
  }

  // ---- cross-KV bat (3072) + emb1 (288) + GPE (256) in ONE launch ----
  {
    GemmMultiP p{};
    p.A = prevb;
    for (int i = 0; i < LL; ++i) {
      p.B[2 * i]     = ckt + (size_t)i * DD * DD;
      p.B[2 * i + 1] = cvt + (size_t)i * DD * DD;
      p.D[2 * i]     = ckall + (size_t)i * MM * DD;
      p.D[2 * i + 1] = cvbT + (size_t)i * MM * DD;
    }
    p.eA = decb; p.eB = ew1t; p.ebias = emb_b1; p.eD = tb2a;
    p.gA = Mbb; p.gB = postabt; p.gC = xf2;
    gemm_multi<<<3616, 256, 0, stream>>>(p);
  }

  // ---- rest of embedding MLP ----
  g1(stream, tb2a, ew2t, emb_b2, nullptr, tb2b, VP, VP, VP, VV, 1);
  g1(stream, tb2b, ew3t, emb_b3, xf1, nullptr, VP, DD, DD, DD, 0);
  addln_kernel<1><<<MM / 4, 256, 0, stream>>>(xf1, xf2, ln0_g, ln0_b, hf, hb);

  for (int i = 0; i < LL; ++i) {
    const size_t od = (size_t)i * DD * DD;
    // self attention (V written transposed by the QKV GEMM)
    g3t(stream, hb, wqt + od, wkt + od, wvt + od, qb, kb, vbT);
    attn_kernel<<<agrid, 128, 0, stream>>>(qb, kb, vbT, qb, kvs);
    g1k<2>(stream, qb, wot + od, nullptr, xk4, DD);
    addln_kernel<2><<<MM / 4, 256, 0, stream>>>(hf, xk4, ln1_g + i * DD, ln1_b + i * DD, hf, hb);
    // cross attention with fused Q-projection (K/V precomputed)
    attnx_kernel<<<agrid, 128, 0, stream>>>(hb, cqt + od, ckall + (size_t)i * MM * DD,
                                            cvbT + (size_t)i * MM * DD, qb, kve);
    g1k<2>(stream, qb, cot + od, nullptr, xk4, DD);
    addln_kernel<2><<<MM / 4, 256, 0, stream>>>(hf, xk4, ln2_g + i * DD, ln2_b + i * DD, hf, hb);
    // FFN (ffn2 split-K x4)
    g1w(stream, hb, f1t + (size_t)i * DFFN * DD, ffn_b1 + i * DFFN, tb1, DD, DFFN, 1);
    g1k<4>(stream, tb1, f2t + (size_t)i * DD * DFFN, ffn_b2 + i * DD, xk4, DFFN);
    addln_kernel<4><<<MM / 4, 256, 0, stream>>>(hf, xk4, ln3_g + i * DD, ln3_b + i * DD, hf, hb);
  }

  // ---- output head ----
  g1(stream, hb, p1t, p_b1, nullptr, tb2a, DD, VP, VP, VV, 1);
  g1(stream, tb2a, p2t, p_b2, nullptr, tb2b, VP, VP, VP, VV, 1);
  g1(stream, tb2b, p3t, p_b3, (float*)d_out, nullptr, VP, VP, VV, VV, 0);
}